// Round 1
// baseline (2306.590 us; speedup 1.0000x reference)
//
#include <hip/hip_runtime.h>
#include <math.h>

#define L_   110
#define B_   64
#define N_   7040
#define U_   768
#define G_   512
#define H_   256
#define FF_  2048
#define E_   140800
#define EPB_ 2200

// prefix(j) = number of edges with src-row j' < j within one dialogue
__device__ __forceinline__ int edge_prefix(int j) {
  if (j <= 10)  return j * 11 + (j * (j - 1)) / 2;
  if (j <= 100) return 155 + (j - 10) * 21;
  return 2045 + ((141 - j) * (j - 100)) / 2;
}

// ---------------- generic f32 GEMM: C = [C +] A @ op(B) [+ bias] [relu] ----
// A: (M,K) lda. TRANS_B: B is (N,K) ldb (weight layout). else B is (K,N) ldb.
// grid = (N/64, M/64); block = 256. Requires M%64==0, N%64==0, K%16==0.
template<bool TRANS_B, bool BIAS, bool RELU, bool ACC>
__global__ __launch_bounds__(256)
void gemm_kernel(const float* __restrict__ A, const float* __restrict__ B,
                 const float* __restrict__ bias, float* __restrict__ C,
                 int K, int lda, int ldb, int ldc)
{
  __shared__ float As[16][68];   // row stride 272B -> 16B aligned for b128
  __shared__ float Bs[16][68];
  const int tid = threadIdx.x;
  const int m0 = blockIdx.y * 64;
  const int n0 = blockIdx.x * 64;
  const int tm = tid >> 4, tn = tid & 15;
  const int lm = tid >> 2, lk = (tid & 3) * 4;
  float c[4][4] = {};
  for (int k0 = 0; k0 < K; k0 += 16) {
    float4 av = *(const float4*)(A + (size_t)(m0 + lm) * lda + (k0 + lk));
    As[lk + 0][lm] = av.x; As[lk + 1][lm] = av.y;
    As[lk + 2][lm] = av.z; As[lk + 3][lm] = av.w;
    if constexpr (TRANS_B) {
      float4 bv = *(const float4*)(B + (size_t)(n0 + lm) * ldb + (k0 + lk));
      Bs[lk + 0][lm] = bv.x; Bs[lk + 1][lm] = bv.y;
      Bs[lk + 2][lm] = bv.z; Bs[lk + 3][lm] = bv.w;
    } else {
      const int bk = tid >> 4, bn = (tid & 15) * 4;
      float4 bv = *(const float4*)(B + (size_t)(k0 + bk) * ldb + (n0 + bn));
      *(float4*)&Bs[bk][bn] = bv;
    }
    __syncthreads();
#pragma unroll
    for (int kk = 0; kk < 16; ++kk) {
      float4 a4 = *(const float4*)&As[kk][tm * 4];
      float4 b4 = *(const float4*)&Bs[kk][tn * 4];
      const float a[4] = {a4.x, a4.y, a4.z, a4.w};
      const float b[4] = {b4.x, b4.y, b4.z, b4.w};
#pragma unroll
      for (int i = 0; i < 4; ++i)
#pragma unroll
        for (int j = 0; j < 4; ++j)
          c[i][j] = fmaf(a[i], b[j], c[i][j]);
    }
    __syncthreads();
  }
#pragma unroll
  for (int i = 0; i < 4; ++i) {
    float* crow = C + (size_t)(m0 + tm * 4 + i) * ldc + (n0 + tn * 4);
    float4 v = make_float4(c[i][0], c[i][1], c[i][2], c[i][3]);
    if constexpr (ACC) {
      float4 o = *(const float4*)crow;
      v.x += o.x; v.y += o.y; v.z += o.z; v.w += o.w;
    }
    if constexpr (BIAS) {
      float4 bb = *(const float4*)(bias + n0 + tn * 4);
      v.x += bb.x; v.y += bb.y; v.z += bb.z; v.w += bb.w;
    }
    if constexpr (RELU) {
      v.x = fmaxf(v.x, 0.f); v.y = fmaxf(v.y, 0.f);
      v.z = fmaxf(v.z, 0.f); v.w = fmaxf(v.w, 0.f);
    }
    *(float4*)crow = v;
  }
}

// ---------------- single-head attention over L=110, ctx = softmax(qk/√U)@v --
__global__ __launch_bounds__(256)
void attn_kernel(const float* __restrict__ qkv, float* __restrict__ ctx)
{
  const int bj = blockIdx.x;
  const int b = bj / L_;
  __shared__ float qrow[U_];
  __shared__ float p[128];
  __shared__ float sinv[1];
  const int tid = threadIdx.x;
  const float* qp = qkv + (size_t)bj * (3 * U_);
  for (int d = tid; d < U_; d += 256) qrow[d] = qp[d];
  __syncthreads();
  const int wave = tid >> 6, lane = tid & 63;
  for (int k = wave; k < L_; k += 4) {
    const float* kp = qkv + (size_t)(b * L_ + k) * (3 * U_) + U_;
    float s = 0.f;
    for (int d = lane; d < U_; d += 64) s = fmaf(qrow[d], kp[d], s);
#pragma unroll
    for (int off = 32; off; off >>= 1) s += __shfl_xor(s, off);
    if (lane == 0) p[k] = s * 0.03608439182435161f;  // 1/sqrt(768)
  }
  __syncthreads();
  if (tid < 64) {
    float m = -1e30f;
    for (int k = tid; k < L_; k += 64) m = fmaxf(m, p[k]);
#pragma unroll
    for (int off = 32; off; off >>= 1) m = fmaxf(m, __shfl_xor(m, off));
    float ss = 0.f;
    for (int k = tid; k < L_; k += 64) { float e = __expf(p[k] - m); p[k] = e; ss += e; }
#pragma unroll
    for (int off = 32; off; off >>= 1) ss += __shfl_xor(ss, off);
    if (tid == 0) sinv[0] = 1.f / ss;
  }
  __syncthreads();
  const float inv = sinv[0];
  for (int d = tid; d < U_; d += 256) {
    float acc = 0.f;
    for (int k = 0; k < L_; ++k)
      acc = fmaf(p[k], qkv[(size_t)(b * L_ + k) * (3 * U_) + 2 * U_ + d], acc);
    ctx[(size_t)bj * U_ + d] = acc * inv;
  }
}

// ---------------- LayerNorm(A + Bres) over last dim 768 ----------------
__global__ __launch_bounds__(256)
void ln_kernel(const float* __restrict__ A, const float* __restrict__ Bres,
               const float* __restrict__ g, const float* __restrict__ beta,
               float* __restrict__ out)
{
  const int row = blockIdx.x, tid = threadIdx.x;
  const float* ap = A + (size_t)row * U_;
  const float* bp = Bres + (size_t)row * U_;
  float v0 = ap[tid] + bp[tid];
  float v1 = ap[tid + 256] + bp[tid + 256];
  float v2 = ap[tid + 512] + bp[tid + 512];
  float s = v0 + v1 + v2, sq = v0 * v0 + v1 * v1 + v2 * v2;
  __shared__ float red[8];
#pragma unroll
  for (int off = 32; off; off >>= 1) { s += __shfl_xor(s, off); sq += __shfl_xor(sq, off); }
  const int wave = tid >> 6, lane = tid & 63;
  if (lane == 0) { red[wave] = s; red[4 + wave] = sq; }
  __syncthreads();
  if (tid == 0) {
    float ts = red[0] + red[1] + red[2] + red[3];
    float tq = red[4] + red[5] + red[6] + red[7];
    float m = ts * (1.f / 768.f);
    float var = tq * (1.f / 768.f) - m * m;
    red[0] = m; red[1] = 1.f / sqrtf(var + 1e-5f);
  }
  __syncthreads();
  const float m = red[0], inv = red[1];
  float* op = out + (size_t)row * U_;
  op[tid]       = (v0 - m) * inv * g[tid]       + beta[tid];
  op[tid + 256] = (v1 - m) * inv * g[tid + 256] + beta[tid + 256];
  op[tid + 512] = (v2 - m) * inv * g[tid + 512] + beta[tid + 512];
}

// ---------------- windowed edge softmax -> edge_norm (per (b,j)) -----------
__global__ __launch_bounds__(256)
void edgeatt_kernel(const float* __restrict__ tmp, const float* __restrict__ feats,
                    float* __restrict__ edge_norm)
{
  const int bj = blockIdx.x;
  const int b = bj / L_, j = bj - b * L_;
  const int k0 = max(0, j - 10), k1 = min(L_ - 1, j + 10);
  __shared__ float trow[G_];
  __shared__ float s[32];
  const int tid = threadIdx.x;
  const float* tp = tmp + (size_t)bj * G_;
  for (int d = tid; d < G_; d += 256) trow[d] = tp[d];
  __syncthreads();
  const int wave = tid >> 6, lane = tid & 63;
  for (int k = k0 + wave; k <= k1; k += 4) {
    const float* fp = feats + (size_t)(b * L_ + k) * G_;
    float sc = 0.f;
    for (int d = lane; d < G_; d += 64) sc = fmaf(trow[d], fp[d], sc);
#pragma unroll
    for (int off = 32; off; off >>= 1) sc += __shfl_xor(sc, off);
    if (lane == 0) s[k - k0] = sc;
  }
  __syncthreads();
  if (tid == 0) {
    const int W = k1 - k0 + 1;
    float m = -1e30f;
    for (int t = 0; t < W; ++t) m = fmaxf(m, s[t]);
    float sum = 0.f;
    for (int t = 0; t < W; ++t) { float e = __expf(s[t] - m); s[t] = e; sum += e; }
    const float inv = 1.f / sum;
    const int base = b * EPB_ + edge_prefix(j);
    for (int t = 0; t < W; ++t) edge_norm[base + t] = s[t] * inv;
  }
}

// ---------------- w_rel[r] = sum_b comp[r,b] * basis[b] --------------------
__global__ __launch_bounds__(256)
void wrel_kernel(const float* __restrict__ basis, const float* __restrict__ comp,
                 float* __restrict__ wrel)
{
  __shared__ float cs[240];
  const int tid = threadIdx.x;
  if (tid < 240) cs[tid] = comp[tid];
  __syncthreads();
  const int gh = blockIdx.x * 256 + tid;  // < 512*256
  float acc[8] = {};
  for (int bb = 0; bb < 30; ++bb) {
    float v = basis[(size_t)bb * (G_ * H_) + gh];
#pragma unroll
    for (int r = 0; r < 8; ++r) acc[r] = fmaf(cs[r * 30 + bb], v, acc[r]);
  }
#pragma unroll
  for (int r = 0; r < 8; ++r) wrel[(size_t)r * (G_ * H_) + gh] = acc[r];
}

// ---------------- RGCN gather: h1[n] += sum_j xproj[etype][src]/cnt --------
__global__ __launch_bounds__(256)
void rgcn_gather_kernel(const float* __restrict__ xproj, const int* __restrict__ speaker,
                        float* __restrict__ h1)
{
  const int n = blockIdx.x;
  const int b = n / L_, k = n - b * L_;
  const int j0 = max(0, k - 10), j1 = min(L_ - 1, k + 10);
  __shared__ int spw[32];
  __shared__ int spk_s;
  const int tid = threadIdx.x;
  if (tid <= j1 - j0) spw[tid] = speaker[b * L_ + j0 + tid];
  if (tid == 0) spk_s = speaker[n];
  __syncthreads();
  const int spk = spk_s;
  float inv[4];
  {
    int cn[4] = {0, 0, 0, 0};
    for (int j = j0; j <= j1; ++j) cn[spw[j - j0] * 2 + (j >= k ? 1 : 0)]++;
#pragma unroll
    for (int q = 0; q < 4; ++q) inv[q] = cn[q] ? 1.f / (float)cn[q] : 0.f;
  }
  float acc = 0.f;
  for (int j = j0; j <= j1; ++j) {
    const int spj = spw[j - j0];
    const int c = (j >= k) ? 1 : 0;
    const int et = (spj * 2 + spk) * 2 + c;
    acc = fmaf(xproj[((size_t)et * N_ + (b * L_ + j)) * H_ + tid], inv[spj * 2 + c], acc);
  }
  h1[(size_t)n * H_ + tid] += acc;
}

// ---------------- GraphConv gather: agg[n] = sum_j en[e] * h1[src] ---------
__global__ __launch_bounds__(256)
void gcn_gather_kernel(const float* __restrict__ edge_norm, const float* __restrict__ h1,
                       float* __restrict__ agg)
{
  const int n = blockIdx.x;
  const int b = n / L_, k = n - b * L_;
  const int j0 = max(0, k - 10), j1 = min(L_ - 1, k + 10);
  __shared__ float en[32];
  const int tid = threadIdx.x;
  if (tid <= j1 - j0) {
    const int j = j0 + tid;
    const int e = b * EPB_ + edge_prefix(j) + (k - max(0, j - 10));
    en[tid] = edge_norm[e];
  }
  __syncthreads();
  float acc = 0.f;
  for (int j = j0; j <= j1; ++j)
    acc = fmaf(en[j - j0], h1[(size_t)(b * L_ + j) * H_ + tid], acc);
  agg[(size_t)n * H_ + tid] = acc;
}

// ---------------- final tiny GEMM: out = hid @ clf2_w^T + clf2_b -----------
__global__ __launch_bounds__(256)
void clf2_kernel(const float* __restrict__ hid, const float* __restrict__ w,
                 const float* __restrict__ bias, float* __restrict__ out)
{
  __shared__ float wsm[7 * H_];
  const int tid = threadIdx.x;
  for (int i = tid; i < 7 * H_; i += 256) wsm[i] = w[i];
  __syncthreads();
  const int idx = blockIdx.x * 256 + tid;
  if (idx < N_ * 7) {
    const int n = idx / 7, t = idx - n * 7;
    const float* hp = hid + (size_t)n * H_;
    const float* wp = wsm + t * H_;
    float acc = bias[t];
    for (int d = 0; d < H_; ++d) acc = fmaf(hp[d], wp[d], acc);
    out[idx] = acc;
  }
}

extern "C" void kernel_launch(void* const* d_in, const int* in_sizes, int n_in,
                              void* d_out, int out_size, void* d_ws, size_t ws_size,
                              hipStream_t stream)
{
  const float* x          = (const float*)d_in[0];
  const float* in_proj_w  = (const float*)d_in[1];
  const float* in_proj_b  = (const float*)d_in[2];
  const float* out_proj_w = (const float*)d_in[3];
  const float* out_proj_b = (const float*)d_in[4];
  const float* ln1_g      = (const float*)d_in[5];
  const float* ln1_b      = (const float*)d_in[6];
  const float* ff1_w      = (const float*)d_in[7];
  const float* ff1_b      = (const float*)d_in[8];
  const float* ff2_w      = (const float*)d_in[9];
  const float* ff2_b      = (const float*)d_in[10];
  const float* ln2_g      = (const float*)d_in[11];
  const float* ln2_b      = (const float*)d_in[12];
  const float* to_w       = (const float*)d_in[13];
  const float* to_b       = (const float*)d_in[14];
  const float* att_w      = (const float*)d_in[15];
  const float* rgcn_basis = (const float*)d_in[16];
  const float* rgcn_comp  = (const float*)d_in[17];
  const float* rgcn_root  = (const float*)d_in[18];
  const float* rgcn_bias  = (const float*)d_in[19];
  const float* gc_rel_w   = (const float*)d_in[20];
  const float* gc_rel_b   = (const float*)d_in[21];
  const float* gc_root_w  = (const float*)d_in[22];
  const float* clf1_w     = (const float*)d_in[23];
  const float* clf1_b     = (const float*)d_in[24];
  const float* clf2_w     = (const float*)d_in[25];
  const float* clf2_b     = (const float*)d_in[26];
  const int*   speaker    = (const int*)d_in[27];
  float* out = (float*)d_out;
  float* ws  = (float*)d_ws;

  // workspace layout (floats), ~149 MiB total with reuse
  float* W_QKV   = ws;                                 // N*2304 ; reused: FF, XPROJ
  float* W_RA    = W_QKV   + (size_t)N_ * 2304;        // N*768  ; ctx -> tmp -> agg/h2/hid
  float* W_RB    = W_RA    + (size_t)N_ * 768;         // N*768  ; aproj -> ffo
  float* W_H     = W_RB    + (size_t)N_ * 768;         // N*768  ; post-LN h
  float* W_FEATS = W_H     + (size_t)N_ * 768;         // N*512
  float* W_WREL  = W_FEATS + (size_t)N_ * 512;         // 8*512*256
  float* W_H1    = W_WREL  + (size_t)8 * G_ * H_;      // N*256
  float* W_EN    = W_H1    + (size_t)N_ * 256;         // E
  float* W_CTX = W_RA;  float* W_TMP = W_RA;
  float* W_AGG = W_RA;  float* W_H2 = W_RA + (size_t)N_ * 256;
  float* W_HID = W_RA + (size_t)N_ * 512;
  float* W_APROJ = W_RB; float* W_FFO = W_RB;
  float* W_FF = W_QKV;   float* W_XPROJ = W_QKV;

  // 1. qkv = x @ in_proj_w^T + b            (7040,768)x(2304,768)
  gemm_kernel<true, true, false, false><<<dim3(36, 110), 256, 0, stream>>>(
      x, in_proj_w, in_proj_b, W_QKV, 768, 768, 768, 2304);
  // 2. attention context
  attn_kernel<<<N_, 256, 0, stream>>>(W_QKV, W_CTX);
  // 3. a = ctx @ out_proj_w^T + b
  gemm_kernel<true, true, false, false><<<dim3(12, 110), 256, 0, stream>>>(
      W_CTX, out_proj_w, out_proj_b, W_APROJ, 768, 768, 768, 768);
  // 4. h = LN(x + a)
  ln_kernel<<<N_, 256, 0, stream>>>(x, W_APROJ, ln1_g, ln1_b, W_H);
  // 5. ff = relu(h @ ff1_w^T + b)
  gemm_kernel<true, true, true, false><<<dim3(32, 110), 256, 0, stream>>>(
      W_H, ff1_w, ff1_b, W_FF, 768, 768, 768, 2048);
  // 6. ffo = ff @ ff2_w^T + b
  gemm_kernel<true, true, false, false><<<dim3(12, 110), 256, 0, stream>>>(
      W_FF, ff2_w, ff2_b, W_FFO, 2048, 2048, 2048, 768);
  // 7. h = LN(h + ffo)   (in place)
  ln_kernel<<<N_, 256, 0, stream>>>(W_H, W_FFO, ln2_g, ln2_b, W_H);
  // 8. feats = h @ to_w^T + b
  gemm_kernel<true, true, false, false><<<dim3(8, 110), 256, 0, stream>>>(
      W_H, to_w, to_b, W_FEATS, 768, 768, 768, 512);
  // 9. tmp = feats @ att_w            (non-transposed B)
  gemm_kernel<false, false, false, false><<<dim3(8, 110), 256, 0, stream>>>(
      W_FEATS, att_w, nullptr, W_TMP, 512, 512, 512, 512);
  // 10. windowed edge softmax -> edge_norm
  edgeatt_kernel<<<N_, 256, 0, stream>>>(W_TMP, W_FEATS, W_EN);
  // 11. w_rel
  wrel_kernel<<<512, 256, 0, stream>>>(rgcn_basis, rgcn_comp, W_WREL);
  // 12. xproj[r] = feats @ w_rel[r]
  for (int r = 0; r < 8; ++r)
    gemm_kernel<false, false, false, false><<<dim3(4, 110), 256, 0, stream>>>(
        W_FEATS, W_WREL + (size_t)r * G_ * H_, nullptr,
        W_XPROJ + (size_t)r * N_ * H_, 512, 512, 256, 256);
  // 13. h1 = feats @ rgcn_root + bias
  gemm_kernel<false, true, false, false><<<dim3(4, 110), 256, 0, stream>>>(
      W_FEATS, rgcn_root, rgcn_bias, W_H1, 512, 512, 256, 256);
  // 14. h1 += per-(dst,etype)-mean messages
  rgcn_gather_kernel<<<N_, 256, 0, stream>>>(W_XPROJ, speaker, W_H1);
  // 15. agg = sum edge_norm * h1[src]
  gcn_gather_kernel<<<N_, 256, 0, stream>>>(W_EN, W_H1, W_AGG);
  // 16. h2 = agg @ gc_rel_w^T + b
  gemm_kernel<true, true, false, false><<<dim3(4, 110), 256, 0, stream>>>(
      W_AGG, gc_rel_w, gc_rel_b, W_H2, 256, 256, 256, 256);
  // 17. h2 += h1 @ gc_root_w^T
  gemm_kernel<true, false, false, true><<<dim3(4, 110), 256, 0, stream>>>(
      W_H1, gc_root_w, nullptr, W_H2, 256, 256, 256, 256);
  // 18. hid = relu([feats|h2] @ clf1_w^T + b)  (split-K over the concat)
  gemm_kernel<true, false, false, false><<<dim3(4, 110), 256, 0, stream>>>(
      W_FEATS, clf1_w, nullptr, W_HID, 512, 512, 768, 256);
  gemm_kernel<true, true, true, true><<<dim3(4, 110), 256, 0, stream>>>(
      W_H2, clf1_w + 512, clf1_b, W_HID, 256, 256, 768, 256);
  // 19. logits
  clf2_kernel<<<(N_ * 7 + 255) / 256, 256, 0, stream>>>(W_HID, clf2_w, clf2_b, out);
}

// Round 3
// 557.197 us; speedup vs baseline: 4.1396x; 4.1396x over previous
//
#include <hip/hip_runtime.h>
#include <hip/hip_bf16.h>
#include <math.h>

#define L_   110
#define B_   64
#define N_   7040
#define U_   768
#define G_   512
#define H_   256
#define FF_  2048
#define EPB_ 2200

typedef __attribute__((ext_vector_type(4))) float f32x4;
typedef __attribute__((ext_vector_type(8))) short bf16x8;

__device__ __forceinline__ ushort f2b(float f) {
  union { __hip_bfloat16 h; ushort u; } cv;
  cv.h = __float2bfloat16(f);
  return cv.u;
}

// prefix(j) = number of edges with src-row j' < j within one dialogue
__device__ __forceinline__ int edge_prefix(int j) {
  if (j <= 10)  return j * 11 + (j * (j - 1)) / 2;
  if (j <= 100) return 155 + (j - 10) * 21;
  return 2045 + ((141 - j) * (j - 100)) / 2;
}

// ------------------- f32 -> bf16 convert (vectorized, grid-stride) ---------
__global__ __launch_bounds__(256)
void cvt_kernel(const float* __restrict__ in, ushort* __restrict__ out, int n4)
{
  for (int i = blockIdx.x * 256 + threadIdx.x; i < n4; i += gridDim.x * 256) {
    float4 v = ((const float4*)in)[i];
    ushort4 o;
    o.x = f2b(v.x); o.y = f2b(v.y); o.z = f2b(v.z); o.w = f2b(v.w);
    ((ushort4*)out)[i] = o;
  }
}

// ---------- batched tiled transpose+convert: in (R,C) f32 -> out (C,R) bf16
__global__ __launch_bounds__(256)
void tcvt_kernel(const float* __restrict__ in, ushort* __restrict__ out,
                 int R, int C, size_t inStride, size_t outStride)
{
  __shared__ float t[32][33];
  const int bt = blockIdx.z;
  const int r0 = blockIdx.y * 32, c0 = blockIdx.x * 32;
  const int tx = threadIdx.x & 31, ty = threadIdx.x >> 5;
  for (int i = ty; i < 32; i += 8)
    t[i][tx] = in[bt * inStride + (size_t)(r0 + i) * C + c0 + tx];
  __syncthreads();
  for (int i = ty; i < 32; i += 8)
    out[bt * outStride + (size_t)(c0 + i) * R + r0 + tx] = f2b(t[tx][i]);
}

// -------- w_rel[r](g,h) = sum_b comp[r,b]*basis[b](g,h) -> f32 temp --------
__global__ __launch_bounds__(256)
void wrel_kernel(const float* __restrict__ basis, const float* __restrict__ comp,
                 float* __restrict__ wrel)
{
  __shared__ float cs[240];
  const int tid = threadIdx.x;
  if (tid < 240) cs[tid] = comp[tid];
  __syncthreads();
  const int gh = blockIdx.x * 256 + tid;
  float acc[8] = {};
  for (int bb = 0; bb < 30; ++bb) {
    float v = basis[(size_t)bb * (G_ * H_) + gh];
#pragma unroll
    for (int r = 0; r < 8; ++r) acc[r] = fmaf(cs[r * 30 + bb], v, acc[r]);
  }
#pragma unroll
  for (int r = 0; r < 8; ++r) wrel[(size_t)r * (G_ * H_) + gh] = acc[r];
}

// -------- bias_comb: [0..2048)=0, [2048..2304)=rgcn_bias -------------------
__global__ void biascomb_kernel(const float* __restrict__ rb, float* __restrict__ bias)
{
  int i = blockIdx.x * 256 + threadIdx.x;
  if (i < 2304) bias[i] = (i < 2048) ? 0.f : rb[i - 2048];
}

// ===================== bf16 MFMA GEMM: C = A @ B^T (+bias)(+Cin)(relu) =====
// A (M,K) bf16 lda ; B (N,K) bf16 ldb ; out f32/bf16, ldc. grid(N/128, M/128)
// 128x128 tile, BK=64, XOR-swizzled LDS, global_load_lds w16, 2-barrier loop.
template<bool BIAS, bool RELU, bool ACC, bool OUTF, bool OUTB>
__global__ __launch_bounds__(256)
void mgemm_kernel(const ushort* __restrict__ A, const ushort* __restrict__ B,
                  const float* __restrict__ bias, const float* __restrict__ Cin,
                  float* __restrict__ Cf, ushort* __restrict__ Cb,
                  int K, int lda, int ldb, int ldc)
{
  __shared__ ushort sA[128 * 64];
  __shared__ ushort sB[128 * 64];
  const int tid = threadIdx.x;
  const int w = tid >> 6, l = tid & 63;
  const int m0 = blockIdx.y * 128, n0 = blockIdx.x * 128;

  // staging: wave w stages tile rows [w*32, w*32+32), 4 issues of 8 rows
  const int srow = l >> 3, sg = l & 7, rbase = w * 32;
  // compute-side
  const int wr = w >> 1, wc = w & 1;
  const int lrow = l & 15, lk = l >> 4;
  const int xm = (l & 7) << 4;           // swizzle XOR (bytes), row&7 == l&7
  const int kb0 = (lk * 16) ^ xm;
  int aoff[4], boff[4];
#pragma unroll
  for (int i = 0; i < 4; ++i) {
    aoff[i] = (wr * 64 + i * 16 + lrow) * 128 + kb0;
    boff[i] = (wc * 64 + i * 16 + lrow) * 128 + kb0;
  }

  f32x4 acc[4][4];
#pragma unroll
  for (int i = 0; i < 4; ++i)
#pragma unroll
    for (int j = 0; j < 4; ++j) acc[i][j] = (f32x4){0.f, 0.f, 0.f, 0.f};

#define STAGE(k0)                                                              \
  {                                                                            \
    _Pragma("unroll")                                                          \
    for (int i = 0; i < 4; ++i) {                                              \
      const int trow = rbase + i * 8 + srow;                                   \
      const int koff = (sg * 8) ^ ((trow & 7) << 3);                           \
      const ushort* ga = A + (size_t)(m0 + trow) * lda + (k0) + koff;          \
      const ushort* gb = B + (size_t)(n0 + trow) * ldb + (k0) + koff;          \
      __builtin_amdgcn_global_load_lds(                                        \
          (const __attribute__((address_space(1))) void*)ga,                   \
          (__attribute__((address_space(3))) void*)&sA[(rbase + i * 8) * 64],  \
          16, 0, 0);                                                           \
      __builtin_amdgcn_global_load_lds(                                        \
          (const __attribute__((address_space(1))) void*)gb,                   \
          (__attribute__((address_space(3))) void*)&sB[(rbase + i * 8) * 64],  \
          16, 0, 0);                                                           \
    }                                                                          \
  }

  STAGE(0)
  for (int kt = 0;;) {
    __syncthreads();   // drains vmcnt: tile ready
#pragma unroll
    for (int h = 0; h < 2; ++h) {
      const int hx = h * 64;
      bf16x8 af[4], bfr[4];
#pragma unroll
      for (int i = 0; i < 4; ++i) {
        af[i]  = *(const bf16x8*)&sA[(aoff[i] ^ hx) >> 1];
        bfr[i] = *(const bf16x8*)&sB[(boff[i] ^ hx) >> 1];
      }
#pragma unroll
      for (int mi = 0; mi < 4; ++mi)
#pragma unroll
        for (int ni = 0; ni < 4; ++ni)
          acc[mi][ni] = __builtin_amdgcn_mfma_f32_16x16x32_bf16(
              af[mi], bfr[ni], acc[mi][ni], 0, 0, 0);
    }
    kt += 64;
    if (kt >= K) break;
    __syncthreads();   // all waves done reading LDS
    STAGE(kt)
  }
#undef STAGE

  // epilogue: row = m0+wr*64+mi*16+lk*4+r ; col = n0+wc*64+ni*16+lrow
  const int orow = m0 + wr * 64 + lk * 4;
  const int ocol = n0 + wc * 64 + lrow;
#pragma unroll
  for (int mi = 0; mi < 4; ++mi) {
#pragma unroll
    for (int r = 0; r < 4; ++r) {
      const int row = orow + mi * 16 + r;
#pragma unroll
      for (int ni = 0; ni < 4; ++ni) {
        const int col = ocol + ni * 16;
        float v = acc[mi][ni][r];
        if constexpr (ACC)  v += Cin[(size_t)row * ldc + col];
        if constexpr (BIAS) v += bias[col];
        if constexpr (RELU) v = fmaxf(v, 0.f);
        if constexpr (OUTF) Cf[(size_t)row * ldc + col] = v;
        if constexpr (OUTB) Cb[(size_t)row * ldc + col] = f2b(v);
      }
    }
  }
}

// ---------------- attention: 8 q-rows per block, V reused 8x ---------------
__global__ __launch_bounds__(256)
void attn2_kernel(const float* __restrict__ qkv, ushort* __restrict__ ctxb)
{
  const int b = blockIdx.y;
  const int jc = blockIdx.x * 8;
  __shared__ float qs[8][768];
  __shared__ float ps[8][112];
  const int tid = threadIdx.x, wv = tid >> 6, ln = tid & 63;
  for (int t = tid; t < 8 * 768; t += 256) {
    const int jj = t / 768, d = t - jj * 768;
    if (jc + jj < L_) qs[jj][d] = qkv[(size_t)(b * L_ + jc + jj) * 2304 + d];
  }
  __syncthreads();
  // scores: wave wv handles q-rows jj = wv and wv+4
  for (int k = 0; k < L_; ++k) {
    const float* kp = qkv + (size_t)(b * L_ + k) * 2304 + 768;
    const float4 k0 = *(const float4*)(kp + ln * 4);
    const float4 k1 = *(const float4*)(kp + 256 + ln * 4);
    const float4 k2 = *(const float4*)(kp + 512 + ln * 4);
#pragma unroll
    for (int hf = 0; hf < 2; ++hf) {
      const int jj = wv + hf * 4;
      if (jc + jj < L_) {
        const float* q = qs[jj];
        const float4 q0 = *(const float4*)(q + ln * 4);
        const float4 q1 = *(const float4*)(q + 256 + ln * 4);
        const float4 q2 = *(const float4*)(q + 512 + ln * 4);
        float s = q0.x * k0.x + q0.y * k0.y + q0.z * k0.z + q0.w * k0.w
                + q1.x * k1.x + q1.y * k1.y + q1.z * k1.z + q1.w * k1.w
                + q2.x * k2.x + q2.y * k2.y + q2.z * k2.z + q2.w * k2.w;
#pragma unroll
        for (int off = 32; off; off >>= 1) s += __shfl_xor(s, off);
        if (ln == 0) ps[jj][k] = s * 0.03608439182435161f;  // 1/sqrt(768)
      }
    }
  }
  __syncthreads();
#pragma unroll
  for (int hf = 0; hf < 2; ++hf) {
    const int jj = wv + hf * 4;
    if (jc + jj < L_) {
      float m = -1e30f;
      for (int k = ln; k < L_; k += 64) m = fmaxf(m, ps[jj][k]);
#pragma unroll
      for (int off = 32; off; off >>= 1) m = fmaxf(m, __shfl_xor(m, off));
      float e0 = __expf(ps[jj][ln] - m), e1 = 0.f;
      float ssum = e0;
      if (ln + 64 < L_) { e1 = __expf(ps[jj][ln + 64] - m); ssum += e1; }
#pragma unroll
      for (int off = 32; off; off >>= 1) ssum += __shfl_xor(ssum, off);
      const float inv = 1.f / ssum;
      ps[jj][ln] = e0 * inv;
      if (ln + 64 < 112) ps[jj][ln + 64] = (ln + 64 < L_) ? e1 * inv : 0.f;
    } else {  // zero invalid rows so PV reads are benign
      ps[jj][ln] = 0.f;
      if (ln + 64 < 112) ps[jj][ln + 64] = 0.f;
    }
  }
  __syncthreads();
  float a0[8], a1[8], a2[8];
#pragma unroll
  for (int jj = 0; jj < 8; ++jj) { a0[jj] = 0.f; a1[jj] = 0.f; a2[jj] = 0.f; }
  for (int k = 0; k < L_; ++k) {
    const float* vp = qkv + (size_t)(b * L_ + k) * 2304 + 1536;
    const float v0 = vp[tid], v1 = vp[tid + 256], v2 = vp[tid + 512];
#pragma unroll
    for (int jj = 0; jj < 8; ++jj) {
      const float pv = ps[jj][k];
      a0[jj] = fmaf(pv, v0, a0[jj]);
      a1[jj] = fmaf(pv, v1, a1[jj]);
      a2[jj] = fmaf(pv, v2, a2[jj]);
    }
  }
#pragma unroll
  for (int jj = 0; jj < 8; ++jj) {
    if (jc + jj < L_) {
      ushort* cp = ctxb + (size_t)(b * L_ + jc + jj) * 768;
      cp[tid] = f2b(a0[jj]); cp[tid + 256] = f2b(a1[jj]); cp[tid + 512] = f2b(a2[jj]);
    }
  }
}

// ---------------- LayerNorm(A + Bres), writes f32 + bf16 -------------------
__global__ __launch_bounds__(256)
void ln_kernel(const float* __restrict__ A, const float* __restrict__ Bres,
               const float* __restrict__ g, const float* __restrict__ beta,
               float* __restrict__ out, ushort* __restrict__ outb)
{
  const int row = blockIdx.x, tid = threadIdx.x;
  const float* ap = A + (size_t)row * U_;
  const float* bp = Bres + (size_t)row * U_;
  float v0 = ap[tid] + bp[tid];
  float v1 = ap[tid + 256] + bp[tid + 256];
  float v2 = ap[tid + 512] + bp[tid + 512];
  float s = v0 + v1 + v2, sq = v0 * v0 + v1 * v1 + v2 * v2;
  __shared__ float red[8];
#pragma unroll
  for (int off = 32; off; off >>= 1) { s += __shfl_xor(s, off); sq += __shfl_xor(sq, off); }
  const int wave = tid >> 6, lane = tid & 63;
  if (lane == 0) { red[wave] = s; red[4 + wave] = sq; }
  __syncthreads();
  if (tid == 0) {
    float ts = red[0] + red[1] + red[2] + red[3];
    float tq = red[4] + red[5] + red[6] + red[7];
    float m = ts * (1.f / 768.f);
    float var = tq * (1.f / 768.f) - m * m;
    red[0] = m; red[1] = 1.f / sqrtf(var + 1e-5f);
  }
  __syncthreads();
  const float m = red[0], inv = red[1];
  float* op = out + (size_t)row * U_;
  ushort* ob = outb + (size_t)row * U_;
  float o0 = (v0 - m) * inv * g[tid] + beta[tid];
  float o1 = (v1 - m) * inv * g[tid + 256] + beta[tid + 256];
  float o2 = (v2 - m) * inv * g[tid + 512] + beta[tid + 512];
  op[tid] = o0; op[tid + 256] = o1; op[tid + 512] = o2;
  ob[tid] = f2b(o0); ob[tid + 256] = f2b(o1); ob[tid + 512] = f2b(o2);
}

// ---------------- windowed edge softmax -> edge_norm -----------------------
__global__ __launch_bounds__(256)
void edgeatt_kernel(const float* __restrict__ tmp, const float* __restrict__ feats,
                    float* __restrict__ edge_norm)
{
  const int bj = blockIdx.x;
  const int b = bj / L_, j = bj - b * L_;
  const int k0 = max(0, j - 10), k1 = min(L_ - 1, j + 10);
  __shared__ float trow[G_];
  __shared__ float s[32];
  const int tid = threadIdx.x;
  const float* tp = tmp + (size_t)bj * G_;
  for (int d = tid; d < G_; d += 256) trow[d] = tp[d];
  __syncthreads();
  const int wave = tid >> 6, lane = tid & 63;
  for (int k = k0 + wave; k <= k1; k += 4) {
    const float* fp = feats + (size_t)(b * L_ + k) * G_;
    float sc = 0.f;
    for (int d = lane; d < G_; d += 64) sc = fmaf(trow[d], fp[d], sc);
#pragma unroll
    for (int off = 32; off; off >>= 1) sc += __shfl_xor(sc, off);
    if (lane == 0) s[k - k0] = sc;
  }
  __syncthreads();
  if (tid == 0) {
    const int W = k1 - k0 + 1;
    float m = -1e30f;
    for (int t = 0; t < W; ++t) m = fmaxf(m, s[t]);
    float sum = 0.f;
    for (int t = 0; t < W; ++t) { float e = __expf(s[t] - m); s[t] = e; sum += e; }
    const float inv = 1.f / sum;
    const int base = b * EPB_ + edge_prefix(j);
    for (int t = 0; t < W; ++t) edge_norm[base + t] = s[t] * inv;
  }
}

// -------- RGCN gather (xcomb layout: [n][et*256+h], root at [n][2048+h]) ---
__global__ __launch_bounds__(256)
void rgcn_gather_kernel(const float* __restrict__ xcomb, const int* __restrict__ speaker,
                        float* __restrict__ h1, ushort* __restrict__ h1b)
{
  const int n = blockIdx.x;
  const int b = n / L_, k = n - b * L_;
  const int j0 = max(0, k - 10), j1 = min(L_ - 1, k + 10);
  __shared__ int spw[32];
  __shared__ int spk_s;
  const int tid = threadIdx.x;
  if (tid <= j1 - j0) spw[tid] = speaker[b * L_ + j0 + tid];
  if (tid == 0) spk_s = speaker[n];
  __syncthreads();
  const int spk = spk_s;
  float inv[4];
  {
    int cn[4] = {0, 0, 0, 0};
    for (int j = j0; j <= j1; ++j) cn[spw[j - j0] * 2 + (j >= k ? 1 : 0)]++;
#pragma unroll
    for (int q = 0; q < 4; ++q) inv[q] = cn[q] ? 1.f / (float)cn[q] : 0.f;
  }
  float acc = 0.f;
  for (int j = j0; j <= j1; ++j) {
    const int spj = spw[j - j0];
    const int c = (j >= k) ? 1 : 0;
    const int et = (spj * 2 + spk) * 2 + c;
    acc = fmaf(xcomb[(size_t)(b * L_ + j) * 2304 + et * 256 + tid], inv[spj * 2 + c], acc);
  }
  const float hv = xcomb[(size_t)n * 2304 + 2048 + tid] + acc;  // root+bias part
  h1[(size_t)n * H_ + tid] = hv;
  h1b[(size_t)n * H_ + tid] = f2b(hv);
}

// ---------------- GraphConv gather -> bf16 agg -----------------------------
__global__ __launch_bounds__(256)
void gcn_gather_kernel(const float* __restrict__ edge_norm, const float* __restrict__ h1,
                       ushort* __restrict__ aggb)
{
  const int n = blockIdx.x;
  const int b = n / L_, k = n - b * L_;
  const int j0 = max(0, k - 10), j1 = min(L_ - 1, k + 10);
  __shared__ float en[32];
  const int tid = threadIdx.x;
  if (tid <= j1 - j0) {
    const int j = j0 + tid;
    const int e = b * EPB_ + edge_prefix(j) + (k - max(0, j - 10));
    en[tid] = edge_norm[e];
  }
  __syncthreads();
  float acc = 0.f;
  for (int j = j0; j <= j1; ++j)
    acc = fmaf(en[j - j0], h1[(size_t)(b * L_ + j) * H_ + tid], acc);
  aggb[(size_t)n * H_ + tid] = f2b(acc);
}

// ---------------- final tiny GEMM: out = hid @ clf2_w^T + clf2_b -----------
__global__ __launch_bounds__(256)
void clf2_kernel(const float* __restrict__ hid, const float* __restrict__ w,
                 const float* __restrict__ bias, float* __restrict__ out)
{
  __shared__ float wsm[7 * H_];
  const int tid = threadIdx.x;
  for (int i = tid; i < 7 * H_; i += 256) wsm[i] = w[i];
  __syncthreads();
  const int idx = blockIdx.x * 256 + threadIdx.x;
  if (idx < N_ * 7) {
    const int n = idx / 7, t = idx - n * 7;
    const float* hp = hid + (size_t)n * H_;
    const float* wp = wsm + t * H_;
    float acc = bias[t];
    for (int d = 0; d < H_; ++d) acc = fmaf(hp[d], wp[d], acc);
    out[idx] = acc;
  }
}

extern "C" void kernel_launch(void* const* d_in, const int* in_sizes, int n_in,
                              void* d_out, int out_size, void* d_ws, size_t ws_size,
                              hipStream_t stream)
{
  const float* x          = (const float*)d_in[0];
  const float* in_proj_w  = (const float*)d_in[1];
  const float* in_proj_b  = (const float*)d_in[2];
  const float* out_proj_w = (const float*)d_in[3];
  const float* out_proj_b = (const float*)d_in[4];
  const float* ln1_g      = (const float*)d_in[5];
  const float* ln1_b      = (const float*)d_in[6];
  const float* ff1_w      = (const float*)d_in[7];
  const float* ff1_b      = (const float*)d_in[8];
  const float* ff2_w      = (const float*)d_in[9];
  const float* ff2_b      = (const float*)d_in[10];
  const float* ln2_g      = (const float*)d_in[11];
  const float* ln2_b      = (const float*)d_in[12];
  const float* to_w       = (const float*)d_in[13];
  const float* to_b       = (const float*)d_in[14];
  const float* att_w      = (const float*)d_in[15];
  const float* rgcn_basis = (const float*)d_in[16];
  const float* rgcn_comp  = (const float*)d_in[17];
  const float* rgcn_root  = (const float*)d_in[18];
  const float* rgcn_bias  = (const float*)d_in[19];
  const float* gc_rel_w   = (const float*)d_in[20];
  const float* gc_rel_b   = (const float*)d_in[21];
  const float* gc_root_w  = (const float*)d_in[22];
  const float* clf1_w     = (const float*)d_in[23];
  const float* clf1_b     = (const float*)d_in[24];
  const float* clf2_w     = (const float*)d_in[25];
  const float* clf2_b     = (const float*)d_in[26];
  const int*   speaker    = (const int*)d_in[27];
  float* out = (float*)d_out;
  char* p = (char*)d_ws;

  // ---- workspace regions (byte offsets, sequential reuse) ----
  // R1 (65MB): wrelTmp -> qkv f32 -> ff bf16 -> tmp f32 -> xcomb f32
  float*  R1f   = (float*)p;
  ushort* R1b   = (ushort*)p;
  p += (size_t)N_ * 2304 * 4;
  // R2 (21.6MB): aproj -> ffo -> feats f32 ; tail: edge_norm
  float*  aproj = (float*)p;
  float*  ffo   = aproj;
  float*  feats = aproj;
  float*  en    = (float*)(p + (size_t)N_ * 512 * 4);
  p += (size_t)N_ * 768 * 4;
  // R3 (21.6MB): h f32 -> {h1, h2, hid}
  float*  hbuf  = (float*)p;
  float*  h1    = hbuf;
  float*  h2    = (float*)(p + (size_t)N_ * 256 * 4);
  float*  hid   = (float*)(p + (size_t)N_ * 512 * 4);
  p += (size_t)N_ * 768 * 4;
  // R4 (10.8MB): xb -> ctxb
  ushort* xb    = (ushort*)p;
  ushort* ctxb  = xb;
  p += (size_t)N_ * 768 * 2;
  // R5 (10.8MB): hb -> {h1b, aggb, h2b}
  ushort* hb    = (ushort*)p;
  ushort* h1b   = hb;
  ushort* aggb  = (ushort*)(p + (size_t)N_ * 256 * 2);
  ushort* h2b   = (ushort*)(p + (size_t)N_ * 512 * 2);
  p += (size_t)N_ * 768 * 2;
  // R6 (7.2MB): featsb
  ushort* featsb = (ushort*)p; p += (size_t)N_ * 512 * 2;
  // R7: bf16 weights + combined RGCN weight + bias
  ushort* in_projb = (ushort*)p; p += (size_t)2304 * 768 * 2;
  ushort* out_projb= (ushort*)p; p += (size_t)768 * 768 * 2;
  ushort* ff1b     = (ushort*)p; p += (size_t)2048 * 768 * 2;
  ushort* ff2b     = (ushort*)p; p += (size_t)768 * 2048 * 2;
  ushort* tob      = (ushort*)p; p += (size_t)512 * 768 * 2;
  ushort* attwb    = (ushort*)p; p += (size_t)512 * 512 * 2;
  ushort* wcomb    = (ushort*)p; p += (size_t)2304 * 512 * 2;
  ushort* gcrelb   = (ushort*)p; p += (size_t)256 * 256 * 2;
  ushort* gcrootb  = (ushort*)p; p += (size_t)256 * 256 * 2;
  ushort* clf1b16  = (ushort*)p; p += (size_t)256 * 768 * 2;
  float*  bias_comb= (float*)p;  p += 2304 * 4;
  float*  wrelTmp  = R1f;   // consumed before qkv GEMM

  // ---- weight prep ----
  cvt_kernel<<<1024, 256, 0, stream>>>(x, xb, N_ * 768 / 4);
  cvt_kernel<<<512, 256, 0, stream>>>(in_proj_w, in_projb, 2304 * 768 / 4);
  cvt_kernel<<<256, 256, 0, stream>>>(out_proj_w, out_projb, 768 * 768 / 4);
  cvt_kernel<<<512, 256, 0, stream>>>(ff1_w, ff1b, 2048 * 768 / 4);
  cvt_kernel<<<512, 256, 0, stream>>>(ff2_w, ff2b, 768 * 2048 / 4);
  cvt_kernel<<<256, 256, 0, stream>>>(to_w, tob, 512 * 768 / 4);
  cvt_kernel<<<64, 256, 0, stream>>>(gc_rel_w, gcrelb, 256 * 256 / 4);
  // gc_root: reference does h1 @ gc_root_w.T and mgemm computes A @ B^T,
  // so B must be gc_root_w AS-IS (round-2 bug: tcvt double-transposed it).
  cvt_kernel<<<64, 256, 0, stream>>>(gc_root_w, gcrootb, 256 * 256 / 4);
  cvt_kernel<<<128, 256, 0, stream>>>(clf1_w, clf1b16, 256 * 768 / 4);
  tcvt_kernel<<<dim3(16, 16, 1), 256, 0, stream>>>(att_w, attwb, 512, 512, 0, 0);
  wrel_kernel<<<512, 256, 0, stream>>>(rgcn_basis, rgcn_comp, wrelTmp);
  tcvt_kernel<<<dim3(8, 16, 8), 256, 0, stream>>>(wrelTmp, wcomb, 512, 256,
                                                  (size_t)512 * 256, (size_t)256 * 512);
  tcvt_kernel<<<dim3(8, 16, 1), 256, 0, stream>>>(rgcn_root, wcomb + (size_t)2048 * 512,
                                                  512, 256, 0, 0);
  biascomb_kernel<<<9, 256, 0, stream>>>(rgcn_bias, bias_comb);

  // ---- main pipeline ----
  // qkv = x @ in_proj^T + b    -> R1f (f32)
  mgemm_kernel<true, false, false, true, false><<<dim3(18, 55), 256, 0, stream>>>(
      xb, in_projb, in_proj_b, nullptr, R1f, nullptr, 768, 768, 768, 2304);
  attn2_kernel<<<dim3(14, 64), 256, 0, stream>>>(R1f, ctxb);
  // aproj = ctx @ out_proj^T + b
  mgemm_kernel<true, false, false, true, false><<<dim3(6, 55), 256, 0, stream>>>(
      ctxb, out_projb, out_proj_b, nullptr, aproj, nullptr, 768, 768, 768, 768);
  ln_kernel<<<N_, 256, 0, stream>>>(x, aproj, ln1_g, ln1_b, hbuf, hb);
  // ff = relu(h @ ff1^T + b)   -> R1b (bf16 only)
  mgemm_kernel<true, true, false, false, true><<<dim3(16, 55), 256, 0, stream>>>(
      hb, ff1b, ff1_b, nullptr, nullptr, R1b, 768, 768, 768, 2048);
  // ffo = ff @ ff2^T + b
  mgemm_kernel<true, false, false, true, false><<<dim3(6, 55), 256, 0, stream>>>(
      R1b, ff2b, ff2_b, nullptr, ffo, nullptr, 2048, 2048, 2048, 768);
  ln_kernel<<<N_, 256, 0, stream>>>(hbuf, ffo, ln2_g, ln2_b, hbuf, hb);
  // feats = h @ to^T + b  (f32 + bf16)
  mgemm_kernel<true, false, false, true, true><<<dim3(4, 55), 256, 0, stream>>>(
      hb, tob, to_b, nullptr, feats, featsb, 768, 768, 768, 512);
  // tmp = feats @ att_w  -> R1f
  mgemm_kernel<false, false, false, true, false><<<dim3(4, 55), 256, 0, stream>>>(
      featsb, attwb, nullptr, nullptr, R1f, nullptr, 512, 512, 512, 512);
  edgeatt_kernel<<<N_, 256, 0, stream>>>(R1f, feats, en);
  // xcomb = feats @ [wrel_t | root_t]^T + bias_comb  -> R1f (N x 2304)
  mgemm_kernel<true, false, false, true, false><<<dim3(18, 55), 256, 0, stream>>>(
      featsb, wcomb, bias_comb, nullptr, R1f, nullptr, 512, 512, 512, 2304);
  rgcn_gather_kernel<<<N_, 256, 0, stream>>>(R1f, speaker, h1, h1b);
  gcn_gather_kernel<<<N_, 256, 0, stream>>>(en, h1, aggb);
  // h2 = agg @ gc_rel^T + b
  mgemm_kernel<true, false, false, true, false><<<dim3(2, 55), 256, 0, stream>>>(
      aggb, gcrelb, gc_rel_b, nullptr, h2, nullptr, 256, 256, 256, 256);
  // h2b = bf16(h2 + h1 @ gc_root^T)
  mgemm_kernel<false, false, true, false, true><<<dim3(2, 55), 256, 0, stream>>>(
      h1b, gcrootb, nullptr, h2, nullptr, h2b, 256, 256, 256, 256);
  // hid = feats @ clf1[:, :512]^T
  mgemm_kernel<false, false, false, true, false><<<dim3(2, 55), 256, 0, stream>>>(
      featsb, clf1b16, nullptr, nullptr, hid, nullptr, 512, 512, 768, 256);
  // hid = relu(hid + h2 @ clf1[:, 512:]^T + b)
  mgemm_kernel<true, true, true, true, false><<<dim3(2, 55), 256, 0, stream>>>(
      h2b, clf1b16 + 512, clf1_b, hid, hid, nullptr, 256, 256, 768, 256);
  clf2_kernel<<<(N_ * 7 + 255) / 256, 256, 0, stream>>>(hid, clf2_w, clf2_b, out);
}

// Round 4
// 433.300 us; speedup vs baseline: 5.3233x; 1.2859x over previous
//
#include <hip/hip_runtime.h>
#include <hip/hip_bf16.h>
#include <math.h>

#define L_   110
#define B_   64
#define N_   7040
#define U_   768
#define G_   512
#define H_   256
#define FF_  2048
#define EPB_ 2200

typedef __attribute__((ext_vector_type(4))) float f32x4;
typedef __attribute__((ext_vector_type(8))) short bf16x8;

__device__ __forceinline__ ushort f2b(float f) {
  union { __hip_bfloat16 h; ushort u; } cv;
  cv.h = __float2bfloat16(f);
  return cv.u;
}
__device__ __forceinline__ float b2f(ushort u) {
  union { float f; unsigned int i; } cv; cv.i = ((unsigned int)u) << 16; return cv.f;
}

// prefix(j) = number of edges with src-row j' < j within one dialogue
__device__ __forceinline__ int edge_prefix(int j) {
  if (j <= 10)  return j * 11 + (j * (j - 1)) / 2;
  if (j <= 100) return 155 + (j - 10) * 21;
  return 2045 + ((141 - j) * (j - 100)) / 2;
}

// ------------- multi-segment f32->bf16 convert (one launch for 9 arrays) ---
struct Segs9 { const float* in[9]; ushort* out[9]; int n4[9]; };

__global__ __launch_bounds__(256)
void cvtmulti_kernel(Segs9 s)
{
  const int seg = blockIdx.y;
  const int n4 = s.n4[seg];
  const float* __restrict__ in = s.in[seg];
  ushort* __restrict__ out = s.out[seg];
  for (int i = blockIdx.x * 256 + threadIdx.x; i < n4; i += gridDim.x * 256) {
    float4 v = ((const float4*)in)[i];
    ushort4 o;
    o.x = f2b(v.x); o.y = f2b(v.y); o.z = f2b(v.z); o.w = f2b(v.w);
    ((ushort4*)out)[i] = o;
  }
}

// ---------- batched tiled transpose+convert: in (R,C) f32 -> out (C,R) bf16
__global__ __launch_bounds__(256)
void tcvt_kernel(const float* __restrict__ in, ushort* __restrict__ out,
                 int R, int C, size_t inStride, size_t outStride)
{
  __shared__ float t[32][33];
  const int bt = blockIdx.z;
  const int r0 = blockIdx.y * 32, c0 = blockIdx.x * 32;
  const int tx = threadIdx.x & 31, ty = threadIdx.x >> 5;
  for (int i = ty; i < 32; i += 8)
    t[i][tx] = in[bt * inStride + (size_t)(r0 + i) * C + c0 + tx];
  __syncthreads();
  for (int i = ty; i < 32; i += 8)
    out[bt * outStride + (size_t)(c0 + i) * R + r0 + tx] = f2b(t[tx][i]);
}

// -------- w_rel[r](g,h) = sum_b comp[r,b]*basis[b](g,h) -> f32 temp --------
__global__ __launch_bounds__(256)
void wrel_kernel(const float* __restrict__ basis, const float* __restrict__ comp,
                 float* __restrict__ wrel)
{
  __shared__ float cs[240];
  const int tid = threadIdx.x;
  if (tid < 240) cs[tid] = comp[tid];
  __syncthreads();
  const int gh = blockIdx.x * 256 + tid;
  float acc[8] = {};
  for (int bb = 0; bb < 30; ++bb) {
    float v = basis[(size_t)bb * (G_ * H_) + gh];
#pragma unroll
    for (int r = 0; r < 8; ++r) acc[r] = fmaf(cs[r * 30 + bb], v, acc[r]);
  }
#pragma unroll
  for (int r = 0; r < 8; ++r) wrel[(size_t)r * (G_ * H_) + gh] = acc[r];
}

// -------- bias_comb: [0..2048)=0, [2048..2304)=rgcn_bias -------------------
__global__ void biascomb_kernel(const float* __restrict__ rb, float* __restrict__ bias)
{
  int i = blockIdx.x * 256 + threadIdx.x;
  if (i < 2304) bias[i] = (i < 2048) ? 0.f : rb[i - 2048];
}

// ===================== bf16 MFMA GEMM: C = A @ B^T (+bias)(+Cin)(relu) =====
template<bool BIAS, bool RELU, bool ACC, bool OUTF, bool OUTB>
__global__ __launch_bounds__(256)
void mgemm_kernel(const ushort* __restrict__ A, const ushort* __restrict__ B,
                  const float* __restrict__ bias, const float* __restrict__ Cin,
                  float* __restrict__ Cf, ushort* __restrict__ Cb,
                  int K, int lda, int ldb, int ldc)
{
  __shared__ ushort sA[128 * 64];
  __shared__ ushort sB[128 * 64];
  const int tid = threadIdx.x;
  const int w = tid >> 6, l = tid & 63;
  const int m0 = blockIdx.y * 128, n0 = blockIdx.x * 128;

  const int srow = l >> 3, sg = l & 7, rbase = w * 32;
  const int wr = w >> 1, wc = w & 1;
  const int lrow = l & 15, lk = l >> 4;
  const int xm = (l & 7) << 4;
  const int kb0 = (lk * 16) ^ xm;
  int aoff[4], boff[4];
#pragma unroll
  for (int i = 0; i < 4; ++i) {
    aoff[i] = (wr * 64 + i * 16 + lrow) * 128 + kb0;
    boff[i] = (wc * 64 + i * 16 + lrow) * 128 + kb0;
  }

  f32x4 acc[4][4];
#pragma unroll
  for (int i = 0; i < 4; ++i)
#pragma unroll
    for (int j = 0; j < 4; ++j) acc[i][j] = (f32x4){0.f, 0.f, 0.f, 0.f};

#define STAGE(k0)                                                              \
  {                                                                            \
    _Pragma("unroll")                                                          \
    for (int i = 0; i < 4; ++i) {                                              \
      const int trow = rbase + i * 8 + srow;                                   \
      const int koff = (sg * 8) ^ ((trow & 7) << 3);                           \
      const ushort* ga = A + (size_t)(m0 + trow) * lda + (k0) + koff;          \
      const ushort* gb = B + (size_t)(n0 + trow) * ldb + (k0) + koff;          \
      __builtin_amdgcn_global_load_lds(                                        \
          (const __attribute__((address_space(1))) void*)ga,                   \
          (__attribute__((address_space(3))) void*)&sA[(rbase + i * 8) * 64],  \
          16, 0, 0);                                                           \
      __builtin_amdgcn_global_load_lds(                                        \
          (const __attribute__((address_space(1))) void*)gb,                   \
          (__attribute__((address_space(3))) void*)&sB[(rbase + i * 8) * 64],  \
          16, 0, 0);                                                           \
    }                                                                          \
  }

  STAGE(0)
  for (int kt = 0;;) {
    __syncthreads();
#pragma unroll
    for (int h = 0; h < 2; ++h) {
      const int hx = h * 64;
      bf16x8 af[4], bfr[4];
#pragma unroll
      for (int i = 0; i < 4; ++i) {
        af[i]  = *(const bf16x8*)&sA[(aoff[i] ^ hx) >> 1];
        bfr[i] = *(const bf16x8*)&sB[(boff[i] ^ hx) >> 1];
      }
#pragma unroll
      for (int mi = 0; mi < 4; ++mi)
#pragma unroll
        for (int ni = 0; ni < 4; ++ni)
          acc[mi][ni] = __builtin_amdgcn_mfma_f32_16x16x32_bf16(
              af[mi], bfr[ni], acc[mi][ni], 0, 0, 0);
    }
    kt += 64;
    if (kt >= K) break;
    __syncthreads();
    STAGE(kt)
  }
#undef STAGE

  const int orow = m0 + wr * 64 + lk * 4;
  const int ocol = n0 + wc * 64 + lrow;
#pragma unroll
  for (int mi = 0; mi < 4; ++mi) {
#pragma unroll
    for (int r = 0; r < 4; ++r) {
      const int row = orow + mi * 16 + r;
#pragma unroll
      for (int ni = 0; ni < 4; ++ni) {
        const int col = ocol + ni * 16;
        float v = acc[mi][ni][r];
        if constexpr (ACC)  v += Cin[(size_t)row * ldc + col];
        if constexpr (BIAS) v += bias[col];
        if constexpr (RELU) v = fmaxf(v, 0.f);
        if constexpr (OUTF) Cf[(size_t)row * ldc + col] = v;
        if constexpr (OUTB) Cb[(size_t)row * ldc + col] = f2b(v);
      }
    }
  }
}

// -------- V transpose: qkvb V block (110x768) -> vt (768x128), pad 0 -------
__global__ __launch_bounds__(256)
void vtrans_kernel(const ushort* __restrict__ qkvb, ushort* __restrict__ vt)
{
  __shared__ ushort t[32][33];
  const int b = blockIdx.z;
  const int r0 = blockIdx.y * 32;   // V row (k), 0..127
  const int c0 = blockIdx.x * 32;   // V col (d), 0..767
  const int tx = threadIdx.x & 31, ty = threadIdx.x >> 5;
  for (int i = ty; i < 32; i += 8) {
    const int r = r0 + i;
    t[i][tx] = (r < L_) ? qkvb[((size_t)(b * L_) + r) * 2304 + 1536 + c0 + tx]
                        : (ushort)0;
  }
  __syncthreads();
  for (int i = ty; i < 32; i += 8)
    vt[((size_t)b * 768 + c0 + i) * 128 + r0 + tx] = t[tx][i];
}

// -------- MFMA attention: block = (16 q-rows, dialogue), 4 waves -----------
__global__ __launch_bounds__(256)
void attnM_kernel(const ushort* __restrict__ qkvb, const ushort* __restrict__ vt,
                  ushort* __restrict__ ctxb)
{
  const int b = blockIdx.y, qr0 = blockIdx.x * 16;
  const int tid = threadIdx.x, w = tid >> 6, l = tid & 63;
  __shared__ float  sS[16 * 128];
  __shared__ ushort sP[16 * 128];   // bf16, 16B-group XOR swizzle
  const int lrow = l & 15, lq = l >> 4;

  // ---- QK^T: wave w covers n-frags {2w, 2w+1} (7 frags over 112 cols) ----
  const ushort* Qbase = qkvb + ((size_t)(b * L_) + qr0 + lrow) * 2304 + lq * 8;
  f32x4 accS[2] = {{0.f,0.f,0.f,0.f},{0.f,0.f,0.f,0.f}};
  const int nf0 = w * 2;
  for (int k0 = 0; k0 < 768; k0 += 32) {
    bf16x8 aq = *(const bf16x8*)(Qbase + k0);
#pragma unroll
    for (int f = 0; f < 2; ++f) {
      const int nf = nf0 + f;
      if (nf < 7) {
        const ushort* Kp = qkvb + ((size_t)(b * L_) + nf * 16 + lrow) * 2304
                         + 768 + k0 + lq * 8;
        bf16x8 bk = *(const bf16x8*)Kp;
        accS[f] = __builtin_amdgcn_mfma_f32_16x16x32_bf16(aq, bk, accS[f], 0, 0, 0);
      }
    }
  }
  const float scale = 0.03608439182435161f;  // 1/sqrt(768)
#pragma unroll
  for (int f = 0; f < 2; ++f) {
    const int nf = nf0 + f;
    if (nf < 7) {
#pragma unroll
      for (int r = 0; r < 4; ++r)
        sS[(lq * 4 + r) * 128 + nf * 16 + lrow] = accS[f][r] * scale;
    }
  }
  __syncthreads();

  // ---- softmax: wave w -> rows 4w..4w+3, 16 lanes per row ----
  {
    const int row = w * 4 + lq;
    const int c0 = lrow;
    float m = -1e30f;
    for (int c = c0; c < L_; c += 16) m = fmaxf(m, sS[row * 128 + c]);
#pragma unroll
    for (int off = 8; off; off >>= 1) m = fmaxf(m, __shfl_xor(m, off));
    float pv[7];
    float sum = 0.f;
#pragma unroll
    for (int i = 0; i < 7; ++i) {
      const int c = c0 + i * 16;
      float e = (c < L_) ? __expf(sS[row * 128 + c] - m) : 0.f;
      pv[i] = e; sum += e;
    }
#pragma unroll
    for (int off = 8; off; off >>= 1) sum += __shfl_xor(sum, off);
    const float inv = 1.f / sum;
#pragma unroll
    for (int i = 0; i < 8; ++i) {
      const int c = c0 + i * 16;
      ushort pb = (i < 7 && c < L_) ? f2b(pv[i < 7 ? i : 0] * inv) : (ushort)0;
      const int g = (c >> 3) ^ (row & 7);
      sP[row * 128 + g * 8 + (c & 7)] = pb;
    }
  }
  __syncthreads();

  // ---- PV: wave w covers ctx cols [192w, 192w+192) = 12 frags, K=128 ----
  f32x4 accO[12];
#pragma unroll
  for (int i = 0; i < 12; ++i) accO[i] = (f32x4){0.f, 0.f, 0.f, 0.f};
#pragma unroll
  for (int ks = 0; ks < 4; ++ks) {
    const int k = ks * 32 + lq * 8;
    const int g = (k >> 3) ^ (lrow & 7);
    bf16x8 ap = *(const bf16x8*)&sP[lrow * 128 + g * 8];
#pragma unroll
    for (int i = 0; i < 12; ++i) {
      const int col = w * 192 + i * 16 + lrow;
      bf16x8 bv = *(const bf16x8*)(vt + ((size_t)b * 768 + col) * 128 + k);
      accO[i] = __builtin_amdgcn_mfma_f32_16x16x32_bf16(ap, bv, accO[i], 0, 0, 0);
    }
  }
#pragma unroll
  for (int i = 0; i < 12; ++i) {
    const int col = w * 192 + i * 16 + lrow;
#pragma unroll
    for (int r = 0; r < 4; ++r) {
      const int row = qr0 + lq * 4 + r;
      if (row < L_)
        ctxb[((size_t)b * L_ + row) * 768 + col] = f2b(accO[i][r]);
    }
  }
}

// ---------------- LayerNorm(A + Bres), writes f32 + bf16 -------------------
__global__ __launch_bounds__(256)
void ln_kernel(const float* __restrict__ A, const float* __restrict__ Bres,
               const float* __restrict__ g, const float* __restrict__ beta,
               float* __restrict__ out, ushort* __restrict__ outb)
{
  const int row = blockIdx.x, tid = threadIdx.x;
  const float* ap = A + (size_t)row * U_;
  const float* bp = Bres + (size_t)row * U_;
  float v0 = ap[tid] + bp[tid];
  float v1 = ap[tid + 256] + bp[tid + 256];
  float v2 = ap[tid + 512] + bp[tid + 512];
  float s = v0 + v1 + v2, sq = v0 * v0 + v1 * v1 + v2 * v2;
  __shared__ float red[8];
#pragma unroll
  for (int off = 32; off; off >>= 1) { s += __shfl_xor(s, off); sq += __shfl_xor(sq, off); }
  const int wave = tid >> 6, lane = tid & 63;
  if (lane == 0) { red[wave] = s; red[4 + wave] = sq; }
  __syncthreads();
  if (tid == 0) {
    float ts = red[0] + red[1] + red[2] + red[3];
    float tq = red[4] + red[5] + red[6] + red[7];
    float m = ts * (1.f / 768.f);
    float var = tq * (1.f / 768.f) - m * m;
    red[0] = m; red[1] = 1.f / sqrtf(var + 1e-5f);
  }
  __syncthreads();
  const float m = red[0], inv = red[1];
  float* op = out + (size_t)row * U_;
  ushort* ob = outb + (size_t)row * U_;
  float o0 = (v0 - m) * inv * g[tid] + beta[tid];
  float o1 = (v1 - m) * inv * g[tid + 256] + beta[tid + 256];
  float o2 = (v2 - m) * inv * g[tid + 512] + beta[tid + 512];
  op[tid] = o0; op[tid + 256] = o1; op[tid + 512] = o2;
  ob[tid] = f2b(o0); ob[tid + 256] = f2b(o1); ob[tid + 512] = f2b(o2);
}

// ---------------- windowed edge softmax -> edge_norm (bf16 feats) ----------
__global__ __launch_bounds__(256)
void edgeatt_kernel(const float* __restrict__ tmp, const ushort* __restrict__ featsb,
                    float* __restrict__ edge_norm)
{
  const int bj = blockIdx.x;
  const int b = bj / L_, j = bj - b * L_;
  const int k0 = max(0, j - 10), k1 = min(L_ - 1, j + 10);
  __shared__ float s[32];
  const int tid = threadIdx.x;
  const int wave = tid >> 6, lane = tid & 63;
  // per-lane slice of tmp row (512 = 64 lanes x 8)
  const float* tp = tmp + (size_t)bj * G_ + lane * 8;
  float tr[8];
#pragma unroll
  for (int i = 0; i < 8; ++i) tr[i] = tp[i];
  for (int k = k0 + wave; k <= k1; k += 4) {
    const ushort* fp = featsb + (size_t)(b * L_ + k) * G_ + lane * 8;
    bf16x8 v = *(const bf16x8*)fp;
    float sc = 0.f;
#pragma unroll
    for (int i = 0; i < 8; ++i) sc = fmaf(b2f((ushort)v[i]), tr[i], sc);
#pragma unroll
    for (int off = 32; off; off >>= 1) sc += __shfl_xor(sc, off);
    if (lane == 0) s[k - k0] = sc;
  }
  __syncthreads();
  if (tid == 0) {
    const int W = k1 - k0 + 1;
    float m = -1e30f;
    for (int t = 0; t < W; ++t) m = fmaxf(m, s[t]);
    float sum = 0.f;
    for (int t = 0; t < W; ++t) { float e = __expf(s[t] - m); s[t] = e; sum += e; }
    const float inv = 1.f / sum;
    const int base = b * EPB_ + edge_prefix(j);
    for (int t = 0; t < W; ++t) edge_norm[base + t] = s[t] * inv;
  }
}

// -------- RGCN gather (bf16 xcomb: [n][et*256+h], root at [n][2048+h]) -----
__global__ __launch_bounds__(256)
void rgcn_gather_kernel(const ushort* __restrict__ xcomb, const int* __restrict__ speaker,
                        float* __restrict__ h1, ushort* __restrict__ h1b)
{
  const int n = blockIdx.x;
  const int b = n / L_, k = n - b * L_;
  const int j0 = max(0, k - 10), j1 = min(L_ - 1, k + 10);
  __shared__ int spw[32];
  __shared__ int spk_s;
  const int tid = threadIdx.x;
  if (tid <= j1 - j0) spw[tid] = speaker[b * L_ + j0 + tid];
  if (tid == 0) spk_s = speaker[n];
  __syncthreads();
  const int spk = spk_s;
  float inv[4];
  {
    int cn[4] = {0, 0, 0, 0};
    for (int j = j0; j <= j1; ++j) cn[spw[j - j0] * 2 + (j >= k ? 1 : 0)]++;
#pragma unroll
    for (int q = 0; q < 4; ++q) inv[q] = cn[q] ? 1.f / (float)cn[q] : 0.f;
  }
  float acc = 0.f;
  for (int j = j0; j <= j1; ++j) {
    const int spj = spw[j - j0];
    const int c = (j >= k) ? 1 : 0;
    const int et = (spj * 2 + spk) * 2 + c;
    acc = fmaf(b2f(xcomb[(size_t)(b * L_ + j) * 2304 + et * 256 + tid]),
               inv[spj * 2 + c], acc);
  }
  const float hv = b2f(xcomb[(size_t)n * 2304 + 2048 + tid]) + acc;
  h1[(size_t)n * H_ + tid] = hv;
  h1b[(size_t)n * H_ + tid] = f2b(hv);
}

// ---------------- GraphConv gather -> bf16 agg -----------------------------
__global__ __launch_bounds__(256)
void gcn_gather_kernel(const float* __restrict__ edge_norm, const float* __restrict__ h1,
                       ushort* __restrict__ aggb)
{
  const int n = blockIdx.x;
  const int b = n / L_, k = n - b * L_;
  const int j0 = max(0, k - 10), j1 = min(L_ - 1, k + 10);
  __shared__ float en[32];
  const int tid = threadIdx.x;
  if (tid <= j1 - j0) {
    const int j = j0 + tid;
    const int e = b * EPB_ + edge_prefix(j) + (k - max(0, j - 10));
    en[tid] = edge_norm[e];
  }
  __syncthreads();
  float acc = 0.f;
  for (int j = j0; j <= j1; ++j)
    acc = fmaf(en[j - j0], h1[(size_t)(b * L_ + j) * H_ + tid], acc);
  aggb[(size_t)n * H_ + tid] = f2b(acc);
}

// ---------------- final tiny GEMM: out = hid @ clf2_w^T + clf2_b -----------
__global__ __launch_bounds__(256)
void clf2_kernel(const float* __restrict__ hid, const float* __restrict__ w,
                 const float* __restrict__ bias, float* __restrict__ out)
{
  __shared__ float wsm[7 * H_];
  const int tid = threadIdx.x;
  for (int i = tid; i < 7 * H_; i += 256) wsm[i] = w[i];
  __syncthreads();
  const int idx = blockIdx.x * 256 + threadIdx.x;
  if (idx < N_ * 7) {
    const int n = idx / 7, t = idx - n * 7;
    const float* hp = hid + (size_t)n * H_;
    const float* wp = wsm + t * H_;
    float acc = bias[t];
    for (int d = 0; d < H_; ++d) acc = fmaf(hp[d], wp[d], acc);
    out[idx] = acc;
  }
}

extern "C" void kernel_launch(void* const* d_in, const int* in_sizes, int n_in,
                              void* d_out, int out_size, void* d_ws, size_t ws_size,
                              hipStream_t stream)
{
  const float* x          = (const float*)d_in[0];
  const float* in_proj_w  = (const float*)d_in[1];
  const float* in_proj_b  = (const float*)d_in[2];
  const float* out_proj_w = (const float*)d_in[3];
  const float* out_proj_b = (const float*)d_in[4];
  const float* ln1_g      = (const float*)d_in[5];
  const float* ln1_b      = (const float*)d_in[6];
  const float* ff1_w      = (const float*)d_in[7];
  const float* ff1_b      = (const float*)d_in[8];
  const float* ff2_w      = (const float*)d_in[9];
  const float* ff2_b      = (const float*)d_in[10];
  const float* ln2_g      = (const float*)d_in[11];
  const float* ln2_b      = (const float*)d_in[12];
  const float* to_w       = (const float*)d_in[13];
  const float* to_b       = (const float*)d_in[14];
  const float* att_w      = (const float*)d_in[15];
  const float* rgcn_basis = (const float*)d_in[16];
  const float* rgcn_comp  = (const float*)d_in[17];
  const float* rgcn_root  = (const float*)d_in[18];
  const float* rgcn_bias  = (const float*)d_in[19];
  const float* gc_rel_w   = (const float*)d_in[20];
  const float* gc_rel_b   = (const float*)d_in[21];
  const float* gc_root_w  = (const float*)d_in[22];
  const float* clf1_w     = (const float*)d_in[23];
  const float* clf1_b     = (const float*)d_in[24];
  const float* clf2_w     = (const float*)d_in[25];
  const float* clf2_b     = (const float*)d_in[26];
  const int*   speaker    = (const int*)d_in[27];
  float* out = (float*)d_out;
  char* p = (char*)d_ws;

  // ---- workspace regions ----
  // R1 (65MB): wrelTmp f32 -> qkvb bf16 -> ff bf16 -> tmp f32 -> xcombB bf16
  float*  R1f    = (float*)p;
  ushort* R1b    = (ushort*)p;
  p += (size_t)N_ * 2304 * 4;
  // R2 (21.6MB): aproj -> ffo -> feats f32 ; tail: edge_norm
  float*  aproj = (float*)p;
  float*  ffo   = aproj;
  float*  feats = aproj;
  float*  en    = (float*)(p + (size_t)N_ * 512 * 4);
  p += (size_t)N_ * 768 * 4;
  // R3 (21.6MB): vt bf16 (attention) -> h f32 -> {h1, h2, hid}
  float*  hbuf  = (float*)p;
  ushort* vt    = (ushort*)p;                       // 64*768*128*2 = 12.6MB
  float*  h1    = hbuf;
  float*  h2    = (float*)(p + (size_t)N_ * 256 * 4);
  float*  hid   = (float*)(p + (size_t)N_ * 512 * 4);
  p += (size_t)N_ * 768 * 4;
  // R4 (10.8MB): xb -> ctxb
  ushort* xb    = (ushort*)p;
  ushort* ctxb  = xb;
  p += (size_t)N_ * 768 * 2;
  // R5 (10.8MB): hb -> {h1b, aggb, h2b}
  ushort* hb    = (ushort*)p;
  ushort* h1b   = hb;
  ushort* aggb  = (ushort*)(p + (size_t)N_ * 256 * 2);
  ushort* h2b   = (ushort*)(p + (size_t)N_ * 512 * 2);
  p += (size_t)N_ * 768 * 2;
  // R6 (7.2MB): featsb
  ushort* featsb = (ushort*)p; p += (size_t)N_ * 512 * 2;
  // R7: bf16 weights
  ushort* in_projb = (ushort*)p; p += (size_t)2304 * 768 * 2;
  ushort* out_projb= (ushort*)p; p += (size_t)768 * 768 * 2;
  ushort* ff1b     = (ushort*)p; p += (size_t)2048 * 768 * 2;
  ushort* ff2b     = (ushort*)p; p += (size_t)768 * 2048 * 2;
  ushort* tob      = (ushort*)p; p += (size_t)512 * 768 * 2;
  ushort* attwb    = (ushort*)p; p += (size_t)512 * 512 * 2;
  ushort* wcomb    = (ushort*)p; p += (size_t)2304 * 512 * 2;
  ushort* gcrelb   = (ushort*)p; p += (size_t)256 * 256 * 2;
  ushort* gcrootb  = (ushort*)p; p += (size_t)256 * 256 * 2;
  ushort* clf1b16  = (ushort*)p; p += (size_t)256 * 768 * 2;
  float*  bias_comb= (float*)p;  p += 2304 * 4;
  float*  wrelTmp  = R1f;   // consumed before qkv GEMM

  // ---- weight/input prep (one fused convert + 3 transposes + wrel) ----
  Segs9 segs;
  segs.in[0] = x;          segs.out[0] = xb;        segs.n4[0] = N_ * 768 / 4;
  segs.in[1] = in_proj_w;  segs.out[1] = in_projb;  segs.n4[1] = 2304 * 768 / 4;
  segs.in[2] = out_proj_w; segs.out[2] = out_projb; segs.n4[2] = 768 * 768 / 4;
  segs.in[3] = ff1_w;      segs.out[3] = ff1b;      segs.n4[3] = 2048 * 768 / 4;
  segs.in[4] = ff2_w;      segs.out[4] = ff2b;      segs.n4[4] = 768 * 2048 / 4;
  segs.in[5] = to_w;       segs.out[5] = tob;       segs.n4[5] = 512 * 768 / 4;
  segs.in[6] = gc_rel_w;   segs.out[6] = gcrelb;    segs.n4[6] = 256 * 256 / 4;
  // gc_root: reference does h1 @ gc_root_w.T; mgemm computes A @ B^T -> as-is
  segs.in[7] = gc_root_w;  segs.out[7] = gcrootb;   segs.n4[7] = 256 * 256 / 4;
  segs.in[8] = clf1_w;     segs.out[8] = clf1b16;   segs.n4[8] = 256 * 768 / 4;
  cvtmulti_kernel<<<dim3(768, 9), 256, 0, stream>>>(segs);
  tcvt_kernel<<<dim3(16, 16, 1), 256, 0, stream>>>(att_w, attwb, 512, 512, 0, 0);
  wrel_kernel<<<512, 256, 0, stream>>>(rgcn_basis, rgcn_comp, wrelTmp);
  tcvt_kernel<<<dim3(8, 16, 8), 256, 0, stream>>>(wrelTmp, wcomb, 512, 256,
                                                  (size_t)512 * 256, (size_t)256 * 512);
  tcvt_kernel<<<dim3(8, 16, 1), 256, 0, stream>>>(rgcn_root, wcomb + (size_t)2048 * 512,
                                                  512, 256, 0, 0);
  biascomb_kernel<<<9, 256, 0, stream>>>(rgcn_bias, bias_comb);

  // ---- main pipeline ----
  // qkvb = bf16(x @ in_proj^T + b)
  mgemm_kernel<true, false, false, false, true><<<dim3(18, 55), 256, 0, stream>>>(
      xb, in_projb, in_proj_b, nullptr, nullptr, R1b, 768, 768, 768, 2304);
  vtrans_kernel<<<dim3(24, 4, 64), 256, 0, stream>>>(R1b, vt);
  attnM_kernel<<<dim3(7, 64), 256, 0, stream>>>(R1b, vt, ctxb);
  // aproj = ctx @ out_proj^T + b
  mgemm_kernel<true, false, false, true, false><<<dim3(6, 55), 256, 0, stream>>>(
      ctxb, out_projb, out_proj_b, nullptr, aproj, nullptr, 768, 768, 768, 768);
  ln_kernel<<<N_, 256, 0, stream>>>(x, aproj, ln1_g, ln1_b, hbuf, hb);
  // ff = relu(h @ ff1^T + b)  (bf16)
  mgemm_kernel<true, true, false, false, true><<<dim3(16, 55), 256, 0, stream>>>(
      hb, ff1b, ff1_b, nullptr, nullptr, R1b, 768, 768, 768, 2048);
  // ffo = ff @ ff2^T + b
  mgemm_kernel<true, false, false, true, false><<<dim3(6, 55), 256, 0, stream>>>(
      R1b, ff2b, ff2_b, nullptr, ffo, nullptr, 2048, 2048, 2048, 768);
  ln_kernel<<<N_, 256, 0, stream>>>(hbuf, ffo, ln2_g, ln2_b, hbuf, hb);
  // feats = h @ to^T + b  (f32 + bf16)
  mgemm_kernel<true, false, false, true, true><<<dim3(4, 55), 256, 0, stream>>>(
      hb, tob, to_b, nullptr, feats, featsb, 768, 768, 768, 512);
  // tmp = feats @ att_w  -> R1f
  mgemm_kernel<false, false, false, true, false><<<dim3(4, 55), 256, 0, stream>>>(
      featsb, attwb, nullptr, nullptr, R1f, nullptr, 512, 512, 512, 512);
  edgeatt_kernel<<<N_, 256, 0, stream>>>(R1f, featsb, en);
  // xcombB = bf16(feats @ [wrel_t | root_t]^T + bias_comb)
  mgemm_kernel<true, false, false, false, true><<<dim3(18, 55), 256, 0, stream>>>(
      featsb, wcomb, bias_comb, nullptr, nullptr, R1b, 512, 512, 512, 2304);
  rgcn_gather_kernel<<<N_, 256, 0, stream>>>(R1b, speaker, h1, h1b);
  gcn_gather_kernel<<<N_, 256, 0, stream>>>(en, h1, aggb);
  // h2 = agg @ gc_rel^T + b
  mgemm_kernel<true, false, false, true, false><<<dim3(2, 55), 256, 0, stream>>>(
      aggb, gcrelb, gc_rel_b, nullptr, h2, nullptr, 256, 256, 256, 256);
  // h2b = bf16(h2 + h1 @ gc_root^T)
  mgemm_kernel<false, false, true, false, true><<<dim3(2, 55), 256, 0, stream>>>(
      h1b, gcrootb, nullptr, h2, nullptr, h2b, 256, 256, 256, 256);
  // hid = feats @ clf1[:, :512]^T
  mgemm_kernel<false, false, false, true, false><<<dim3(2, 55), 256, 0, stream>>>(
      featsb, clf1b16, nullptr, nullptr, hid, nullptr, 512, 512, 768, 256);
  // hid = relu(hid + h2 @ clf1[:, 512:]^T + b)
  mgemm_kernel<true, true, true, true, false><<<dim3(2, 55), 256, 0, stream>>>(
      h2b, clf1b16 + 512, clf1_b, hid, hid, nullptr, 256, 256, 768, 256);
  clf2_kernel<<<(N_ * 7 + 255) / 256, 256, 0, stream>>>(hid, clf2_w, clf2_b, out);
}

// Round 5
// 381.395 us; speedup vs baseline: 6.0478x; 1.1361x over previous
//
#include <hip/hip_runtime.h>
#include <hip/hip_bf16.h>
#include <math.h>

#define L_   110
#define B_   64
#define N_   7040
#define U_   768
#define G_   512
#define H_   256
#define FF_  2048
#define EPB_ 2200

typedef __attribute__((ext_vector_type(4))) float f32x4;
typedef __attribute__((ext_vector_type(8))) short bf16x8;

__device__ __forceinline__ ushort f2b(float f) {
  union { __hip_bfloat16 h; ushort u; } cv;
  cv.h = __float2bfloat16(f);
  return cv.u;
}
__device__ __forceinline__ float b2f(ushort u) {
  union { float f; unsigned int i; } cv; cv.i = ((unsigned int)u) << 16; return cv.f;
}

// prefix(j) = number of edges with src-row j' < j within one dialogue
__device__ __forceinline__ int edge_prefix(int j) {
  if (j <= 10)  return j * 11 + (j * (j - 1)) / 2;
  if (j <= 100) return 155 + (j - 10) * 21;
  return 2045 + ((141 - j) * (j - 100)) / 2;
}

// ------------- multi-segment f32->bf16 convert (one launch for 7 arrays) ---
struct Segs7 { const float* in[7]; ushort* out[7]; int n4[7]; };

__global__ __launch_bounds__(256)
void cvtmulti_kernel(Segs7 s)
{
  const int seg = blockIdx.y;
  const int n4 = s.n4[seg];
  const float* __restrict__ in = s.in[seg];
  ushort* __restrict__ out = s.out[seg];
  for (int i = blockIdx.x * 256 + threadIdx.x; i < n4; i += gridDim.x * 256) {
    float4 v = ((const float4*)in)[i];
    ushort4 o;
    o.x = f2b(v.x); o.y = f2b(v.y); o.z = f2b(v.z); o.w = f2b(v.w);
    ((ushort4*)out)[i] = o;
  }
}

// ---------- batched tiled transpose+convert: in (R,C) f32 -> out (C,R) bf16
__global__ __launch_bounds__(256)
void tcvt_kernel(const float* __restrict__ in, ushort* __restrict__ out,
                 int R, int C, size_t inStride, size_t outStride)
{
  __shared__ float t[32][33];
  const int bt = blockIdx.z;
  const int r0 = blockIdx.y * 32, c0 = blockIdx.x * 32;
  const int tx = threadIdx.x & 31, ty = threadIdx.x >> 5;
  for (int i = ty; i < 32; i += 8)
    t[i][tx] = in[bt * inStride + (size_t)(r0 + i) * C + c0 + tx];
  __syncthreads();
  for (int i = ty; i < 32; i += 8)
    out[bt * outStride + (size_t)(c0 + i) * R + r0 + tx] = f2b(t[tx][i]);
}

// -------- w_rel[r](g,h) = sum_b comp[r,b]*basis[b](g,h) -> f32 temp --------
__global__ __launch_bounds__(256)
void wrel_kernel(const float* __restrict__ basis, const float* __restrict__ comp,
                 float* __restrict__ wrel)
{
  __shared__ float cs[240];
  const int tid = threadIdx.x;
  if (tid < 240) cs[tid] = comp[tid];
  __syncthreads();
  const int gh = blockIdx.x * 256 + tid;
  float acc[8] = {};
  for (int bb = 0; bb < 30; ++bb) {
    float v = basis[(size_t)bb * (G_ * H_) + gh];
#pragma unroll
    for (int r = 0; r < 8; ++r) acc[r] = fmaf(cs[r * 30 + bb], v, acc[r]);
  }
#pragma unroll
  for (int r = 0; r < 8; ++r) wrel[(size_t)r * (G_ * H_) + gh] = acc[r];
}

// -------- bias_comb: [0..2048)=0, [2048..2304)=rgcn_bias -------------------
__global__ void biascomb_kernel(const float* __restrict__ rb, float* __restrict__ bias)
{
  int i = blockIdx.x * 256 + threadIdx.x;
  if (i < 2304) bias[i] = (i < 2048) ? 0.f : rb[i - 2048];
}

// -------- gccat: row i = [gc_rel_w[i] | gc_root_w[i]]  (256 x 512 bf16) ----
__global__ __launch_bounds__(256)
void gccat_kernel(const float* __restrict__ rel, const float* __restrict__ root,
                  ushort* __restrict__ outp)
{
  int i = blockIdx.x * 256 + threadIdx.x;   // 65536 total
  const int r = i >> 8, c = i & 255;
  outp[(size_t)r * 512 + c]       = f2b(rel[i]);
  outp[(size_t)r * 512 + 256 + c] = f2b(root[i]);
}

// ===================== bf16 MFMA GEMM: C = A @ B^T (+bias)(+Cin)(relu) =====
template<bool BIAS, bool RELU, bool ACC, bool OUTF, bool OUTB>
__global__ __launch_bounds__(256)
void mgemm_kernel(const ushort* __restrict__ A, const ushort* __restrict__ B,
                  const float* __restrict__ bias, const float* __restrict__ Cin,
                  float* __restrict__ Cf, ushort* __restrict__ Cb,
                  int K, int lda, int ldb, int ldc)
{
  __shared__ ushort sA[128 * 64];
  __shared__ ushort sB[128 * 64];
  const int tid = threadIdx.x;
  const int w = tid >> 6, l = tid & 63;
  const int m0 = blockIdx.y * 128, n0 = blockIdx.x * 128;

  const int srow = l >> 3, sg = l & 7, rbase = w * 32;
  const int wr = w >> 1, wc = w & 1;
  const int lrow = l & 15, lk = l >> 4;
  const int xm = (l & 7) << 4;
  const int kb0 = (lk * 16) ^ xm;
  int aoff[4], boff[4];
#pragma unroll
  for (int i = 0; i < 4; ++i) {
    aoff[i] = (wr * 64 + i * 16 + lrow) * 128 + kb0;
    boff[i] = (wc * 64 + i * 16 + lrow) * 128 + kb0;
  }

  f32x4 acc[4][4];
#pragma unroll
  for (int i = 0; i < 4; ++i)
#pragma unroll
    for (int j = 0; j < 4; ++j) acc[i][j] = (f32x4){0.f, 0.f, 0.f, 0.f};

#define STAGE(k0)                                                              \
  {                                                                            \
    _Pragma("unroll")                                                          \
    for (int i = 0; i < 4; ++i) {                                              \
      const int trow = rbase + i * 8 + srow;                                   \
      const int koff = (sg * 8) ^ ((trow & 7) << 3);                           \
      const ushort* ga = A + (size_t)(m0 + trow) * lda + (k0) + koff;          \
      const ushort* gb = B + (size_t)(n0 + trow) * ldb + (k0) + koff;          \
      __builtin_amdgcn_global_load_lds(                                        \
          (const __attribute__((address_space(1))) void*)ga,                   \
          (__attribute__((address_space(3))) void*)&sA[(rbase + i * 8) * 64],  \
          16, 0, 0);                                                           \
      __builtin_amdgcn_global_load_lds(                                        \
          (const __attribute__((address_space(1))) void*)gb,                   \
          (__attribute__((address_space(3))) void*)&sB[(rbase + i * 8) * 64],  \
          16, 0, 0);                                                           \
    }                                                                          \
  }

  STAGE(0)
  for (int kt = 0;;) {
    __syncthreads();
#pragma unroll
    for (int h = 0; h < 2; ++h) {
      const int hx = h * 64;
      bf16x8 af[4], bfr[4];
#pragma unroll
      for (int i = 0; i < 4; ++i) {
        af[i]  = *(const bf16x8*)&sA[(aoff[i] ^ hx) >> 1];
        bfr[i] = *(const bf16x8*)&sB[(boff[i] ^ hx) >> 1];
      }
#pragma unroll
      for (int mi = 0; mi < 4; ++mi)
#pragma unroll
        for (int ni = 0; ni < 4; ++ni)
          acc[mi][ni] = __builtin_amdgcn_mfma_f32_16x16x32_bf16(
              af[mi], bfr[ni], acc[mi][ni], 0, 0, 0);
    }
    kt += 64;
    if (kt >= K) break;
    __syncthreads();
    STAGE(kt)
  }
#undef STAGE

  const int orow = m0 + wr * 64 + lk * 4;
  const int ocol = n0 + wc * 64 + lrow;
#pragma unroll
  for (int mi = 0; mi < 4; ++mi) {
#pragma unroll
    for (int r = 0; r < 4; ++r) {
      const int row = orow + mi * 16 + r;
#pragma unroll
      for (int ni = 0; ni < 4; ++ni) {
        const int col = ocol + ni * 16;
        float v = acc[mi][ni][r];
        if constexpr (ACC)  v += Cin[(size_t)row * ldc + col];
        if constexpr (BIAS) v += bias[col];
        if constexpr (RELU) v = fmaxf(v, 0.f);
        if constexpr (OUTF) Cf[(size_t)row * ldc + col] = v;
        if constexpr (OUTB) Cb[(size_t)row * ldc + col] = f2b(v);
      }
    }
  }
}

// -------- V transpose: qkvb V block (110x768) -> vt (768x128), pad 0 -------
__global__ __launch_bounds__(256)
void vtrans_kernel(const ushort* __restrict__ qkvb, ushort* __restrict__ vt)
{
  __shared__ ushort t[32][33];
  const int b = blockIdx.z;
  const int r0 = blockIdx.y * 32;   // V row (k), 0..127
  const int c0 = blockIdx.x * 32;   // V col (d), 0..767
  const int tx = threadIdx.x & 31, ty = threadIdx.x >> 5;
  for (int i = ty; i < 32; i += 8) {
    const int r = r0 + i;
    t[i][tx] = (r < L_) ? qkvb[((size_t)(b * L_) + r) * 2304 + 1536 + c0 + tx]
                        : (ushort)0;
  }
  __syncthreads();
  for (int i = ty; i < 32; i += 8)
    vt[((size_t)b * 768 + c0 + i) * 128 + r0 + tx] = t[tx][i];
}

// -------- MFMA attention: block = (16 q-rows, dialogue), 4 waves -----------
__global__ __launch_bounds__(256)
void attnM_kernel(const ushort* __restrict__ qkvb, const ushort* __restrict__ vt,
                  ushort* __restrict__ ctxb)
{
  const int b = blockIdx.y, qr0 = blockIdx.x * 16;
  const int tid = threadIdx.x, w = tid >> 6, l = tid & 63;
  __shared__ float  sS[16 * 128];
  __shared__ ushort sP[16 * 128];   // bf16, 16B-group XOR swizzle
  const int lrow = l & 15, lq = l >> 4;

  // ---- QK^T: wave w covers n-frags {2w, 2w+1} (7 frags over 112 cols) ----
  const ushort* Qbase = qkvb + ((size_t)(b * L_) + qr0 + lrow) * 2304 + lq * 8;
  f32x4 accS[2] = {{0.f,0.f,0.f,0.f},{0.f,0.f,0.f,0.f}};
  const int nf0 = w * 2;
  for (int k0 = 0; k0 < 768; k0 += 32) {
    bf16x8 aq = *(const bf16x8*)(Qbase + k0);
#pragma unroll
    for (int f = 0; f < 2; ++f) {
      const int nf = nf0 + f;
      if (nf < 7) {
        const ushort* Kp = qkvb + ((size_t)(b * L_) + nf * 16 + lrow) * 2304
                         + 768 + k0 + lq * 8;
        bf16x8 bk = *(const bf16x8*)Kp;
        accS[f] = __builtin_amdgcn_mfma_f32_16x16x32_bf16(aq, bk, accS[f], 0, 0, 0);
      }
    }
  }
  const float scale = 0.03608439182435161f;  // 1/sqrt(768)
#pragma unroll
  for (int f = 0; f < 2; ++f) {
    const int nf = nf0 + f;
    if (nf < 7) {
#pragma unroll
      for (int r = 0; r < 4; ++r)
        sS[(lq * 4 + r) * 128 + nf * 16 + lrow] = accS[f][r] * scale;
    }
  }
  __syncthreads();

  // ---- softmax: wave w -> rows 4w..4w+3, 16 lanes per row ----
  {
    const int row = w * 4 + lq;
    const int c0 = lrow;
    float m = -1e30f;
    for (int c = c0; c < L_; c += 16) m = fmaxf(m, sS[row * 128 + c]);
#pragma unroll
    for (int off = 8; off; off >>= 1) m = fmaxf(m, __shfl_xor(m, off));
    float pv[7];
    float sum = 0.f;
#pragma unroll
    for (int i = 0; i < 7; ++i) {
      const int c = c0 + i * 16;
      float e = (c < L_) ? __expf(sS[row * 128 + c] - m) : 0.f;
      pv[i] = e; sum += e;
    }
#pragma unroll
    for (int off = 8; off; off >>= 1) sum += __shfl_xor(sum, off);
    const float inv = 1.f / sum;
#pragma unroll
    for (int i = 0; i < 8; ++i) {
      const int c = c0 + i * 16;
      ushort pb = (i < 7 && c < L_) ? f2b(pv[i < 7 ? i : 0] * inv) : (ushort)0;
      const int g = (c >> 3) ^ (row & 7);
      sP[row * 128 + g * 8 + (c & 7)] = pb;
    }
  }
  __syncthreads();

  // ---- PV: wave w covers ctx cols [192w, 192w+192) = 12 frags, K=128 ----
  f32x4 accO[12];
#pragma unroll
  for (int i = 0; i < 12; ++i) accO[i] = (f32x4){0.f, 0.f, 0.f, 0.f};
#pragma unroll
  for (int ks = 0; ks < 4; ++ks) {
    const int k = ks * 32 + lq * 8;
    const int g = (k >> 3) ^ (lrow & 7);
    bf16x8 ap = *(const bf16x8*)&sP[lrow * 128 + g * 8];
#pragma unroll
    for (int i = 0; i < 12; ++i) {
      const int col = w * 192 + i * 16 + lrow;
      bf16x8 bv = *(const bf16x8*)(vt + ((size_t)b * 768 + col) * 128 + k);
      accO[i] = __builtin_amdgcn_mfma_f32_16x16x32_bf16(ap, bv, accO[i], 0, 0, 0);
    }
  }
#pragma unroll
  for (int i = 0; i < 12; ++i) {
    const int col = w * 192 + i * 16 + lrow;
#pragma unroll
    for (int r = 0; r < 4; ++r) {
      const int row = qr0 + lq * 4 + r;
      if (row < L_)
        ctxb[((size_t)b * L_ + row) * 768 + col] = f2b(accO[i][r]);
    }
  }
}

// ---------------- LayerNorm(A + Bres), writes f32 + bf16 -------------------
__global__ __launch_bounds__(256)
void ln_kernel(const float* __restrict__ A, const float* __restrict__ Bres,
               const float* __restrict__ g, const float* __restrict__ beta,
               float* __restrict__ out, ushort* __restrict__ outb)
{
  const int row = blockIdx.x, tid = threadIdx.x;
  const float* ap = A + (size_t)row * U_;
  const float* bp = Bres + (size_t)row * U_;
  float v0 = ap[tid] + bp[tid];
  float v1 = ap[tid + 256] + bp[tid + 256];
  float v2 = ap[tid + 512] + bp[tid + 512];
  float s = v0 + v1 + v2, sq = v0 * v0 + v1 * v1 + v2 * v2;
  __shared__ float red[8];
#pragma unroll
  for (int off = 32; off; off >>= 1) { s += __shfl_xor(s, off); sq += __shfl_xor(sq, off); }
  const int wave = tid >> 6, lane = tid & 63;
  if (lane == 0) { red[wave] = s; red[4 + wave] = sq; }
  __syncthreads();
  if (tid == 0) {
    float ts = red[0] + red[1] + red[2] + red[3];
    float tq = red[4] + red[5] + red[6] + red[7];
    float m = ts * (1.f / 768.f);
    float var = tq * (1.f / 768.f) - m * m;
    red[0] = m; red[1] = 1.f / sqrtf(var + 1e-5f);
  }
  __syncthreads();
  const float m = red[0], inv = red[1];
  float* op = out + (size_t)row * U_;
  ushort* ob = outb + (size_t)row * U_;
  float o0 = (v0 - m) * inv * g[tid] + beta[tid];
  float o1 = (v1 - m) * inv * g[tid + 256] + beta[tid + 256];
  float o2 = (v2 - m) * inv * g[tid + 512] + beta[tid + 512];
  op[tid] = o0; op[tid + 256] = o1; op[tid + 512] = o2;
  ob[tid] = f2b(o0); ob[tid + 256] = f2b(o1); ob[tid + 512] = f2b(o2);
}

// ------ windowed edge softmax -> edge_norm (bf16 feats in fcat, ld 768) ----
__global__ __launch_bounds__(256)
void edgeatt_kernel(const float* __restrict__ tmp, const ushort* __restrict__ fcat,
                    float* __restrict__ edge_norm)
{
  const int bj = blockIdx.x;
  const int b = bj / L_, j = bj - b * L_;
  const int k0 = max(0, j - 10), k1 = min(L_ - 1, j + 10);
  __shared__ float s[32];
  const int tid = threadIdx.x;
  const int wave = tid >> 6, lane = tid & 63;
  const float* tp = tmp + (size_t)bj * G_ + lane * 8;
  float tr[8];
#pragma unroll
  for (int i = 0; i < 8; ++i) tr[i] = tp[i];
  for (int k = k0 + wave; k <= k1; k += 4) {
    const ushort* fp = fcat + (size_t)(b * L_ + k) * 768 + lane * 8;
    bf16x8 v = *(const bf16x8*)fp;
    float sc = 0.f;
#pragma unroll
    for (int i = 0; i < 8; ++i) sc = fmaf(b2f((ushort)v[i]), tr[i], sc);
#pragma unroll
    for (int off = 32; off; off >>= 1) sc += __shfl_xor(sc, off);
    if (lane == 0) s[k - k0] = sc;
  }
  __syncthreads();
  if (tid == 0) {
    const int W = k1 - k0 + 1;
    float m = -1e30f;
    for (int t = 0; t < W; ++t) m = fmaxf(m, s[t]);
    float sum = 0.f;
    for (int t = 0; t < W; ++t) { float e = __expf(s[t] - m); s[t] = e; sum += e; }
    const float inv = 1.f / sum;
    const int base = b * EPB_ + edge_prefix(j);
    for (int t = 0; t < W; ++t) edge_norm[base + t] = s[t] * inv;
  }
}

// -------- RGCN gather, vectorized: 8 nodes/block, 32 lanes/node, bf16x8 ----
// writes h1 (bf16) into catb[n][256:512] (row stride 512)
__global__ __launch_bounds__(256)
void rgcn_gather2_kernel(const ushort* __restrict__ xcomb,
                         const int* __restrict__ speaker,
                         ushort* __restrict__ catb)
{
  const int tid = threadIdx.x;
  const int n = blockIdx.x * 8 + (tid >> 5);
  const int lane = tid & 31;
  const int b = n / L_, k = n - b * L_;
  const int j0 = max(0, k - 10), j1 = min(L_ - 1, k + 10);
  const int spk = speaker[n];
  float inv[4];
  {
    int cn[4] = {0, 0, 0, 0};
    for (int j = j0; j <= j1; ++j)
      cn[speaker[b * L_ + j] * 2 + (j >= k ? 1 : 0)]++;
#pragma unroll
    for (int q = 0; q < 4; ++q) inv[q] = cn[q] ? 1.f / (float)cn[q] : 0.f;
  }
  float acc[8] = {};
  for (int j = j0; j <= j1; ++j) {
    const int spj = speaker[b * L_ + j];
    const int c = (j >= k) ? 1 : 0;
    const int et = (spj * 2 + spk) * 2 + c;
    const float w = inv[spj * 2 + c];
    bf16x8 v = *(const bf16x8*)&xcomb[(size_t)(b * L_ + j) * 2304 + et * 256 + lane * 8];
#pragma unroll
    for (int i = 0; i < 8; ++i) acc[i] = fmaf(b2f((ushort)v[i]), w, acc[i]);
  }
  bf16x8 rt = *(const bf16x8*)&xcomb[(size_t)n * 2304 + 2048 + lane * 8];
  bf16x8 o;
#pragma unroll
  for (int i = 0; i < 8; ++i) o[i] = (short)f2b(acc[i] + b2f((ushort)rt[i]));
  *(bf16x8*)&catb[(size_t)n * 512 + 256 + lane * 8] = o;
}

// -------- GraphConv gather, vectorized: reads h1 bf16 (catb[:,256:512]),
//          writes agg bf16 into catb[:,0:256] ------------------------------
__global__ __launch_bounds__(256)
void gcn_gather2_kernel(const float* __restrict__ edge_norm,
                        ushort* __restrict__ catb)
{
  const int tid = threadIdx.x;
  const int n = blockIdx.x * 8 + (tid >> 5);
  const int lane = tid & 31;
  const int b = n / L_, k = n - b * L_;
  const int j0 = max(0, k - 10), j1 = min(L_ - 1, k + 10);
  float acc[8] = {};
  for (int j = j0; j <= j1; ++j) {
    const float w = edge_norm[b * EPB_ + edge_prefix(j) + (k - max(0, j - 10))];
    bf16x8 v = *(const bf16x8*)&catb[(size_t)(b * L_ + j) * 512 + 256 + lane * 8];
#pragma unroll
    for (int i = 0; i < 8; ++i) acc[i] = fmaf(b2f((ushort)v[i]), w, acc[i]);
  }
  bf16x8 o;
#pragma unroll
  for (int i = 0; i < 8; ++i) o[i] = (short)f2b(acc[i]);
  *(bf16x8*)&catb[(size_t)n * 512 + lane * 8] = o;
}

// ---------------- final tiny GEMM: out = hid @ clf2_w^T + clf2_b -----------
__global__ __launch_bounds__(256)
void clf2_kernel(const float* __restrict__ hid, const float* __restrict__ w,
                 const float* __restrict__ bias, float* __restrict__ out)
{
  __shared__ float wsm[7 * H_];
  const int tid = threadIdx.x;
  for (int i = tid; i < 7 * H_; i += 256) wsm[i] = w[i];
  __syncthreads();
  const int idx = blockIdx.x * 256 + threadIdx.x;
  if (idx < N_ * 7) {
    const int n = idx / 7, t = idx - n * 7;
    const float* hp = hid + (size_t)n * H_;
    const float* wp = wsm + t * H_;
    float acc = bias[t];
    for (int d = 0; d < H_; ++d) acc = fmaf(hp[d], wp[d], acc);
    out[idx] = acc;
  }
}

extern "C" void kernel_launch(void* const* d_in, const int* in_sizes, int n_in,
                              void* d_out, int out_size, void* d_ws, size_t ws_size,
                              hipStream_t stream)
{
  const float* x          = (const float*)d_in[0];
  const float* in_proj_w  = (const float*)d_in[1];
  const float* in_proj_b  = (const float*)d_in[2];
  const float* out_proj_w = (const float*)d_in[3];
  const float* out_proj_b = (const float*)d_in[4];
  const float* ln1_g      = (const float*)d_in[5];
  const float* ln1_b      = (const float*)d_in[6];
  const float* ff1_w      = (const float*)d_in[7];
  const float* ff1_b      = (const float*)d_in[8];
  const float* ff2_w      = (const float*)d_in[9];
  const float* ff2_b      = (const float*)d_in[10];
  const float* ln2_g      = (const float*)d_in[11];
  const float* ln2_b      = (const float*)d_in[12];
  const float* to_w       = (const float*)d_in[13];
  const float* to_b       = (const float*)d_in[14];
  const float* att_w      = (const float*)d_in[15];
  const float* rgcn_basis = (const float*)d_in[16];
  const float* rgcn_comp  = (const float*)d_in[17];
  const float* rgcn_root  = (const float*)d_in[18];
  const float* rgcn_bias  = (const float*)d_in[19];
  const float* gc_rel_w   = (const float*)d_in[20];
  const float* gc_rel_b   = (const float*)d_in[21];
  const float* gc_root_w  = (const float*)d_in[22];
  const float* clf1_w     = (const float*)d_in[23];
  const float* clf1_b     = (const float*)d_in[24];
  const float* clf2_w     = (const float*)d_in[25];
  const float* clf2_b     = (const float*)d_in[26];
  const int*   speaker    = (const int*)d_in[27];
  float* out = (float*)d_out;
  char* p = (char*)d_ws;

  // ---- workspace regions ----
  // R1 (65MB): wrelTmp f32 -> qkvb bf16 -> ff bf16 -> tmp f32 -> xcombB bf16
  float*  R1f    = (float*)p;
  ushort* R1b    = (ushort*)p;
  p += (size_t)N_ * 2304 * 4;
  // R2 (21.6MB): aproj -> ffo f32 ; tail reused for edge_norm after ln2
  float*  aproj = (float*)p;
  float*  ffo   = aproj;
  float*  en    = (float*)(p + (size_t)N_ * 512 * 4);
  p += (size_t)N_ * 768 * 4;
  // R3 (21.6MB): vt bf16 (attn) -> hbuf f32 -> hid f32
  float*  hbuf  = (float*)p;
  ushort* vt    = (ushort*)p;
  float*  hid   = (float*)p;
  p += (size_t)N_ * 768 * 4;
  // R4 (10.8MB): xb -> ctxb
  ushort* xb    = (ushort*)p;
  ushort* ctxb  = xb;
  p += (size_t)N_ * 768 * 2;
  // R5 (10.8MB): hb bf16 (N x 768) -> catb bf16 (N x 512: [agg | h1])
  ushort* hb    = (ushort*)p;
  ushort* catb  = hb;
  p += (size_t)N_ * 768 * 2;
  // R6 (10.8MB): fcat bf16 (N x 768: [feats | h2])
  ushort* fcat  = (ushort*)p; p += (size_t)N_ * 768 * 2;
  // R7: bf16 weights
  ushort* in_projb = (ushort*)p; p += (size_t)2304 * 768 * 2;
  ushort* out_projb= (ushort*)p; p += (size_t)768 * 768 * 2;
  ushort* ff1b     = (ushort*)p; p += (size_t)2048 * 768 * 2;
  ushort* ff2b     = (ushort*)p; p += (size_t)768 * 2048 * 2;
  ushort* tob      = (ushort*)p; p += (size_t)512 * 768 * 2;
  ushort* attwb    = (ushort*)p; p += (size_t)512 * 512 * 2;
  ushort* wcomb    = (ushort*)p; p += (size_t)2304 * 512 * 2;
  ushort* gccat    = (ushort*)p; p += (size_t)256 * 512 * 2;
  ushort* clf1b16  = (ushort*)p; p += (size_t)256 * 768 * 2;
  float*  bias_comb= (float*)p;  p += 2304 * 4;
  float*  wrelTmp  = R1f;   // consumed before qkv GEMM

  // ---- weight/input prep ----
  Segs7 segs;
  segs.in[0] = x;          segs.out[0] = xb;        segs.n4[0] = N_ * 768 / 4;
  segs.in[1] = in_proj_w;  segs.out[1] = in_projb;  segs.n4[1] = 2304 * 768 / 4;
  segs.in[2] = out_proj_w; segs.out[2] = out_projb; segs.n4[2] = 768 * 768 / 4;
  segs.in[3] = ff1_w;      segs.out[3] = ff1b;      segs.n4[3] = 2048 * 768 / 4;
  segs.in[4] = ff2_w;      segs.out[4] = ff2b;      segs.n4[4] = 768 * 2048 / 4;
  segs.in[5] = to_w;       segs.out[5] = tob;       segs.n4[5] = 512 * 768 / 4;
  segs.in[6] = clf1_w;     segs.out[6] = clf1b16;   segs.n4[6] = 256 * 768 / 4;
  cvtmulti_kernel<<<dim3(768, 7), 256, 0, stream>>>(segs);
  gccat_kernel<<<256, 256, 0, stream>>>(gc_rel_w, gc_root_w, gccat);
  tcvt_kernel<<<dim3(16, 16, 1), 256, 0, stream>>>(att_w, attwb, 512, 512, 0, 0);
  wrel_kernel<<<512, 256, 0, stream>>>(rgcn_basis, rgcn_comp, wrelTmp);
  tcvt_kernel<<<dim3(8, 16, 8), 256, 0, stream>>>(wrelTmp, wcomb, 512, 256,
                                                  (size_t)512 * 256, (size_t)256 * 512);
  tcvt_kernel<<<dim3(8, 16, 1), 256, 0, stream>>>(rgcn_root, wcomb + (size_t)2048 * 512,
                                                  512, 256, 0, 0);
  biascomb_kernel<<<9, 256, 0, stream>>>(rgcn_bias, bias_comb);

  // ---- main pipeline ----
  // qkvb = bf16(x @ in_proj^T + b)
  mgemm_kernel<true, false, false, false, true><<<dim3(18, 55), 256, 0, stream>>>(
      xb, in_projb, in_proj_b, nullptr, nullptr, R1b, 768, 768, 768, 2304);
  vtrans_kernel<<<dim3(24, 4, 64), 256, 0, stream>>>(R1b, vt);
  attnM_kernel<<<dim3(7, 64), 256, 0, stream>>>(R1b, vt, ctxb);
  // aproj = ctx @ out_proj^T + b
  mgemm_kernel<true, false, false, true, false><<<dim3(6, 55), 256, 0, stream>>>(
      ctxb, out_projb, out_proj_b, nullptr, aproj, nullptr, 768, 768, 768, 768);
  ln_kernel<<<N_, 256, 0, stream>>>(x, aproj, ln1_g, ln1_b, hbuf, hb);
  // ff = relu(h @ ff1^T + b)  (bf16)
  mgemm_kernel<true, true, false, false, true><<<dim3(16, 55), 256, 0, stream>>>(
      hb, ff1b, ff1_b, nullptr, nullptr, R1b, 768, 768, 768, 2048);
  // ffo = ff @ ff2^T + b
  mgemm_kernel<true, false, false, true, false><<<dim3(6, 55), 256, 0, stream>>>(
      R1b, ff2b, ff2_b, nullptr, ffo, nullptr, 2048, 2048, 2048, 768);
  ln_kernel<<<N_, 256, 0, stream>>>(hbuf, ffo, ln2_g, ln2_b, hbuf, hb);
  // feats(bf16) -> fcat[:, 0:512]   (ldc = 768)
  mgemm_kernel<true, false, false, false, true><<<dim3(4, 55), 256, 0, stream>>>(
      hb, tob, to_b, nullptr, nullptr, fcat, 768, 768, 768, 768);
  // tmp = feats @ att_w  -> R1f
  mgemm_kernel<false, false, false, true, false><<<dim3(4, 55), 256, 0, stream>>>(
      fcat, attwb, nullptr, nullptr, R1f, nullptr, 512, 768, 512, 512);
  edgeatt_kernel<<<N_, 256, 0, stream>>>(R1f, fcat, en);
  // xcombB = bf16(feats @ [wrel_t | root_t]^T + bias_comb)
  mgemm_kernel<true, false, false, false, true><<<dim3(18, 55), 256, 0, stream>>>(
      fcat, wcomb, bias_comb, nullptr, nullptr, R1b, 512, 768, 512, 2304);
  rgcn_gather2_kernel<<<N_ / 8, 256, 0, stream>>>(R1b, speaker, catb);
  gcn_gather2_kernel<<<N_ / 8, 256, 0, stream>>>(en, catb);
  // h2(bf16) -> fcat[:, 512:768] : [agg|h1] @ [gc_rel|gc_root]^T + gc_rel_b
  mgemm_kernel<true, false, false, false, true><<<dim3(2, 55), 256, 0, stream>>>(
      catb, gccat, gc_rel_b, nullptr, nullptr, fcat + 512, 512, 512, 512, 768);
  // hid = relu(fcat @ clf1^T + b)   (K = 768)
  mgemm_kernel<true, true, false, true, false><<<dim3(2, 55), 256, 0, stream>>>(
      fcat, clf1b16, clf1_b, nullptr, hid, nullptr, 768, 768, 768, 256);
  clf2_kernel<<<(N_ * 7 + 255) / 256, 256, 0, stream>>>(hid, clf2_w, clf2_b, out);
}

// Round 6
// 360.525 us; speedup vs baseline: 6.3979x; 1.0579x over previous
//
#include <hip/hip_runtime.h>
#include <hip/hip_bf16.h>
#include <math.h>

#define L_   110
#define B_   64
#define N_   7040
#define U_   768
#define G_   512
#define H_   256
#define FF_  2048
#define EPB_ 2200
#define NC_  2816   // combined att_w(512) + wrel(2048) + root(256)

typedef __attribute__((ext_vector_type(4))) float f32x4;
typedef __attribute__((ext_vector_type(8))) short bf16x8;

__device__ __forceinline__ ushort f2b(float f) {
  union { __hip_bfloat16 h; ushort u; } cv;
  cv.h = __float2bfloat16(f);
  return cv.u;
}
__device__ __forceinline__ float b2f(ushort u) {
  union { float f; unsigned int i; } cv; cv.i = ((unsigned int)u) << 16; return cv.f;
}

// prefix(j) = number of edges with src-row j' < j within one dialogue
__device__ __forceinline__ int edge_prefix(int j) {
  if (j <= 10)  return j * 11 + (j * (j - 1)) / 2;
  if (j <= 100) return 155 + (j - 10) * 21;
  return 2045 + ((141 - j) * (j - 100)) / 2;
}

// ------------- multi-segment f32->bf16 convert (one launch for 7 arrays) ---
struct Segs7 { const float* in[7]; ushort* out[7]; int n4[7]; };

__global__ __launch_bounds__(256)
void cvtmulti_kernel(Segs7 s)
{
  const int seg = blockIdx.y;
  const int n4 = s.n4[seg];
  const float* __restrict__ in = s.in[seg];
  ushort* __restrict__ out = s.out[seg];
  for (int i = blockIdx.x * 256 + threadIdx.x; i < n4; i += gridDim.x * 256) {
    float4 v = ((const float4*)in)[i];
    ushort4 o;
    o.x = f2b(v.x); o.y = f2b(v.y); o.z = f2b(v.z); o.w = f2b(v.w);
    ((ushort4*)out)[i] = o;
  }
}

// ---------- batched tiled transpose+convert: in (R,C) f32 -> out (C,R) bf16
__global__ __launch_bounds__(256)
void tcvt_kernel(const float* __restrict__ in, ushort* __restrict__ out,
                 int R, int C, size_t inStride, size_t outStride)
{
  __shared__ float t[32][33];
  const int bt = blockIdx.z;
  const int r0 = blockIdx.y * 32, c0 = blockIdx.x * 32;
  const int tx = threadIdx.x & 31, ty = threadIdx.x >> 5;
  for (int i = ty; i < 32; i += 8)
    t[i][tx] = in[bt * inStride + (size_t)(r0 + i) * C + c0 + tx];
  __syncthreads();
  for (int i = ty; i < 32; i += 8)
    out[bt * outStride + (size_t)(c0 + i) * R + r0 + tx] = f2b(t[tx][i]);
}

// -------- w_rel[r](g,h) = sum_b comp[r,b]*basis[b](g,h) -> f32 temp --------
__global__ __launch_bounds__(256)
void wrel_kernel(const float* __restrict__ basis, const float* __restrict__ comp,
                 float* __restrict__ wrel)
{
  __shared__ float cs[240];
  const int tid = threadIdx.x;
  if (tid < 240) cs[tid] = comp[tid];
  __syncthreads();
  const int gh = blockIdx.x * 256 + tid;
  float acc[8] = {};
  for (int bb = 0; bb < 30; ++bb) {
    float v = basis[(size_t)bb * (G_ * H_) + gh];
#pragma unroll
    for (int r = 0; r < 8; ++r) acc[r] = fmaf(cs[r * 30 + bb], v, acc[r]);
  }
#pragma unroll
  for (int r = 0; r < 8; ++r) wrel[(size_t)r * (G_ * H_) + gh] = acc[r];
}

// -------- bias_comb: [0..2560)=0, [2560..2816)=rgcn_bias -------------------
__global__ void biascomb_kernel(const float* __restrict__ rb, float* __restrict__ bias)
{
  int i = blockIdx.x * 256 + threadIdx.x;
  if (i < NC_) bias[i] = (i < 2560) ? 0.f : rb[i - 2560];
}

// -------- gccat: row i = [gc_rel_w[i] | gc_root_w[i]]  (256 x 512 bf16) ----
__global__ __launch_bounds__(256)
void gccat_kernel(const float* __restrict__ rel, const float* __restrict__ root,
                  ushort* __restrict__ outp)
{
  int i = blockIdx.x * 256 + threadIdx.x;   // 65536 total
  const int r = i >> 8, c = i & 255;
  outp[(size_t)r * 512 + c]       = f2b(rel[i]);
  outp[(size_t)r * 512 + 256 + c] = f2b(root[i]);
}

// ===================== bf16 MFMA GEMM: C = A @ B^T (+bias)(+Cin)(relu) =====
template<bool BIAS, bool RELU, bool ACC, bool OUTF, bool OUTB>
__global__ __launch_bounds__(256)
void mgemm_kernel(const ushort* __restrict__ A, const ushort* __restrict__ B,
                  const float* __restrict__ bias, const float* __restrict__ Cin,
                  float* __restrict__ Cf, ushort* __restrict__ Cb,
                  int K, int lda, int ldb, int ldc)
{
  __shared__ ushort sA[128 * 64];
  __shared__ ushort sB[128 * 64];
  const int tid = threadIdx.x;
  const int w = tid >> 6, l = tid & 63;
  const int m0 = blockIdx.y * 128, n0 = blockIdx.x * 128;

  const int srow = l >> 3, sg = l & 7, rbase = w * 32;
  const int wr = w >> 1, wc = w & 1;
  const int lrow = l & 15, lk = l >> 4;
  const int xm = (l & 7) << 4;
  const int kb0 = (lk * 16) ^ xm;
  int aoff[4], boff[4];
#pragma unroll
  for (int i = 0; i < 4; ++i) {
    aoff[i] = (wr * 64 + i * 16 + lrow) * 128 + kb0;
    boff[i] = (wc * 64 + i * 16 + lrow) * 128 + kb0;
  }

  f32x4 acc[4][4];
#pragma unroll
  for (int i = 0; i < 4; ++i)
#pragma unroll
    for (int j = 0; j < 4; ++j) acc[i][j] = (f32x4){0.f, 0.f, 0.f, 0.f};

#define STAGE(k0)                                                              \
  {                                                                            \
    _Pragma("unroll")                                                          \
    for (int i = 0; i < 4; ++i) {                                              \
      const int trow = rbase + i * 8 + srow;                                   \
      const int koff = (sg * 8) ^ ((trow & 7) << 3);                           \
      const ushort* ga = A + (size_t)(m0 + trow) * lda + (k0) + koff;          \
      const ushort* gb = B + (size_t)(n0 + trow) * ldb + (k0) + koff;          \
      __builtin_amdgcn_global_load_lds(                                        \
          (const __attribute__((address_space(1))) void*)ga,                   \
          (__attribute__((address_space(3))) void*)&sA[(rbase + i * 8) * 64],  \
          16, 0, 0);                                                           \
      __builtin_amdgcn_global_load_lds(                                        \
          (const __attribute__((address_space(1))) void*)gb,                   \
          (__attribute__((address_space(3))) void*)&sB[(rbase + i * 8) * 64],  \
          16, 0, 0);                                                           \
    }                                                                          \
  }

  STAGE(0)
  for (int kt = 0;;) {
    __syncthreads();
#pragma unroll
    for (int h = 0; h < 2; ++h) {
      const int hx = h * 64;
      bf16x8 af[4], bfr[4];
#pragma unroll
      for (int i = 0; i < 4; ++i) {
        af[i]  = *(const bf16x8*)&sA[(aoff[i] ^ hx) >> 1];
        bfr[i] = *(const bf16x8*)&sB[(boff[i] ^ hx) >> 1];
      }
#pragma unroll
      for (int mi = 0; mi < 4; ++mi)
#pragma unroll
        for (int ni = 0; ni < 4; ++ni)
          acc[mi][ni] = __builtin_amdgcn_mfma_f32_16x16x32_bf16(
              af[mi], bfr[ni], acc[mi][ni], 0, 0, 0);
    }
    kt += 64;
    if (kt >= K) break;
    __syncthreads();
    STAGE(kt)
  }
#undef STAGE

  const int orow = m0 + wr * 64 + lk * 4;
  const int ocol = n0 + wc * 64 + lrow;
#pragma unroll
  for (int mi = 0; mi < 4; ++mi) {
#pragma unroll
    for (int r = 0; r < 4; ++r) {
      const int row = orow + mi * 16 + r;
#pragma unroll
      for (int ni = 0; ni < 4; ++ni) {
        const int col = ocol + ni * 16;
        float v = acc[mi][ni][r];
        if constexpr (ACC)  v += Cin[(size_t)row * ldc + col];
        if constexpr (BIAS) v += bias[col];
        if constexpr (RELU) v = fmaxf(v, 0.f);
        if constexpr (OUTF) Cf[(size_t)row * ldc + col] = v;
        if constexpr (OUTB) Cb[(size_t)row * ldc + col] = f2b(v);
      }
    }
  }
}

// -------- V transpose: qkvb V block (110x768) -> vt (768x128), pad 0 -------
__global__ __launch_bounds__(256)
void vtrans_kernel(const ushort* __restrict__ qkvb, ushort* __restrict__ vt)
{
  __shared__ ushort t[32][33];
  const int b = blockIdx.z;
  const int r0 = blockIdx.y * 32;   // V row (k), 0..127
  const int c0 = blockIdx.x * 32;   // V col (d), 0..767
  const int tx = threadIdx.x & 31, ty = threadIdx.x >> 5;
  for (int i = ty; i < 32; i += 8) {
    const int r = r0 + i;
    t[i][tx] = (r < L_) ? qkvb[((size_t)(b * L_) + r) * 2304 + 1536 + c0 + tx]
                        : (ushort)0;
  }
  __syncthreads();
  for (int i = ty; i < 32; i += 8)
    vt[((size_t)b * 768 + c0 + i) * 128 + r0 + tx] = t[tx][i];
}

// -------- MFMA attention: 448 blocks, XCD-grouped so one dialogue's 7 ------
// q-blocks share an XCD's L2 (K/V fetched once per dialogue per XCD).
__global__ __launch_bounds__(256)
void attnM_kernel(const ushort* __restrict__ qkvb, const ushort* __restrict__ vt,
                  ushort* __restrict__ ctxb)
{
  // wg -> (xcd, slot); 56 slots/XCD = 8 dialogues x 7 q-blocks
  const int wg = blockIdx.x;
  const int xcd = wg & 7, slot = wg >> 3;
  const int b = xcd * 8 + slot / 7;
  const int qr0 = (slot % 7) * 16;
  const int tid = threadIdx.x, w = tid >> 6, l = tid & 63;
  __shared__ float  sS[16 * 128];
  __shared__ ushort sP[16 * 128];   // bf16, 16B-group XOR swizzle
  const int lrow = l & 15, lq = l >> 4;

  // ---- QK^T: wave w covers n-frags {2w, 2w+1} (7 frags over 112 cols) ----
  const ushort* Qbase = qkvb + ((size_t)(b * L_) + qr0 + lrow) * 2304 + lq * 8;
  f32x4 accS[2] = {{0.f,0.f,0.f,0.f},{0.f,0.f,0.f,0.f}};
  const int nf0 = w * 2;
  for (int k0 = 0; k0 < 768; k0 += 32) {
    bf16x8 aq = *(const bf16x8*)(Qbase + k0);
#pragma unroll
    for (int f = 0; f < 2; ++f) {
      const int nf = nf0 + f;
      if (nf < 7) {
        const ushort* Kp = qkvb + ((size_t)(b * L_) + nf * 16 + lrow) * 2304
                         + 768 + k0 + lq * 8;
        bf16x8 bk = *(const bf16x8*)Kp;
        accS[f] = __builtin_amdgcn_mfma_f32_16x16x32_bf16(aq, bk, accS[f], 0, 0, 0);
      }
    }
  }
  const float scale = 0.03608439182435161f;  // 1/sqrt(768)
#pragma unroll
  for (int f = 0; f < 2; ++f) {
    const int nf = nf0 + f;
    if (nf < 7) {
#pragma unroll
      for (int r = 0; r < 4; ++r)
        sS[(lq * 4 + r) * 128 + nf * 16 + lrow] = accS[f][r] * scale;
    }
  }
  __syncthreads();

  // ---- softmax: wave w -> rows 4w..4w+3, 16 lanes per row ----
  {
    const int row = w * 4 + lq;
    const int c0 = lrow;
    float m = -1e30f;
    for (int c = c0; c < L_; c += 16) m = fmaxf(m, sS[row * 128 + c]);
#pragma unroll
    for (int off = 8; off; off >>= 1) m = fmaxf(m, __shfl_xor(m, off));
    float pv[7];
    float sum = 0.f;
#pragma unroll
    for (int i = 0; i < 7; ++i) {
      const int c = c0 + i * 16;
      float e = (c < L_) ? __expf(sS[row * 128 + c] - m) : 0.f;
      pv[i] = e; sum += e;
    }
#pragma unroll
    for (int off = 8; off; off >>= 1) sum += __shfl_xor(sum, off);
    const float inv = 1.f / sum;
#pragma unroll
    for (int i = 0; i < 8; ++i) {
      const int c = c0 + i * 16;
      ushort pb = (i < 7 && c < L_) ? f2b(pv[i < 7 ? i : 0] * inv) : (ushort)0;
      const int g = (c >> 3) ^ (row & 7);
      sP[row * 128 + g * 8 + (c & 7)] = pb;
    }
  }
  __syncthreads();

  // ---- PV: wave w covers ctx cols [192w, 192w+192) = 12 frags, K=128 ----
  f32x4 accO[12];
#pragma unroll
  for (int i = 0; i < 12; ++i) accO[i] = (f32x4){0.f, 0.f, 0.f, 0.f};
#pragma unroll
  for (int ks = 0; ks < 4; ++ks) {
    const int k = ks * 32 + lq * 8;
    const int g = (k >> 3) ^ (lrow & 7);
    bf16x8 ap = *(const bf16x8*)&sP[lrow * 128 + g * 8];
#pragma unroll
    for (int i = 0; i < 12; ++i) {
      const int col = w * 192 + i * 16 + lrow;
      bf16x8 bv = *(const bf16x8*)(vt + ((size_t)b * 768 + col) * 128 + k);
      accO[i] = __builtin_amdgcn_mfma_f32_16x16x32_bf16(ap, bv, accO[i], 0, 0, 0);
    }
  }
#pragma unroll
  for (int i = 0; i < 12; ++i) {
    const int col = w * 192 + i * 16 + lrow;
#pragma unroll
    for (int r = 0; r < 4; ++r) {
      const int row = qr0 + lq * 4 + r;
      if (row < L_)
        ctxb[((size_t)b * L_ + row) * 768 + col] = f2b(accO[i][r]);
    }
  }
}

// ---------------- LayerNorm(A + Bres), writes f32 + bf16 -------------------
__global__ __launch_bounds__(256)
void ln_kernel(const float* __restrict__ A, const float* __restrict__ Bres,
               const float* __restrict__ g, const float* __restrict__ beta,
               float* __restrict__ out, ushort* __restrict__ outb)
{
  const int row = blockIdx.x, tid = threadIdx.x;
  const float* ap = A + (size_t)row * U_;
  const float* bp = Bres + (size_t)row * U_;
  float v0 = ap[tid] + bp[tid];
  float v1 = ap[tid + 256] + bp[tid + 256];
  float v2 = ap[tid + 512] + bp[tid + 512];
  float s = v0 + v1 + v2, sq = v0 * v0 + v1 * v1 + v2 * v2;
  __shared__ float red[8];
#pragma unroll
  for (int off = 32; off; off >>= 1) { s += __shfl_xor(s, off); sq += __shfl_xor(sq, off); }
  const int wave = tid >> 6, lane = tid & 63;
  if (lane == 0) { red[wave] = s; red[4 + wave] = sq; }
  __syncthreads();
  if (tid == 0) {
    float ts = red[0] + red[1] + red[2] + red[3];
    float tq = red[4] + red[5] + red[6] + red[7];
    float m = ts * (1.f / 768.f);
    float var = tq * (1.f / 768.f) - m * m;
    red[0] = m; red[1] = 1.f / sqrtf(var + 1e-5f);
  }
  __syncthreads();
  const float m = red[0], inv = red[1];
  float* op = out + (size_t)row * U_;
  ushort* ob = outb + (size_t)row * U_;
  float o0 = (v0 - m) * inv * g[tid] + beta[tid];
  float o1 = (v1 - m) * inv * g[tid + 256] + beta[tid + 256];
  float o2 = (v2 - m) * inv * g[tid + 512] + beta[tid + 512];
  op[tid] = o0; op[tid + 256] = o1; op[tid + 512] = o2;
  ob[tid] = f2b(o0); ob[tid + 256] = f2b(o1); ob[tid + 512] = f2b(o2);
}

// ------ windowed edge softmax; tmpB bf16 (ld NC_), feats bf16 (fcat ld 768)
__global__ __launch_bounds__(256)
void edgeatt_kernel(const ushort* __restrict__ tmpB, const ushort* __restrict__ fcat,
                    float* __restrict__ edge_norm)
{
  const int bj = blockIdx.x;
  const int b = bj / L_, j = bj - b * L_;
  const int k0 = max(0, j - 10), k1 = min(L_ - 1, j + 10);
  __shared__ float s[32];
  const int tid = threadIdx.x;
  const int wave = tid >> 6, lane = tid & 63;
  const ushort* tp = tmpB + (size_t)bj * NC_ + lane * 8;
  float tr[8];
  {
    bf16x8 tv = *(const bf16x8*)tp;
#pragma unroll
    for (int i = 0; i < 8; ++i) tr[i] = b2f((ushort)tv[i]);
  }
  for (int k = k0 + wave; k <= k1; k += 4) {
    const ushort* fp = fcat + (size_t)(b * L_ + k) * 768 + lane * 8;
    bf16x8 v = *(const bf16x8*)fp;
    float sc = 0.f;
#pragma unroll
    for (int i = 0; i < 8; ++i) sc = fmaf(b2f((ushort)v[i]), tr[i], sc);
#pragma unroll
    for (int off = 32; off; off >>= 1) sc += __shfl_xor(sc, off);
    if (lane == 0) s[k - k0] = sc;
  }
  __syncthreads();
  if (tid == 0) {
    const int W = k1 - k0 + 1;
    float m = -1e30f;
    for (int t = 0; t < W; ++t) m = fmaxf(m, s[t]);
    float sum = 0.f;
    for (int t = 0; t < W; ++t) { float e = __expf(s[t] - m); s[t] = e; sum += e; }
    const float inv = 1.f / sum;
    const int base = b * EPB_ + edge_prefix(j);
    for (int t = 0; t < W; ++t) edge_norm[base + t] = s[t] * inv;
  }
}

// -------- RGCN gather (xcomb in combined buffer, ld NC_, offset 512) -------
__global__ __launch_bounds__(256)
void rgcn_gather2_kernel(const ushort* __restrict__ xcomb,
                         const int* __restrict__ speaker,
                         ushort* __restrict__ catb)
{
  const int tid = threadIdx.x;
  const int n = blockIdx.x * 8 + (tid >> 5);
  const int lane = tid & 31;
  const int b = n / L_, k = n - b * L_;
  const int j0 = max(0, k - 10), j1 = min(L_ - 1, k + 10);
  const int spk = speaker[n];
  float inv[4];
  {
    int cn[4] = {0, 0, 0, 0};
    for (int j = j0; j <= j1; ++j)
      cn[speaker[b * L_ + j] * 2 + (j >= k ? 1 : 0)]++;
#pragma unroll
    for (int q = 0; q < 4; ++q) inv[q] = cn[q] ? 1.f / (float)cn[q] : 0.f;
  }
  float acc[8] = {};
  for (int j = j0; j <= j1; ++j) {
    const int spj = speaker[b * L_ + j];
    const int c = (j >= k) ? 1 : 0;
    const int et = (spj * 2 + spk) * 2 + c;
    const float w = inv[spj * 2 + c];
    bf16x8 v = *(const bf16x8*)&xcomb[(size_t)(b * L_ + j) * NC_ + 512 + et * 256 + lane * 8];
#pragma unroll
    for (int i = 0; i < 8; ++i) acc[i] = fmaf(b2f((ushort)v[i]), w, acc[i]);
  }
  bf16x8 rt = *(const bf16x8*)&xcomb[(size_t)n * NC_ + 2560 + lane * 8];
  bf16x8 o;
#pragma unroll
  for (int i = 0; i < 8; ++i) o[i] = (short)f2b(acc[i] + b2f((ushort)rt[i]));
  *(bf16x8*)&catb[(size_t)n * 512 + 256 + lane * 8] = o;
}

// -------- GraphConv gather: reads h1 bf16 (catb[:,256:512]) -> agg ---------
__global__ __launch_bounds__(256)
void gcn_gather2_kernel(const float* __restrict__ edge_norm,
                        ushort* __restrict__ catb)
{
  const int tid = threadIdx.x;
  const int n = blockIdx.x * 8 + (tid >> 5);
  const int lane = tid & 31;
  const int b = n / L_, k = n - b * L_;
  const int j0 = max(0, k - 10), j1 = min(L_ - 1, k + 10);
  float acc[8] = {};
  for (int j = j0; j <= j1; ++j) {
    const float w = edge_norm[b * EPB_ + edge_prefix(j) + (k - max(0, j - 10))];
    bf16x8 v = *(const bf16x8*)&catb[(size_t)(b * L_ + j) * 512 + 256 + lane * 8];
#pragma unroll
    for (int i = 0; i < 8; ++i) acc[i] = fmaf(b2f((ushort)v[i]), w, acc[i]);
  }
  bf16x8 o;
#pragma unroll
  for (int i = 0; i < 8; ++i) o[i] = (short)f2b(acc[i]);
  *(bf16x8*)&catb[(size_t)n * 512 + lane * 8] = o;
}

// ---------------- final tiny GEMM: out = hid @ clf2_w^T + clf2_b -----------
__global__ __launch_bounds__(256)
void clf2_kernel(const float* __restrict__ hid, const float* __restrict__ w,
                 const float* __restrict__ bias, float* __restrict__ out)
{
  __shared__ float wsm[7 * H_];
  const int tid = threadIdx.x;
  for (int i = tid; i < 7 * H_; i += 256) wsm[i] = w[i];
  __syncthreads();
  const int idx = blockIdx.x * 256 + threadIdx.x;
  if (idx < N_ * 7) {
    const int n = idx / 7, t = idx - n * 7;
    const float* hp = hid + (size_t)n * H_;
    const float* wp = wsm + t * H_;
    float acc = bias[t];
    for (int d = 0; d < H_; ++d) acc = fmaf(hp[d], wp[d], acc);
    out[idx] = acc;
  }
}

extern "C" void kernel_launch(void* const* d_in, const int* in_sizes, int n_in,
                              void* d_out, int out_size, void* d_ws, size_t ws_size,
                              hipStream_t stream)
{
  const float* x          = (const float*)d_in[0];
  const float* in_proj_w  = (const float*)d_in[1];
  const float* in_proj_b  = (const float*)d_in[2];
  const float* out_proj_w = (const float*)d_in[3];
  const float* out_proj_b = (const float*)d_in[4];
  const float* ln1_g      = (const float*)d_in[5];
  const float* ln1_b      = (const float*)d_in[6];
  const float* ff1_w      = (const float*)d_in[7];
  const float* ff1_b      = (const float*)d_in[8];
  const float* ff2_w      = (const float*)d_in[9];
  const float* ff2_b      = (const float*)d_in[10];
  const float* ln2_g      = (const float*)d_in[11];
  const float* ln2_b      = (const float*)d_in[12];
  const float* to_w       = (const float*)d_in[13];
  const float* to_b       = (const float*)d_in[14];
  const float* att_w      = (const float*)d_in[15];
  const float* rgcn_basis = (const float*)d_in[16];
  const float* rgcn_comp  = (const float*)d_in[17];
  const float* rgcn_root  = (const float*)d_in[18];
  const float* rgcn_bias  = (const float*)d_in[19];
  const float* gc_rel_w   = (const float*)d_in[20];
  const float* gc_rel_b   = (const float*)d_in[21];
  const float* gc_root_w  = (const float*)d_in[22];
  const float* clf1_w     = (const float*)d_in[23];
  const float* clf1_b     = (const float*)d_in[24];
  const float* clf2_w     = (const float*)d_in[25];
  const float* clf2_b     = (const float*)d_in[26];
  const int*   speaker    = (const int*)d_in[27];
  float* out = (float*)d_out;
  char* p = (char*)d_ws;

  // ---- workspace regions ----
  // R1 (65MB): wrelTmp f32 -> qkvb bf16 -> ff bf16 -> combo bf16 (N x 2816)
  float*  R1f    = (float*)p;
  ushort* R1b    = (ushort*)p;
  p += (size_t)N_ * 2304 * 4;
  // R2 (21.6MB): aproj -> ffo f32 ; tail reused for edge_norm after ln2
  float*  aproj = (float*)p;
  float*  ffo   = aproj;
  float*  en    = (float*)(p + (size_t)N_ * 512 * 4);
  p += (size_t)N_ * 768 * 4;
  // R3 (21.6MB): vt bf16 (attn) -> hbuf f32 -> hid f32
  float*  hbuf  = (float*)p;
  ushort* vt    = (ushort*)p;
  float*  hid   = (float*)p;
  p += (size_t)N_ * 768 * 4;
  // R4 (10.8MB): xb -> ctxb
  ushort* xb    = (ushort*)p;
  ushort* ctxb  = xb;
  p += (size_t)N_ * 768 * 2;
  // R5 (10.8MB): hb bf16 (N x 768) -> catb bf16 (N x 512: [agg | h1])
  ushort* hb    = (ushort*)p;
  ushort* catb  = hb;
  p += (size_t)N_ * 768 * 2;
  // R6 (10.8MB): fcat bf16 (N x 768: [feats | h2])
  ushort* fcat  = (ushort*)p; p += (size_t)N_ * 768 * 2;
  // R7: bf16 weights
  ushort* in_projb = (ushort*)p; p += (size_t)2304 * 768 * 2;
  ushort* out_projb= (ushort*)p; p += (size_t)768 * 768 * 2;
  ushort* ff1b     = (ushort*)p; p += (size_t)2048 * 768 * 2;
  ushort* ff2b     = (ushort*)p; p += (size_t)768 * 2048 * 2;
  ushort* tob      = (ushort*)p; p += (size_t)512 * 768 * 2;
  ushort* combw    = (ushort*)p; p += (size_t)NC_ * 512 * 2;  // [attw_t|wrel_t|root_t]
  ushort* gccat    = (ushort*)p; p += (size_t)256 * 512 * 2;
  ushort* clf1b16  = (ushort*)p; p += (size_t)256 * 768 * 2;
  float*  bias_comb= (float*)p;  p += NC_ * 4;
  float*  wrelTmp  = R1f;   // consumed before qkv GEMM

  // ---- weight/input prep ----
  Segs7 segs;
  segs.in[0] = x;          segs.out[0] = xb;        segs.n4[0] = N_ * 768 / 4;
  segs.in[1] = in_proj_w;  segs.out[1] = in_projb;  segs.n4[1] = 2304 * 768 / 4;
  segs.in[2] = out_proj_w; segs.out[2] = out_projb; segs.n4[2] = 768 * 768 / 4;
  segs.in[3] = ff1_w;      segs.out[3] = ff1b;      segs.n4[3] = 2048 * 768 / 4;
  segs.in[4] = ff2_w;      segs.out[4] = ff2b;      segs.n4[4] = 768 * 2048 / 4;
  segs.in[5] = to_w;       segs.out[5] = tob;       segs.n4[5] = 512 * 768 / 4;
  segs.in[6] = clf1_w;     segs.out[6] = clf1b16;   segs.n4[6] = 256 * 768 / 4;
  cvtmulti_kernel<<<dim3(768, 7), 256, 0, stream>>>(segs);
  gccat_kernel<<<256, 256, 0, stream>>>(gc_rel_w, gc_root_w, gccat);
  // combw rows 0..511 = att_w^T
  tcvt_kernel<<<dim3(16, 16, 1), 256, 0, stream>>>(att_w, combw, 512, 512, 0, 0);
  wrel_kernel<<<512, 256, 0, stream>>>(rgcn_basis, rgcn_comp, wrelTmp);
  // combw rows 512..2559 = wrel^T (8 relations)
  tcvt_kernel<<<dim3(8, 16, 8), 256, 0, stream>>>(wrelTmp, combw + (size_t)512 * 512,
                                                  512, 256,
                                                  (size_t)512 * 256, (size_t)256 * 512);
  // combw rows 2560..2815 = root^T
  tcvt_kernel<<<dim3(8, 16, 1), 256, 0, stream>>>(rgcn_root, combw + (size_t)2560 * 512,
                                                  512, 256, 0, 0);
  biascomb_kernel<<<11, 256, 0, stream>>>(rgcn_bias, bias_comb);

  // ---- main pipeline ----
  // qkvb = bf16(x @ in_proj^T + b)
  mgemm_kernel<true, false, false, false, true><<<dim3(18, 55), 256, 0, stream>>>(
      xb, in_projb, in_proj_b, nullptr, nullptr, R1b, 768, 768, 768, 2304);
  vtrans_kernel<<<dim3(24, 4, 64), 256, 0, stream>>>(R1b, vt);
  attnM_kernel<<<448, 256, 0, stream>>>(R1b, vt, ctxb);
  // aproj = ctx @ out_proj^T + b
  mgemm_kernel<true, false, false, true, false><<<dim3(6, 55), 256, 0, stream>>>(
      ctxb, out_projb, out_proj_b, nullptr, aproj, nullptr, 768, 768, 768, 768);
  ln_kernel<<<N_, 256, 0, stream>>>(x, aproj, ln1_g, ln1_b, hbuf, hb);
  // ff = relu(h @ ff1^T + b)  (bf16)
  mgemm_kernel<true, true, false, false, true><<<dim3(16, 55), 256, 0, stream>>>(
      hb, ff1b, ff1_b, nullptr, nullptr, R1b, 768, 768, 768, 2048);
  // ffo = ff @ ff2^T + b
  mgemm_kernel<true, false, false, true, false><<<dim3(6, 55), 256, 0, stream>>>(
      R1b, ff2b, ff2_b, nullptr, ffo, nullptr, 2048, 2048, 2048, 768);
  ln_kernel<<<N_, 256, 0, stream>>>(hbuf, ffo, ln2_g, ln2_b, hbuf, hb);
  // feats(bf16) -> fcat[:, 0:512]   (ldc = 768)
  mgemm_kernel<true, false, false, false, true><<<dim3(4, 55), 256, 0, stream>>>(
      hb, tob, to_b, nullptr, nullptr, fcat, 768, 768, 768, 768);
  // combo = bf16(feats @ [attw_t | wrel_t | root_t]^T + bias_comb) (N x 2816)
  mgemm_kernel<true, false, false, false, true><<<dim3(22, 55), 256, 0, stream>>>(
      fcat, combw, bias_comb, nullptr, nullptr, R1b, 512, 768, 512, NC_);
  edgeatt_kernel<<<N_, 256, 0, stream>>>(R1b, fcat, en);
  rgcn_gather2_kernel<<<N_ / 8, 256, 0, stream>>>(R1b, speaker, catb);
  gcn_gather2_kernel<<<N_ / 8, 256, 0, stream>>>(en, catb);
  // h2(bf16) -> fcat[:, 512:768] : [agg|h1] @ [gc_rel|gc_root]^T + gc_rel_b
  mgemm_kernel<true, false, false, false, true><<<dim3(2, 55), 256, 0, stream>>>(
      catb, gccat, gc_rel_b, nullptr, nullptr, fcat + 512, 512, 512, 512, 768);
  // hid = relu(fcat @ clf1^T + b)   (K = 768)
  mgemm_kernel<true, true, false, true, false><<<dim3(2, 55), 256, 0, stream>>>(
      fcat, clf1b16, clf1_b, nullptr, hid, nullptr, 768, 768, 768, 256);
  clf2_kernel<<<(N_ * 7 + 255) / 256, 256, 0, stream>>>(hid, clf2_w, clf2_b, out);
}

// Round 7
// 349.326 us; speedup vs baseline: 6.6030x; 1.0321x over previous
//
#include <hip/hip_runtime.h>
#include <hip/hip_bf16.h>
#include <math.h>

#define L_   110
#define B_   64
#define N_   7040
#define U_   768
#define G_   512
#define H_   256
#define FF_  2048
#define EPB_ 2200
#define NC_  2816   // combined att_w(512) + wrel(2048) + root(256)

typedef __attribute__((ext_vector_type(4))) float f32x4;
typedef __attribute__((ext_vector_type(8))) short bf16x8;

__device__ __forceinline__ ushort f2b(float f) {
  union { __hip_bfloat16 h; ushort u; } cv;
  cv.h = __float2bfloat16(f);
  return cv.u;
}
__device__ __forceinline__ float b2f(ushort u) {
  union { float f; unsigned int i; } cv; cv.i = ((unsigned int)u) << 16; return cv.f;
}

// prefix(j) = number of edges with src-row j' < j within one dialogue
__device__ __forceinline__ int edge_prefix(int j) {
  if (j <= 10)  return j * 11 + (j * (j - 1)) / 2;
  if (j <= 100) return 155 + (j - 10) * 21;
  return 2045 + ((141 - j) * (j - 100)) / 2;
}

// ------------- multi-segment f32->bf16 convert (one launch for 7 arrays) ---
struct Segs7 { const float* in[7]; ushort* out[7]; int n4[7]; };

__global__ __launch_bounds__(256)
void cvtmulti_kernel(Segs7 s)
{
  const int seg = blockIdx.y;
  const int n4 = s.n4[seg];
  const float* __restrict__ in = s.in[seg];
  ushort* __restrict__ out = s.out[seg];
  for (int i = blockIdx.x * 256 + threadIdx.x; i < n4; i += gridDim.x * 256) {
    float4 v = ((const float4*)in)[i];
    ushort4 o;
    o.x = f2b(v.x); o.y = f2b(v.y); o.z = f2b(v.z); o.w = f2b(v.w);
    ((ushort4*)out)[i] = o;
  }
}

// ---------- batched tiled transpose+convert: in (R,C) f32 -> out (C,R) bf16
__global__ __launch_bounds__(256)
void tcvt_kernel(const float* __restrict__ in, ushort* __restrict__ out,
                 int R, int C, size_t inStride, size_t outStride)
{
  __shared__ float t[32][33];
  const int bt = blockIdx.z;
  const int r0 = blockIdx.y * 32, c0 = blockIdx.x * 32;
  const int tx = threadIdx.x & 31, ty = threadIdx.x >> 5;
  for (int i = ty; i < 32; i += 8)
    t[i][tx] = in[bt * inStride + (size_t)(r0 + i) * C + c0 + tx];
  __syncthreads();
  for (int i = ty; i < 32; i += 8)
    out[bt * outStride + (size_t)(c0 + i) * R + r0 + tx] = f2b(t[tx][i]);
}

// -------- w_rel[r](g,h) = sum_b comp[r,b]*basis[b](g,h) -> f32 temp --------
__global__ __launch_bounds__(256)
void wrel_kernel(const float* __restrict__ basis, const float* __restrict__ comp,
                 float* __restrict__ wrel)
{
  __shared__ float cs[240];
  const int tid = threadIdx.x;
  if (tid < 240) cs[tid] = comp[tid];
  __syncthreads();
  const int gh = blockIdx.x * 256 + tid;
  float acc[8] = {};
  for (int bb = 0; bb < 30; ++bb) {
    float v = basis[(size_t)bb * (G_ * H_) + gh];
#pragma unroll
    for (int r = 0; r < 8; ++r) acc[r] = fmaf(cs[r * 30 + bb], v, acc[r]);
  }
#pragma unroll
  for (int r = 0; r < 8; ++r) wrel[(size_t)r * (G_ * H_) + gh] = acc[r];
}

// -------- bias_comb: [0..2560)=0, [2560..2816)=rgcn_bias -------------------
__global__ void biascomb_kernel(const float* __restrict__ rb, float* __restrict__ bias)
{
  int i = blockIdx.x * 256 + threadIdx.x;
  if (i < NC_) bias[i] = (i < 2560) ? 0.f : rb[i - 2560];
}

// -------- gccat: row i = [gc_rel_w[i] | gc_root_w[i]]  (256 x 512 bf16) ----
__global__ __launch_bounds__(256)
void gccat_kernel(const float* __restrict__ rel, const float* __restrict__ root,
                  ushort* __restrict__ outp)
{
  int i = blockIdx.x * 256 + threadIdx.x;   // 65536 total
  const int r = i >> 8, c = i & 255;
  outp[(size_t)r * 512 + c]       = f2b(rel[i]);
  outp[(size_t)r * 512 + 256 + c] = f2b(root[i]);
}

// ===================== bf16 MFMA GEMM: C = A @ B^T (+bias)(+Cin)(relu) =====
// XCD-aware bijective block remap (m204): each XCD owns a contiguous chunk of
// the x-fastest linear block order, so blocks sharing an A-panel land on the
// same XCD's L2 instead of round-robining across all 8.
template<bool BIAS, bool RELU, bool ACC, bool OUTF, bool OUTB>
__global__ __launch_bounds__(256)
void mgemm_kernel(const ushort* __restrict__ A, const ushort* __restrict__ B,
                  const float* __restrict__ bias, const float* __restrict__ Cin,
                  float* __restrict__ Cf, ushort* __restrict__ Cb,
                  int K, int lda, int ldb, int ldc)
{
  __shared__ ushort sA[128 * 64];
  __shared__ ushort sB[128 * 64];
  const int tid = threadIdx.x;
  const int w = tid >> 6, l = tid & 63;

  // ---- XCD swizzle ----
  const int gx = gridDim.x;
  const int nwg = gx * gridDim.y;
  const int lid = blockIdx.y * gx + blockIdx.x;   // dispatch order (x fastest)
  const int q = nwg >> 3, r = nwg & 7;
  const int xcd = lid & 7, pos = lid >> 3;
  const int nlid = (xcd < r ? xcd * (q + 1) : r * (q + 1) + (xcd - r) * q) + pos;
  const int m0 = (nlid / gx) * 128, n0 = (nlid % gx) * 128;

  const int srow = l >> 3, sg = l & 7, rbase = w * 32;
  const int wr = w >> 1, wc = w & 1;
  const int lrow = l & 15, lk = l >> 4;
  const int xm = (l & 7) << 4;
  const int kb0 = (lk * 16) ^ xm;
  int aoff[4], boff[4];
#pragma unroll
  for (int i = 0; i < 4; ++i) {
    aoff[i] = (wr * 64 + i * 16 + lrow) * 128 + kb0;
    boff[i] = (wc * 64 + i * 16 + lrow) * 128 + kb0;
  }

  f32x4 acc[4][4];
#pragma unroll
  for (int i = 0; i < 4; ++i)
#pragma unroll
    for (int j = 0; j < 4; ++j) acc[i][j] = (f32x4){0.f, 0.f, 0.f, 0.f};

#define STAGE(k0)                                                              \
  {                                                                            \
    _Pragma("unroll")                                                          \
    for (int i = 0; i < 4; ++i) {                                              \
      const int trow = rbase + i * 8 + srow;                                   \
      const int koff = (sg * 8) ^ ((trow & 7) << 3);                           \
      const ushort* ga = A + (size_t)(m0 + trow) * lda + (k0) + koff;          \
      const ushort* gb = B + (size_t)(n0 + trow) * ldb + (k0) + koff;          \
      __builtin_amdgcn_global_load_lds(                                        \
          (const __attribute__((address_space(1))) void*)ga,                   \
          (__attribute__((address_space(3))) void*)&sA[(rbase + i * 8) * 64],  \
          16, 0, 0);                                                           \
      __builtin_amdgcn_global_load_lds(                                        \
          (const __attribute__((address_space(1))) void*)gb,                   \
          (__attribute__((address_space(3))) void*)&sB[(rbase + i * 8) * 64],  \
          16, 0, 0);                                                           \
    }                                                                          \
  }

  STAGE(0)
  for (int kt = 0;;) {
    __syncthreads();
#pragma unroll
    for (int h = 0; h < 2; ++h) {
      const int hx = h * 64;
      bf16x8 af[4], bfr[4];
#pragma unroll
      for (int i = 0; i < 4; ++i) {
        af[i]  = *(const bf16x8*)&sA[(aoff[i] ^ hx) >> 1];
        bfr[i] = *(const bf16x8*)&sB[(boff[i] ^ hx) >> 1];
      }
#pragma unroll
      for (int mi = 0; mi < 4; ++mi)
#pragma unroll
        for (int ni = 0; ni < 4; ++ni)
          acc[mi][ni] = __builtin_amdgcn_mfma_f32_16x16x32_bf16(
              af[mi], bfr[ni], acc[mi][ni], 0, 0, 0);
    }
    kt += 64;
    if (kt >= K) break;
    __syncthreads();
    STAGE(kt)
  }
#undef STAGE

  const int orow = m0 + wr * 64 + lk * 4;
  const int ocol = n0 + wc * 64 + lrow;
#pragma unroll
  for (int mi = 0; mi < 4; ++mi) {
#pragma unroll
    for (int r2 = 0; r2 < 4; ++r2) {
      const int row = orow + mi * 16 + r2;
#pragma unroll
      for (int ni = 0; ni < 4; ++ni) {
        const int col = ocol + ni * 16;
        float v = acc[mi][ni][r2];
        if constexpr (ACC)  v += Cin[(size_t)row * ldc + col];
        if constexpr (BIAS) v += bias[col];
        if constexpr (RELU) v = fmaxf(v, 0.f);
        if constexpr (OUTF) Cf[(size_t)row * ldc + col] = v;
        if constexpr (OUTB) Cb[(size_t)row * ldc + col] = f2b(v);
      }
    }
  }
}

// -------- V transpose: qkvb V block (110x768) -> vt (768x128), pad 0 -------
__global__ __launch_bounds__(256)
void vtrans_kernel(const ushort* __restrict__ qkvb, ushort* __restrict__ vt)
{
  __shared__ ushort t[32][33];
  const int b = blockIdx.z;
  const int r0 = blockIdx.y * 32;   // V row (k), 0..127
  const int c0 = blockIdx.x * 32;   // V col (d), 0..767
  const int tx = threadIdx.x & 31, ty = threadIdx.x >> 5;
  for (int i = ty; i < 32; i += 8) {
    const int r = r0 + i;
    t[i][tx] = (r < L_) ? qkvb[((size_t)(b * L_) + r) * 2304 + 1536 + c0 + tx]
                        : (ushort)0;
  }
  __syncthreads();
  for (int i = ty; i < 32; i += 8)
    vt[((size_t)b * 768 + c0 + i) * 128 + r0 + tx] = t[tx][i];
}

// -------- MFMA attention: 448 blocks, XCD-grouped so one dialogue's 7 ------
// q-blocks share an XCD's L2 (K/V fetched once per dialogue per XCD).
__global__ __launch_bounds__(256)
void attnM_kernel(const ushort* __restrict__ qkvb, const ushort* __restrict__ vt,
                  ushort* __restrict__ ctxb)
{
  // wg -> (xcd, slot); 56 slots/XCD = 8 dialogues x 7 q-blocks
  const int wg = blockIdx.x;
  const int xcd = wg & 7, slot = wg >> 3;
  const int b = xcd * 8 + slot / 7;
  const int qr0 = (slot % 7) * 16;
  const int tid = threadIdx.x, w = tid >> 6, l = tid & 63;
  __shared__ float  sS[16 * 128];
  __shared__ ushort sP[16 * 128];   // bf16, 16B-group XOR swizzle
  const int lrow = l & 15, lq = l >> 4;

  // ---- QK^T: wave w covers n-frags {2w, 2w+1} (7 frags over 112 cols) ----
  const ushort* Qbase = qkvb + ((size_t)(b * L_) + qr0 + lrow) * 2304 + lq * 8;
  f32x4 accS[2] = {{0.f,0.f,0.f,0.f},{0.f,0.f,0.f,0.f}};
  const int nf0 = w * 2;
  for (int k0 = 0; k0 < 768; k0 += 32) {
    bf16x8 aq = *(const bf16x8*)(Qbase + k0);
#pragma unroll
    for (int f = 0; f < 2; ++f) {
      const int nf = nf0 + f;
      if (nf < 7) {
        const ushort* Kp = qkvb + ((size_t)(b * L_) + nf * 16 + lrow) * 2304
                         + 768 + k0 + lq * 8;
        bf16x8 bk = *(const bf16x8*)Kp;
        accS[f] = __builtin_amdgcn_mfma_f32_16x16x32_bf16(aq, bk, accS[f], 0, 0, 0);
      }
    }
  }
  const float scale = 0.03608439182435161f;  // 1/sqrt(768)
#pragma unroll
  for (int f = 0; f < 2; ++f) {
    const int nf = nf0 + f;
    if (nf < 7) {
#pragma unroll
      for (int r = 0; r < 4; ++r)
        sS[(lq * 4 + r) * 128 + nf * 16 + lrow] = accS[f][r] * scale;
    }
  }
  __syncthreads();

  // ---- softmax: wave w -> rows 4w..4w+3, 16 lanes per row ----
  {
    const int row = w * 4 + lq;
    const int c0 = lrow;
    float m = -1e30f;
    for (int c = c0; c < L_; c += 16) m = fmaxf(m, sS[row * 128 + c]);
#pragma unroll
    for (int off = 8; off; off >>= 1) m = fmaxf(m, __shfl_xor(m, off));
    float pv[7];
    float sum = 0.f;
#pragma unroll
    for (int i = 0; i < 7; ++i) {
      const int c = c0 + i * 16;
      float e = (c < L_) ? __expf(sS[row * 128 + c] - m) : 0.f;
      pv[i] = e; sum += e;
    }
#pragma unroll
    for (int off = 8; off; off >>= 1) sum += __shfl_xor(sum, off);
    const float inv = 1.f / sum;
#pragma unroll
    for (int i = 0; i < 8; ++i) {
      const int c = c0 + i * 16;
      ushort pb = (i < 7 && c < L_) ? f2b(pv[i < 7 ? i : 0] * inv) : (ushort)0;
      const int g = (c >> 3) ^ (row & 7);
      sP[row * 128 + g * 8 + (c & 7)] = pb;
    }
  }
  __syncthreads();

  // ---- PV: wave w covers ctx cols [192w, 192w+192) = 12 frags, K=128 ----
  f32x4 accO[12];
#pragma unroll
  for (int i = 0; i < 12; ++i) accO[i] = (f32x4){0.f, 0.f, 0.f, 0.f};
#pragma unroll
  for (int ks = 0; ks < 4; ++ks) {
    const int k = ks * 32 + lq * 8;
    const int g = (k >> 3) ^ (lrow & 7);
    bf16x8 ap = *(const bf16x8*)&sP[lrow * 128 + g * 8];
#pragma unroll
    for (int i = 0; i < 12; ++i) {
      const int col = w * 192 + i * 16 + lrow;
      bf16x8 bv = *(const bf16x8*)(vt + ((size_t)b * 768 + col) * 128 + k);
      accO[i] = __builtin_amdgcn_mfma_f32_16x16x32_bf16(ap, bv, accO[i], 0, 0, 0);
    }
  }
#pragma unroll
  for (int i = 0; i < 12; ++i) {
    const int col = w * 192 + i * 16 + lrow;
#pragma unroll
    for (int r = 0; r < 4; ++r) {
      const int row = qr0 + lq * 4 + r;
      if (row < L_)
        ctxb[((size_t)b * L_ + row) * 768 + col] = f2b(accO[i][r]);
    }
  }
}

// ---------------- LayerNorm(A + Bres), writes f32 + bf16 -------------------
__global__ __launch_bounds__(256)
void ln_kernel(const float* __restrict__ A, const float* __restrict__ Bres,
               const float* __restrict__ g, const float* __restrict__ beta,
               float* __restrict__ out, ushort* __restrict__ outb)
{
  const int row = blockIdx.x, tid = threadIdx.x;
  const float* ap = A + (size_t)row * U_;
  const float* bp = Bres + (size_t)row * U_;
  float v0 = ap[tid] + bp[tid];
  float v1 = ap[tid + 256] + bp[tid + 256];
  float v2 = ap[tid + 512] + bp[tid + 512];
  float s = v0 + v1 + v2, sq = v0 * v0 + v1 * v1 + v2 * v2;
  __shared__ float red[8];
#pragma unroll
  for (int off = 32; off; off >>= 1) { s += __shfl_xor(s, off); sq += __shfl_xor(sq, off); }
  const int wave = tid >> 6, lane = tid & 63;
  if (lane == 0) { red[wave] = s; red[4 + wave] = sq; }
  __syncthreads();
  if (tid == 0) {
    float ts = red[0] + red[1] + red[2] + red[3];
    float tq = red[4] + red[5] + red[6] + red[7];
    float m = ts * (1.f / 768.f);
    float var = tq * (1.f / 768.f) - m * m;
    red[0] = m; red[1] = 1.f / sqrtf(var + 1e-5f);
  }
  __syncthreads();
  const float m = red[0], inv = red[1];
  float* op = out + (size_t)row * U_;
  ushort* ob = outb + (size_t)row * U_;
  float o0 = (v0 - m) * inv * g[tid] + beta[tid];
  float o1 = (v1 - m) * inv * g[tid + 256] + beta[tid + 256];
  float o2 = (v2 - m) * inv * g[tid + 512] + beta[tid + 512];
  op[tid] = o0; op[tid + 256] = o1; op[tid + 512] = o2;
  ob[tid] = f2b(o0); ob[tid + 256] = f2b(o1); ob[tid + 512] = f2b(o2);
}

// ------ windowed edge softmax; tmpB bf16 (ld NC_), feats bf16 (fcat ld 768)
__global__ __launch_bounds__(256)
void edgeatt_kernel(const ushort* __restrict__ tmpB, const ushort* __restrict__ fcat,
                    float* __restrict__ edge_norm)
{
  const int bj = blockIdx.x;
  const int b = bj / L_, j = bj - b * L_;
  const int k0 = max(0, j - 10), k1 = min(L_ - 1, j + 10);
  __shared__ float s[32];
  const int tid = threadIdx.x;
  const int wave = tid >> 6, lane = tid & 63;
  const ushort* tp = tmpB + (size_t)bj * NC_ + lane * 8;
  float tr[8];
  {
    bf16x8 tv = *(const bf16x8*)tp;
#pragma unroll
    for (int i = 0; i < 8; ++i) tr[i] = b2f((ushort)tv[i]);
  }
  for (int k = k0 + wave; k <= k1; k += 4) {
    const ushort* fp = fcat + (size_t)(b * L_ + k) * 768 + lane * 8;
    bf16x8 v = *(const bf16x8*)fp;
    float sc = 0.f;
#pragma unroll
    for (int i = 0; i < 8; ++i) sc = fmaf(b2f((ushort)v[i]), tr[i], sc);
#pragma unroll
    for (int off = 32; off; off >>= 1) sc += __shfl_xor(sc, off);
    if (lane == 0) s[k - k0] = sc;
  }
  __syncthreads();
  if (tid == 0) {
    const int W = k1 - k0 + 1;
    float m = -1e30f;
    for (int t = 0; t < W; ++t) m = fmaxf(m, s[t]);
    float sum = 0.f;
    for (int t = 0; t < W; ++t) { float e = __expf(s[t] - m); s[t] = e; sum += e; }
    const float inv = 1.f / sum;
    const int base = b * EPB_ + edge_prefix(j);
    for (int t = 0; t < W; ++t) edge_norm[base + t] = s[t] * inv;
  }
}

// -------- RGCN gather (xcomb in combined buffer, ld NC_, offset 512) -------
__global__ __launch_bounds__(256)
void rgcn_gather2_kernel(const ushort* __restrict__ xcomb,
                         const int* __restrict__ speaker,
                         ushort* __restrict__ catb)
{
  const int tid = threadIdx.x;
  const int n = blockIdx.x * 8 + (tid >> 5);
  const int lane = tid & 31;
  const int b = n / L_, k = n - b * L_;
  const int j0 = max(0, k - 10), j1 = min(L_ - 1, k + 10);
  const int spk = speaker[n];
  float inv[4];
  {
    int cn[4] = {0, 0, 0, 0};
    for (int j = j0; j <= j1; ++j)
      cn[speaker[b * L_ + j] * 2 + (j >= k ? 1 : 0)]++;
#pragma unroll
    for (int q = 0; q < 4; ++q) inv[q] = cn[q] ? 1.f / (float)cn[q] : 0.f;
  }
  float acc[8] = {};
  for (int j = j0; j <= j1; ++j) {
    const int spj = speaker[b * L_ + j];
    const int c = (j >= k) ? 1 : 0;
    const int et = (spj * 2 + spk) * 2 + c;
    const float w = inv[spj * 2 + c];
    bf16x8 v = *(const bf16x8*)&xcomb[(size_t)(b * L_ + j) * NC_ + 512 + et * 256 + lane * 8];
#pragma unroll
    for (int i = 0; i < 8; ++i) acc[i] = fmaf(b2f((ushort)v[i]), w, acc[i]);
  }
  bf16x8 rt = *(const bf16x8*)&xcomb[(size_t)n * NC_ + 2560 + lane * 8];
  bf16x8 o;
#pragma unroll
  for (int i = 0; i < 8; ++i) o[i] = (short)f2b(acc[i] + b2f((ushort)rt[i]));
  *(bf16x8*)&catb[(size_t)n * 512 + 256 + lane * 8] = o;
}

// -------- GraphConv gather: reads h1 bf16 (catb[:,256:512]) -> agg ---------
__global__ __launch_bounds__(256)
void gcn_gather2_kernel(const float* __restrict__ edge_norm,
                        ushort* __restrict__ catb)
{
  const int tid = threadIdx.x;
  const int n = blockIdx.x * 8 + (tid >> 5);
  const int lane = tid & 31;
  const int b = n / L_, k = n - b * L_;
  const int j0 = max(0, k - 10), j1 = min(L_ - 1, k + 10);
  float acc[8] = {};
  for (int j = j0; j <= j1; ++j) {
    const float w = edge_norm[b * EPB_ + edge_prefix(j) + (k - max(0, j - 10))];
    bf16x8 v = *(const bf16x8*)&catb[(size_t)(b * L_ + j) * 512 + 256 + lane * 8];
#pragma unroll
    for (int i = 0; i < 8; ++i) acc[i] = fmaf(b2f((ushort)v[i]), w, acc[i]);
  }
  bf16x8 o;
#pragma unroll
  for (int i = 0; i < 8; ++i) o[i] = (short)f2b(acc[i]);
  *(bf16x8*)&catb[(size_t)n * 512 + lane * 8] = o;
}

// ---------------- final tiny GEMM: out = hid @ clf2_w^T + clf2_b -----------
__global__ __launch_bounds__(256)
void clf2_kernel(const float* __restrict__ hid, const float* __restrict__ w,
                 const float* __restrict__ bias, float* __restrict__ out)
{
  __shared__ float wsm[7 * H_];
  const int tid = threadIdx.x;
  for (int i = tid; i < 7 * H_; i += 256) wsm[i] = w[i];
  __syncthreads();
  const int idx = blockIdx.x * 256 + threadIdx.x;
  if (idx < N_ * 7) {
    const int n = idx / 7, t = idx - n * 7;
    const float* hp = hid + (size_t)n * H_;
    const float* wp = wsm + t * H_;
    float acc = bias[t];
    for (int d = 0; d < H_; ++d) acc = fmaf(hp[d], wp[d], acc);
    out[idx] = acc;
  }
}

extern "C" void kernel_launch(void* const* d_in, const int* in_sizes, int n_in,
                              void* d_out, int out_size, void* d_ws, size_t ws_size,
                              hipStream_t stream)
{
  const float* x          = (const float*)d_in[0];
  const float* in_proj_w  = (const float*)d_in[1];
  const float* in_proj_b  = (const float*)d_in[2];
  const float* out_proj_w = (const float*)d_in[3];
  const float* out_proj_b = (const float*)d_in[4];
  const float* ln1_g      = (const float*)d_in[5];
  const float* ln1_b      = (const float*)d_in[6];
  const float* ff1_w      = (const float*)d_in[7];
  const float* ff1_b      = (const float*)d_in[8];
  const float* ff2_w      = (const float*)d_in[9];
  const float* ff2_b      = (const float*)d_in[10];
  const float* ln2_g      = (const float*)d_in[11];
  const float* ln2_b      = (const float*)d_in[12];
  const float* to_w       = (const float*)d_in[13];
  const float* to_b       = (const float*)d_in[14];
  const float* att_w      = (const float*)d_in[15];
  const float* rgcn_basis = (const float*)d_in[16];
  const float* rgcn_comp  = (const float*)d_in[17];
  const float* rgcn_root  = (const float*)d_in[18];
  const float* rgcn_bias  = (const float*)d_in[19];
  const float* gc_rel_w   = (const float*)d_in[20];
  const float* gc_rel_b   = (const float*)d_in[21];
  const float* gc_root_w  = (const float*)d_in[22];
  const float* clf1_w     = (const float*)d_in[23];
  const float* clf1_b     = (const float*)d_in[24];
  const float* clf2_w     = (const float*)d_in[25];
  const float* clf2_b     = (const float*)d_in[26];
  const int*   speaker    = (const int*)d_in[27];
  float* out = (float*)d_out;
  char* p = (char*)d_ws;

  // ---- workspace regions ----
  // R1 (65MB): wrelTmp f32 -> qkvb bf16 -> ff bf16 -> combo bf16 (N x 2816)
  float*  R1f    = (float*)p;
  ushort* R1b    = (ushort*)p;
  p += (size_t)N_ * 2304 * 4;
  // R2 (21.6MB): aproj -> ffo f32 ; tail reused for edge_norm after ln2
  float*  aproj = (float*)p;
  float*  ffo   = aproj;
  float*  en    = (float*)(p + (size_t)N_ * 512 * 4);
  p += (size_t)N_ * 768 * 4;
  // R3 (21.6MB): vt bf16 (attn) -> hbuf f32 -> hid f32
  float*  hbuf  = (float*)p;
  ushort* vt    = (ushort*)p;
  float*  hid   = (float*)p;
  p += (size_t)N_ * 768 * 4;
  // R4 (10.8MB): xb -> ctxb
  ushort* xb    = (ushort*)p;
  ushort* ctxb  = xb;
  p += (size_t)N_ * 768 * 2;
  // R5 (10.8MB): hb bf16 (N x 768) -> catb bf16 (N x 512: [agg | h1])
  ushort* hb    = (ushort*)p;
  ushort* catb  = hb;
  p += (size_t)N_ * 768 * 2;
  // R6 (10.8MB): fcat bf16 (N x 768: [feats | h2])
  ushort* fcat  = (ushort*)p; p += (size_t)N_ * 768 * 2;
  // R7: bf16 weights
  ushort* in_projb = (ushort*)p; p += (size_t)2304 * 768 * 2;
  ushort* out_projb= (ushort*)p; p += (size_t)768 * 768 * 2;
  ushort* ff1b     = (ushort*)p; p += (size_t)2048 * 768 * 2;
  ushort* ff2b     = (ushort*)p; p += (size_t)768 * 2048 * 2;
  ushort* tob      = (ushort*)p; p += (size_t)512 * 768 * 2;
  ushort* combw    = (ushort*)p; p += (size_t)NC_ * 512 * 2;  // [attw_t|wrel_t|root_t]
  ushort* gccat    = (ushort*)p; p += (size_t)256 * 512 * 2;
  ushort* clf1b16  = (ushort*)p; p += (size_t)256 * 768 * 2;
  float*  bias_comb= (float*)p;  p += NC_ * 4;
  float*  wrelTmp  = R1f;   // consumed before qkv GEMM

  // ---- weight/input prep ----
  Segs7 segs;
  segs.in[0] = x;          segs.out[0] = xb;        segs.n4[0] = N_ * 768 / 4;
  segs.in[1] = in_proj_w;  segs.out[1] = in_projb;  segs.n4[1] = 2304 * 768 / 4;
  segs.in[2] = out_proj_w; segs.out[2] = out_projb; segs.n4[2] = 768 * 768 / 4;
  segs.in[3] = ff1_w;      segs.out[3] = ff1b;      segs.n4[3] = 2048 * 768 / 4;
  segs.in[4] = ff2_w;      segs.out[4] = ff2b;      segs.n4[4] = 768 * 2048 / 4;
  segs.in[5] = to_w;       segs.out[5] = tob;       segs.n4[5] = 512 * 768 / 4;
  segs.in[6] = clf1_w;     segs.out[6] = clf1b16;   segs.n4[6] = 256 * 768 / 4;
  cvtmulti_kernel<<<dim3(768, 7), 256, 0, stream>>>(segs);
  gccat_kernel<<<256, 256, 0, stream>>>(gc_rel_w, gc_root_w, gccat);
  // combw rows 0..511 = att_w^T
  tcvt_kernel<<<dim3(16, 16, 1), 256, 0, stream>>>(att_w, combw, 512, 512, 0, 0);
  wrel_kernel<<<512, 256, 0, stream>>>(rgcn_basis, rgcn_comp, wrelTmp);
  // combw rows 512..2559 = wrel^T (8 relations)
  tcvt_kernel<<<dim3(8, 16, 8), 256, 0, stream>>>(wrelTmp, combw + (size_t)512 * 512,
                                                  512, 256,
                                                  (size_t)512 * 256, (size_t)256 * 512);
  // combw rows 2560..2815 = root^T
  tcvt_kernel<<<dim3(8, 16, 1), 256, 0, stream>>>(rgcn_root, combw + (size_t)2560 * 512,
                                                  512, 256, 0, 0);
  biascomb_kernel<<<11, 256, 0, stream>>>(rgcn_bias, bias_comb);

  // ---- main pipeline ----
  // qkvb = bf16(x @ in_proj^T + b)
  mgemm_kernel<true, false, false, false, true><<<dim3(18, 55), 256, 0, stream>>>(
      xb, in_projb, in_proj_b, nullptr, nullptr, R1b, 768, 768, 768, 2304);
  vtrans_kernel<<<dim3(24, 4, 64), 256, 0, stream>>>(R1b, vt);
  attnM_kernel<<<448, 256, 0, stream>>>(R1b, vt, ctxb);
  // aproj = ctx @ out_proj^T + b
  mgemm_kernel<true, false, false, true, false><<<dim3(6, 55), 256, 0, stream>>>(
      ctxb, out_projb, out_proj_b, nullptr, aproj, nullptr, 768, 768, 768, 768);
  ln_kernel<<<N_, 256, 0, stream>>>(x, aproj, ln1_g, ln1_b, hbuf, hb);
  // ff = relu(h @ ff1^T + b)  (bf16)
  mgemm_kernel<true, true, false, false, true><<<dim3(16, 55), 256, 0, stream>>>(
      hb, ff1b, ff1_b, nullptr, nullptr, R1b, 768, 768, 768, 2048);
  // ffo = ff @ ff2^T + b
  mgemm_kernel<true, false, false, true, false><<<dim3(6, 55), 256, 0, stream>>>(
      R1b, ff2b, ff2_b, nullptr, ffo, nullptr, 2048, 2048, 2048, 768);
  ln_kernel<<<N_, 256, 0, stream>>>(hbuf, ffo, ln2_g, ln2_b, hbuf, hb);
  // feats(bf16) -> fcat[:, 0:512]   (ldc = 768)
  mgemm_kernel<true, false, false, false, true><<<dim3(4, 55), 256, 0, stream>>>(
      hb, tob, to_b, nullptr, nullptr, fcat, 768, 768, 768, 768);
  // combo = bf16(feats @ [attw_t | wrel_t | root_t]^T + bias_comb) (N x 2816)
  mgemm_kernel<true, false, false, false, true><<<dim3(22, 55), 256, 0, stream>>>(
      fcat, combw, bias_comb, nullptr, nullptr, R1b, 512, 768, 512, NC_);
  edgeatt_kernel<<<N_, 256, 0, stream>>>(R1b, fcat, en);
  rgcn_gather2_kernel<<<N_ / 8, 256, 0, stream>>>(R1b, speaker, catb);
  gcn_gather2_kernel<<<N_ / 8, 256, 0, stream>>>(en, catb);
  // h2(bf16) -> fcat[:, 512:768] : [agg|h1] @ [gc_rel|gc_root]^T + gc_rel_b
  mgemm_kernel<true, false, false, false, true><<<dim3(2, 55), 256, 0, stream>>>(
      catb, gccat, gc_rel_b, nullptr, nullptr, fcat + 512, 512, 512, 512, 768);
  // hid = relu(fcat @ clf1^T + b)   (K = 768)
  mgemm_kernel<true, true, false, true, false><<<dim3(2, 55), 256, 0, stream>>>(
      fcat, clf1b16, clf1_b, nullptr, hid, nullptr, 768, 768, 768, 256);
  clf2_kernel<<<(N_ * 7 + 255) / 256, 256, 0, stream>>>(hid, clf2_w, clf2_b, out);
}

// Round 8
// 337.114 us; speedup vs baseline: 6.8422x; 1.0362x over previous
//
#include <hip/hip_runtime.h>
#include <hip/hip_bf16.h>
#include <math.h>

#define L_   110
#define B_   64
#define N_   7040
#define U_   768
#define G_   512
#define H_   256
#define FF_  2048
#define EPB_ 2200
#define NC_  2816   // combined att_w(512) + wrel(2048) + root(256)

typedef __attribute__((ext_vector_type(4))) float f32x4;
typedef __attribute__((ext_vector_type(8))) short bf16x8;

__device__ __forceinline__ ushort f2b(float f) {
  union { __hip_bfloat16 h; ushort u; } cv;
  cv.h = __float2bfloat16(f);
  return cv.u;
}
__device__ __forceinline__ float b2f(ushort u) {
  union { float f; unsigned int i; } cv; cv.i = ((unsigned int)u) << 16; return cv.f;
}

// prefix(j) = number of edges with src-row j' < j within one dialogue
__device__ __forceinline__ int edge_prefix(int j) {
  if (j <= 10)  return j * 11 + (j * (j - 1)) / 2;
  if (j <= 100) return 155 + (j - 10) * 21;
  return 2045 + ((141 - j) * (j - 100)) / 2;
}

// ------------- multi-segment f32->bf16 convert (one launch for 7 arrays) ---
struct Segs7 { const float* in[7]; ushort* out[7]; int n4[7]; };

__global__ __launch_bounds__(256)
void cvtmulti_kernel(Segs7 s)
{
  const int seg = blockIdx.y;
  const int n4 = s.n4[seg];
  const float* __restrict__ in = s.in[seg];
  ushort* __restrict__ out = s.out[seg];
  for (int i = blockIdx.x * 256 + threadIdx.x; i < n4; i += gridDim.x * 256) {
    float4 v = ((const float4*)in)[i];
    ushort4 o;
    o.x = f2b(v.x); o.y = f2b(v.y); o.z = f2b(v.z); o.w = f2b(v.w);
    ((ushort4*)out)[i] = o;
  }
}

// ---------- batched tiled transpose+convert: in (R,C) f32 -> out (C,R) bf16
__global__ __launch_bounds__(256)
void tcvt_kernel(const float* __restrict__ in, ushort* __restrict__ out,
                 int R, int C, size_t inStride, size_t outStride)
{
  __shared__ float t[32][33];
  const int bt = blockIdx.z;
  const int r0 = blockIdx.y * 32, c0 = blockIdx.x * 32;
  const int tx = threadIdx.x & 31, ty = threadIdx.x >> 5;
  for (int i = ty; i < 32; i += 8)
    t[i][tx] = in[bt * inStride + (size_t)(r0 + i) * C + c0 + tx];
  __syncthreads();
  for (int i = ty; i < 32; i += 8)
    out[bt * outStride + (size_t)(c0 + i) * R + r0 + tx] = f2b(t[tx][i]);
}

// -------- w_rel[r](g,h) = sum_b comp[r,b]*basis[b](g,h) -> f32 temp --------
__global__ __launch_bounds__(256)
void wrel_kernel(const float* __restrict__ basis, const float* __restrict__ comp,
                 float* __restrict__ wrel)
{
  __shared__ float cs[240];
  const int tid = threadIdx.x;
  if (tid < 240) cs[tid] = comp[tid];
  __syncthreads();
  const int gh = blockIdx.x * 256 + tid;
  float acc[8] = {};
  for (int bb = 0; bb < 30; ++bb) {
    float v = basis[(size_t)bb * (G_ * H_) + gh];
#pragma unroll
    for (int r = 0; r < 8; ++r) acc[r] = fmaf(cs[r * 30 + bb], v, acc[r]);
  }
#pragma unroll
  for (int r = 0; r < 8; ++r) wrel[(size_t)r * (G_ * H_) + gh] = acc[r];
}

// ---- prep misc: bias_comb + gccat + vt pad-row zeroing (one launch) -------
__global__ __launch_bounds__(256)
void prepmisc_kernel(const float* __restrict__ rb, const float* __restrict__ rel,
                     const float* __restrict__ root, float* __restrict__ bias,
                     ushort* __restrict__ gccat, ushort* __restrict__ vt)
{
  const int i = blockIdx.x * 256 + threadIdx.x;
  if (i < NC_) {
    bias[i] = (i < 2560) ? 0.f : rb[i - 2560];
  } else if (i < NC_ + 65536) {
    const int j = i - NC_;
    const int r = j >> 8, c = j & 255;
    gccat[(size_t)r * 512 + c]       = f2b(rel[j]);
    gccat[(size_t)r * 512 + 256 + c] = f2b(root[j]);
  } else if (i < NC_ + 65536 + 64 * 768 * 18) {
    const int j = i - (NC_ + 65536);
    const int bd = j / 18, kk = 110 + (j - bd * 18);
    vt[(size_t)bd * 128 + kk] = 0;   // zero V^T pad rows (avoid NaN in PV)
  }
}

// ===================== bf16 MFMA GEMM: C = A @ B^T (+bias)(+relu) ==========
// XCD-aware bijective block remap (m204). Optional fused V^T emit (VTOUT):
// cols >= 1536 also stored transposed to vt[(b*768+col-1536)*128 + k].
template<bool BIAS, bool RELU, bool OUTB, bool VTOUT>
__global__ __launch_bounds__(256)
void mgemm_kernel(const ushort* __restrict__ A, const ushort* __restrict__ B,
                  const float* __restrict__ bias, ushort* __restrict__ Cb,
                  ushort* __restrict__ Vt,
                  int K, int lda, int ldb, int ldc)
{
  __shared__ ushort sA[128 * 64];
  __shared__ ushort sB[128 * 64];
  const int tid = threadIdx.x;
  const int w = tid >> 6, l = tid & 63;

  // ---- XCD swizzle ----
  const int gx = gridDim.x;
  const int nwg = gx * gridDim.y;
  const int lid = blockIdx.y * gx + blockIdx.x;
  const int q = nwg >> 3, r = nwg & 7;
  const int xcd = lid & 7, pos = lid >> 3;
  const int nlid = (xcd < r ? xcd * (q + 1) : r * (q + 1) + (xcd - r) * q) + pos;
  const int m0 = (nlid / gx) * 128, n0 = (nlid % gx) * 128;

  const int srow = l >> 3, sg = l & 7, rbase = w * 32;
  const int wr = w >> 1, wc = w & 1;
  const int lrow = l & 15, lk = l >> 4;
  const int xm = (l & 7) << 4;
  const int kb0 = (lk * 16) ^ xm;
  int aoff[4], boff[4];
#pragma unroll
  for (int i = 0; i < 4; ++i) {
    aoff[i] = (wr * 64 + i * 16 + lrow) * 128 + kb0;
    boff[i] = (wc * 64 + i * 16 + lrow) * 128 + kb0;
  }

  f32x4 acc[4][4];
#pragma unroll
  for (int i = 0; i < 4; ++i)
#pragma unroll
    for (int j = 0; j < 4; ++j) acc[i][j] = (f32x4){0.f, 0.f, 0.f, 0.f};

#define STAGE(k0)                                                              \
  {                                                                            \
    _Pragma("unroll")                                                          \
    for (int i = 0; i < 4; ++i) {                                              \
      const int trow = rbase + i * 8 + srow;                                   \
      const int koff = (sg * 8) ^ ((trow & 7) << 3);                           \
      const ushort* ga = A + (size_t)(m0 + trow) * lda + (k0) + koff;          \
      const ushort* gb = B + (size_t)(n0 + trow) * ldb + (k0) + koff;          \
      __builtin_amdgcn_global_load_lds(                                        \
          (const __attribute__((address_space(1))) void*)ga,                   \
          (__attribute__((address_space(3))) void*)&sA[(rbase + i * 8) * 64],  \
          16, 0, 0);                                                           \
      __builtin_amdgcn_global_load_lds(                                        \
          (const __attribute__((address_space(1))) void*)gb,                   \
          (__attribute__((address_space(3))) void*)&sB[(rbase + i * 8) * 64],  \
          16, 0, 0);                                                           \
    }                                                                          \
  }

  STAGE(0)
  for (int kt = 0;;) {
    __syncthreads();
#pragma unroll
    for (int h = 0; h < 2; ++h) {
      const int hx = h * 64;
      bf16x8 af[4], bfr[4];
#pragma unroll
      for (int i = 0; i < 4; ++i) {
        af[i]  = *(const bf16x8*)&sA[(aoff[i] ^ hx) >> 1];
        bfr[i] = *(const bf16x8*)&sB[(boff[i] ^ hx) >> 1];
      }
#pragma unroll
      for (int mi = 0; mi < 4; ++mi)
#pragma unroll
        for (int ni = 0; ni < 4; ++ni)
          acc[mi][ni] = __builtin_amdgcn_mfma_f32_16x16x32_bf16(
              af[mi], bfr[ni], acc[mi][ni], 0, 0, 0);
    }
    kt += 64;
    if (kt >= K) break;
    __syncthreads();
    STAGE(kt)
  }
#undef STAGE

  const int orow = m0 + wr * 64 + lk * 4;
  const int ocol = n0 + wc * 64 + lrow;
#pragma unroll
  for (int mi = 0; mi < 4; ++mi) {
#pragma unroll
    for (int r2 = 0; r2 < 4; ++r2) {
      const int row = orow + mi * 16 + r2;
#pragma unroll
      for (int ni = 0; ni < 4; ++ni) {
        const int col = ocol + ni * 16;
        float v = acc[mi][ni][r2];
        if constexpr (BIAS) v += bias[col];
        if constexpr (RELU) v = fmaxf(v, 0.f);
        const ushort vb = f2b(v);
        if constexpr (OUTB) Cb[(size_t)row * ldc + col] = vb;
        if constexpr (VTOUT) {
          if (col >= 1536) {
            const int brow = row / L_, kk = row - brow * L_;
            Vt[((size_t)brow * 768 + (col - 1536)) * 128 + kk] = vb;
          }
        }
      }
    }
  }
}

// -------- MFMA attention: 448 blocks, XCD-grouped so one dialogue's 7 ------
// q-blocks share an XCD's L2 (K/V fetched once per dialogue per XCD).
__global__ __launch_bounds__(256)
void attnM_kernel(const ushort* __restrict__ qkvb, const ushort* __restrict__ vt,
                  ushort* __restrict__ ctxb)
{
  const int wg = blockIdx.x;
  const int xcd = wg & 7, slot = wg >> 3;
  const int b = xcd * 8 + slot / 7;
  const int qr0 = (slot % 7) * 16;
  const int tid = threadIdx.x, w = tid >> 6, l = tid & 63;
  __shared__ float  sS[16 * 128];
  __shared__ ushort sP[16 * 128];   // bf16, 16B-group XOR swizzle
  const int lrow = l & 15, lq = l >> 4;

  // ---- QK^T ----
  const ushort* Qbase = qkvb + ((size_t)(b * L_) + qr0 + lrow) * 2304 + lq * 8;
  f32x4 accS[2] = {{0.f,0.f,0.f,0.f},{0.f,0.f,0.f,0.f}};
  const int nf0 = w * 2;
  for (int k0 = 0; k0 < 768; k0 += 32) {
    bf16x8 aq = *(const bf16x8*)(Qbase + k0);
#pragma unroll
    for (int f = 0; f < 2; ++f) {
      const int nf = nf0 + f;
      if (nf < 7) {
        const ushort* Kp = qkvb + ((size_t)(b * L_) + nf * 16 + lrow) * 2304
                         + 768 + k0 + lq * 8;
        bf16x8 bk = *(const bf16x8*)Kp;
        accS[f] = __builtin_amdgcn_mfma_f32_16x16x32_bf16(aq, bk, accS[f], 0, 0, 0);
      }
    }
  }
  const float scale = 0.03608439182435161f;  // 1/sqrt(768)
#pragma unroll
  for (int f = 0; f < 2; ++f) {
    const int nf = nf0 + f;
    if (nf < 7) {
#pragma unroll
      for (int r = 0; r < 4; ++r)
        sS[(lq * 4 + r) * 128 + nf * 16 + lrow] = accS[f][r] * scale;
    }
  }
  __syncthreads();

  // ---- softmax: wave w -> rows 4w..4w+3, 16 lanes per row ----
  {
    const int row = w * 4 + lq;
    const int c0 = lrow;
    float m = -1e30f;
    for (int c = c0; c < L_; c += 16) m = fmaxf(m, sS[row * 128 + c]);
#pragma unroll
    for (int off = 8; off; off >>= 1) m = fmaxf(m, __shfl_xor(m, off));
    float pv[7];
    float sum = 0.f;
#pragma unroll
    for (int i = 0; i < 7; ++i) {
      const int c = c0 + i * 16;
      float e = (c < L_) ? __expf(sS[row * 128 + c] - m) : 0.f;
      pv[i] = e; sum += e;
    }
#pragma unroll
    for (int off = 8; off; off >>= 1) sum += __shfl_xor(sum, off);
    const float inv = 1.f / sum;
#pragma unroll
    for (int i = 0; i < 8; ++i) {
      const int c = c0 + i * 16;
      ushort pb = (i < 7 && c < L_) ? f2b(pv[i < 7 ? i : 0] * inv) : (ushort)0;
      const int g = (c >> 3) ^ (row & 7);
      sP[row * 128 + g * 8 + (c & 7)] = pb;
    }
  }
  __syncthreads();

  // ---- PV: wave w covers ctx cols [192w, 192w+192) = 12 frags, K=128 ----
  f32x4 accO[12];
#pragma unroll
  for (int i = 0; i < 12; ++i) accO[i] = (f32x4){0.f, 0.f, 0.f, 0.f};
#pragma unroll
  for (int ks = 0; ks < 4; ++ks) {
    const int k = ks * 32 + lq * 8;
    const int g = (k >> 3) ^ (lrow & 7);
    bf16x8 ap = *(const bf16x8*)&sP[lrow * 128 + g * 8];
#pragma unroll
    for (int i = 0; i < 12; ++i) {
      const int col = w * 192 + i * 16 + lrow;
      bf16x8 bv = *(const bf16x8*)(vt + ((size_t)b * 768 + col) * 128 + k);
      accO[i] = __builtin_amdgcn_mfma_f32_16x16x32_bf16(ap, bv, accO[i], 0, 0, 0);
    }
  }
#pragma unroll
  for (int i = 0; i < 12; ++i) {
    const int col = w * 192 + i * 16 + lrow;
#pragma unroll
    for (int r = 0; r < 4; ++r) {
      const int row = qr0 + lq * 4 + r;
      if (row < L_)
        ctxb[((size_t)b * L_ + row) * 768 + col] = f2b(accO[i][r]);
    }
  }
}

// ------- LayerNorm(A + Bres[bf16]), optional f32 out, always bf16 out ------
template<bool WF>
__global__ __launch_bounds__(256)
void ln_kernel(const float* __restrict__ A, const ushort* __restrict__ Bres,
               const float* __restrict__ g, const float* __restrict__ beta,
               float* __restrict__ out, ushort* __restrict__ outb)
{
  const int row = blockIdx.x, tid = threadIdx.x;
  const float* ap = A + (size_t)row * U_;
  const ushort* bp = Bres + (size_t)row * U_;
  float v0 = ap[tid] + b2f(bp[tid]);
  float v1 = ap[tid + 256] + b2f(bp[tid + 256]);
  float v2 = ap[tid + 512] + b2f(bp[tid + 512]);
  float s = v0 + v1 + v2, sq = v0 * v0 + v1 * v1 + v2 * v2;
  __shared__ float red[8];
#pragma unroll
  for (int off = 32; off; off >>= 1) { s += __shfl_xor(s, off); sq += __shfl_xor(sq, off); }
  const int wave = tid >> 6, lane = tid & 63;
  if (lane == 0) { red[wave] = s; red[4 + wave] = sq; }
  __syncthreads();
  if (tid == 0) {
    float ts = red[0] + red[1] + red[2] + red[3];
    float tq = red[4] + red[5] + red[6] + red[7];
    float m = ts * (1.f / 768.f);
    float var = tq * (1.f / 768.f) - m * m;
    red[0] = m; red[1] = 1.f / sqrtf(var + 1e-5f);
  }
  __syncthreads();
  const float m = red[0], inv = red[1];
  ushort* ob = outb + (size_t)row * U_;
  float o0 = (v0 - m) * inv * g[tid] + beta[tid];
  float o1 = (v1 - m) * inv * g[tid + 256] + beta[tid + 256];
  float o2 = (v2 - m) * inv * g[tid + 512] + beta[tid + 512];
  if constexpr (WF) {
    float* op = out + (size_t)row * U_;
    op[tid] = o0; op[tid + 256] = o1; op[tid + 512] = o2;
  }
  ob[tid] = f2b(o0); ob[tid + 256] = f2b(o1); ob[tid + 512] = f2b(o2);
}

// ---- graph front: role-split {RGCN gather | edge softmax}, both read combo
__global__ __launch_bounds__(256)
void graphfront_kernel(const ushort* __restrict__ combo, const ushort* __restrict__ fcat,
                       const int* __restrict__ speaker,
                       ushort* __restrict__ catb, float* __restrict__ edge_norm)
{
  const int tid = threadIdx.x;
  if (blockIdx.x < N_ / 8) {
    // ---- RGCN gather: 8 nodes/block, 32 lanes/node ----
    const int n = blockIdx.x * 8 + (tid >> 5);
    const int lane = tid & 31;
    const int b = n / L_, k = n - b * L_;
    const int j0 = max(0, k - 10), j1 = min(L_ - 1, k + 10);
    const int spk = speaker[n];
    float inv[4];
    {
      int cn[4] = {0, 0, 0, 0};
      for (int j = j0; j <= j1; ++j)
        cn[speaker[b * L_ + j] * 2 + (j >= k ? 1 : 0)]++;
#pragma unroll
      for (int q = 0; q < 4; ++q) inv[q] = cn[q] ? 1.f / (float)cn[q] : 0.f;
    }
    float acc[8] = {};
    for (int j = j0; j <= j1; ++j) {
      const int spj = speaker[b * L_ + j];
      const int c = (j >= k) ? 1 : 0;
      const int et = (spj * 2 + spk) * 2 + c;
      const float w = inv[spj * 2 + c];
      bf16x8 v = *(const bf16x8*)&combo[(size_t)(b * L_ + j) * NC_ + 512 + et * 256 + lane * 8];
#pragma unroll
      for (int i = 0; i < 8; ++i) acc[i] = fmaf(b2f((ushort)v[i]), w, acc[i]);
    }
    bf16x8 rt = *(const bf16x8*)&combo[(size_t)n * NC_ + 2560 + lane * 8];
    bf16x8 o;
#pragma unroll
    for (int i = 0; i < 8; ++i) o[i] = (short)f2b(acc[i] + b2f((ushort)rt[i]));
    *(bf16x8*)&catb[(size_t)n * 512 + 256 + lane * 8] = o;
  } else {
    // ---- windowed edge softmax ----
    const int bj = blockIdx.x - N_ / 8;
    const int b = bj / L_, j = bj - b * L_;
    const int k0 = max(0, j - 10), k1 = min(L_ - 1, j + 10);
    __shared__ float s[32];
    const int wave = tid >> 6, lane = tid & 63;
    float tr[8];
    {
      bf16x8 tv = *(const bf16x8*)&combo[(size_t)bj * NC_ + lane * 8];
#pragma unroll
      for (int i = 0; i < 8; ++i) tr[i] = b2f((ushort)tv[i]);
    }
    for (int k = k0 + wave; k <= k1; k += 4) {
      bf16x8 v = *(const bf16x8*)&fcat[(size_t)(b * L_ + k) * 768 + lane * 8];
      float sc = 0.f;
#pragma unroll
      for (int i = 0; i < 8; ++i) sc = fmaf(b2f((ushort)v[i]), tr[i], sc);
#pragma unroll
      for (int off = 32; off; off >>= 1) sc += __shfl_xor(sc, off);
      if (lane == 0) s[k - k0] = sc;
    }
    __syncthreads();
    if (tid == 0) {
      const int W = k1 - k0 + 1;
      float m = -1e30f;
      for (int t = 0; t < W; ++t) m = fmaxf(m, s[t]);
      float sum = 0.f;
      for (int t = 0; t < W; ++t) { float e = __expf(s[t] - m); s[t] = e; sum += e; }
      const float inv = 1.f / sum;
      const int base = b * EPB_ + edge_prefix(j);
      for (int t = 0; t < W; ++t) edge_norm[base + t] = s[t] * inv;
    }
  }
}

// -------- GraphConv gather: reads h1 bf16 (catb[:,256:512]) -> agg ---------
__global__ __launch_bounds__(256)
void gcn_gather2_kernel(const float* __restrict__ edge_norm,
                        ushort* __restrict__ catb)
{
  const int tid = threadIdx.x;
  const int n = blockIdx.x * 8 + (tid >> 5);
  const int lane = tid & 31;
  const int b = n / L_, k = n - b * L_;
  const int j0 = max(0, k - 10), j1 = min(L_ - 1, k + 10);
  float acc[8] = {};
  for (int j = j0; j <= j1; ++j) {
    const float w = edge_norm[b * EPB_ + edge_prefix(j) + (k - max(0, j - 10))];
    bf16x8 v = *(const bf16x8*)&catb[(size_t)(b * L_ + j) * 512 + 256 + lane * 8];
#pragma unroll
    for (int i = 0; i < 8; ++i) acc[i] = fmaf(b2f((ushort)v[i]), w, acc[i]);
  }
  bf16x8 o;
#pragma unroll
  for (int i = 0; i < 8; ++i) o[i] = (short)f2b(acc[i]);
  *(bf16x8*)&catb[(size_t)n * 512 + lane * 8] = o;
}

// ------------- final tiny GEMM: out = hid(bf16) @ clf2_w^T + clf2_b --------
__global__ __launch_bounds__(256)
void clf2_kernel(const ushort* __restrict__ hid, const float* __restrict__ w,
                 const float* __restrict__ bias, float* __restrict__ out)
{
  __shared__ float wsm[7 * H_];
  const int tid = threadIdx.x;
  for (int i = tid; i < 7 * H_; i += 256) wsm[i] = w[i];
  __syncthreads();
  const int idx = blockIdx.x * 256 + threadIdx.x;
  if (idx < N_ * 7) {
    const int n = idx / 7, t = idx - n * 7;
    const ushort* hp = hid + (size_t)n * H_;
    const float* wp = wsm + t * H_;
    float acc = bias[t];
    for (int d0 = 0; d0 < H_; d0 += 8) {
      bf16x8 v = *(const bf16x8*)(hp + d0);
#pragma unroll
      for (int i = 0; i < 8; ++i) acc = fmaf(b2f((ushort)v[i]), wp[d0 + i], acc);
    }
    out[idx] = acc;
  }
}

extern "C" void kernel_launch(void* const* d_in, const int* in_sizes, int n_in,
                              void* d_out, int out_size, void* d_ws, size_t ws_size,
                              hipStream_t stream)
{
  const float* x          = (const float*)d_in[0];
  const float* in_proj_w  = (const float*)d_in[1];
  const float* in_proj_b  = (const float*)d_in[2];
  const float* out_proj_w = (const float*)d_in[3];
  const float* out_proj_b = (const float*)d_in[4];
  const float* ln1_g      = (const float*)d_in[5];
  const float* ln1_b      = (const float*)d_in[6];
  const float* ff1_w      = (const float*)d_in[7];
  const float* ff1_b      = (const float*)d_in[8];
  const float* ff2_w      = (const float*)d_in[9];
  const float* ff2_b      = (const float*)d_in[10];
  const float* ln2_g      = (const float*)d_in[11];
  const float* ln2_b      = (const float*)d_in[12];
  const float* to_w       = (const float*)d_in[13];
  const float* to_b       = (const float*)d_in[14];
  const float* att_w      = (const float*)d_in[15];
  const float* rgcn_basis = (const float*)d_in[16];
  const float* rgcn_comp  = (const float*)d_in[17];
  const float* rgcn_root  = (const float*)d_in[18];
  const float* rgcn_bias  = (const float*)d_in[19];
  const float* gc_rel_w   = (const float*)d_in[20];
  const float* gc_rel_b   = (const float*)d_in[21];
  const float* gc_root_w  = (const float*)d_in[22];
  const float* clf1_w     = (const float*)d_in[23];
  const float* clf1_b     = (const float*)d_in[24];
  const float* clf2_w     = (const float*)d_in[25];
  const float* clf2_b     = (const float*)d_in[26];
  const int*   speaker    = (const int*)d_in[27];
  float* out = (float*)d_out;
  char* p = (char*)d_ws;

  // ---- workspace regions ----
  // R1 (65MB): wrelTmp f32 -> qkvb bf16 -> ff bf16 -> combo bf16 (N x 2816)
  float*  R1f    = (float*)p;
  ushort* R1b    = (ushort*)p;
  p += (size_t)N_ * 2304 * 4;
  // R2 (21.6MB): aprojB/ffoB bf16 (N x 768) ; tail: edge_norm f32
  ushort* aprojB = (ushort*)p;
  ushort* ffoB   = aprojB;
  float*  en     = (float*)(p + (size_t)N_ * 512 * 4);
  p += (size_t)N_ * 768 * 4;
  // R3 (21.6MB): vt bf16 (attn) -> hbuf f32 -> hidB bf16
  float*  hbuf  = (float*)p;
  ushort* vt    = (ushort*)p;
  ushort* hidB  = (ushort*)p;
  p += (size_t)N_ * 768 * 4;
  // R4 (10.8MB): xb -> ctxb
  ushort* xb    = (ushort*)p;
  ushort* ctxb  = xb;
  p += (size_t)N_ * 768 * 2;
  // R5 (10.8MB): hb bf16 (N x 768) -> catb bf16 (N x 512: [agg | h1])
  ushort* hb    = (ushort*)p;
  ushort* catb  = hb;
  p += (size_t)N_ * 768 * 2;
  // R6 (10.8MB): fcat bf16 (N x 768: [feats | h2])
  ushort* fcat  = (ushort*)p; p += (size_t)N_ * 768 * 2;
  // R7: bf16 weights
  ushort* in_projb = (ushort*)p; p += (size_t)2304 * 768 * 2;
  ushort* out_projb= (ushort*)p; p += (size_t)768 * 768 * 2;
  ushort* ff1b     = (ushort*)p; p += (size_t)2048 * 768 * 2;
  ushort* ff2b     = (ushort*)p; p += (size_t)768 * 2048 * 2;
  ushort* tob      = (ushort*)p; p += (size_t)512 * 768 * 2;
  ushort* combw    = (ushort*)p; p += (size_t)NC_ * 512 * 2;  // [attw_t|wrel_t|root_t]
  ushort* gccat    = (ushort*)p; p += (size_t)256 * 512 * 2;
  ushort* clf1b16  = (ushort*)p; p += (size_t)256 * 768 * 2;
  float*  bias_comb= (float*)p;  p += NC_ * 4;
  float*  wrelTmp  = R1f;   // consumed before qkv GEMM

  // ---- weight/input prep ----
  Segs7 segs;
  segs.in[0] = x;          segs.out[0] = xb;        segs.n4[0] = N_ * 768 / 4;
  segs.in[1] = in_proj_w;  segs.out[1] = in_projb;  segs.n4[1] = 2304 * 768 / 4;
  segs.in[2] = out_proj_w; segs.out[2] = out_projb; segs.n4[2] = 768 * 768 / 4;
  segs.in[3] = ff1_w;      segs.out[3] = ff1b;      segs.n4[3] = 2048 * 768 / 4;
  segs.in[4] = ff2_w;      segs.out[4] = ff2b;      segs.n4[4] = 768 * 2048 / 4;
  segs.in[5] = to_w;       segs.out[5] = tob;       segs.n4[5] = 512 * 768 / 4;
  segs.in[6] = clf1_w;     segs.out[6] = clf1b16;   segs.n4[6] = 256 * 768 / 4;
  cvtmulti_kernel<<<dim3(768, 7), 256, 0, stream>>>(segs);
  prepmisc_kernel<<<(NC_ + 65536 + 64 * 768 * 18 + 255) / 256, 256, 0, stream>>>(
      rgcn_bias, gc_rel_w, gc_root_w, bias_comb, gccat, vt);
  // combw rows 0..511 = att_w^T
  tcvt_kernel<<<dim3(16, 16, 1), 256, 0, stream>>>(att_w, combw, 512, 512, 0, 0);
  wrel_kernel<<<512, 256, 0, stream>>>(rgcn_basis, rgcn_comp, wrelTmp);
  // combw rows 512..2559 = wrel^T (8 relations)
  tcvt_kernel<<<dim3(8, 16, 8), 256, 0, stream>>>(wrelTmp, combw + (size_t)512 * 512,
                                                  512, 256,
                                                  (size_t)512 * 256, (size_t)256 * 512);
  // combw rows 2560..2815 = root^T
  tcvt_kernel<<<dim3(8, 16, 1), 256, 0, stream>>>(rgcn_root, combw + (size_t)2560 * 512,
                                                  512, 256, 0, 0);

  // ---- main pipeline ----
  // qkvb = bf16(x @ in_proj^T + b), V part also emitted transposed to vt
  mgemm_kernel<true, false, true, true><<<dim3(18, 55), 256, 0, stream>>>(
      xb, in_projb, in_proj_b, R1b, vt, 768, 768, 768, 2304);
  attnM_kernel<<<448, 256, 0, stream>>>(R1b, vt, ctxb);
  // aprojB = bf16(ctx @ out_proj^T + b)
  mgemm_kernel<true, false, true, false><<<dim3(6, 55), 256, 0, stream>>>(
      ctxb, out_projb, out_proj_b, aprojB, nullptr, 768, 768, 768, 768);
  ln_kernel<true><<<N_, 256, 0, stream>>>(x, aprojB, ln1_g, ln1_b, hbuf, hb);
  // ff = relu(h @ ff1^T + b)  (bf16)
  mgemm_kernel<true, true, true, false><<<dim3(16, 55), 256, 0, stream>>>(
      hb, ff1b, ff1_b, R1b, nullptr, 768, 768, 768, 2048);
  // ffoB = bf16(ff @ ff2^T + b)
  mgemm_kernel<true, false, true, false><<<dim3(6, 55), 256, 0, stream>>>(
      R1b, ff2b, ff2_b, ffoB, nullptr, 2048, 2048, 2048, 768);
  ln_kernel<false><<<N_, 256, 0, stream>>>(hbuf, ffoB, ln2_g, ln2_b, nullptr, hb);
  // feats(bf16) -> fcat[:, 0:512]   (ldc = 768)
  mgemm_kernel<true, false, true, false><<<dim3(4, 55), 256, 0, stream>>>(
      hb, tob, to_b, fcat, nullptr, 768, 768, 768, 768);
  // combo = bf16(feats @ [attw_t | wrel_t | root_t]^T + bias_comb) (N x 2816)
  mgemm_kernel<true, false, true, false><<<dim3(22, 55), 256, 0, stream>>>(
      fcat, combw, bias_comb, R1b, nullptr, 512, 768, 512, NC_);
  graphfront_kernel<<<N_ / 8 + N_, 256, 0, stream>>>(R1b, fcat, speaker, catb, en);
  gcn_gather2_kernel<<<N_ / 8, 256, 0, stream>>>(en, catb);
  // h2(bf16) -> fcat[:, 512:768] : [agg|h1] @ [gc_rel|gc_root]^T + gc_rel_b
  mgemm_kernel<true, false, true, false><<<dim3(2, 55), 256, 0, stream>>>(
      catb, gccat, gc_rel_b, fcat + 512, nullptr, 512, 512, 512, 768);
  // hidB = bf16(relu(fcat @ clf1^T + b))   (K = 768)
  mgemm_kernel<true, true, true, false><<<dim3(2, 55), 256, 0, stream>>>(
      fcat, clf1b16, clf1_b, hidB, nullptr, 768, 768, 768, 256);
  clf2_kernel<<<(N_ * 7 + 255) / 256, 256, 0, stream>>>(hidB, clf2_w, clf2_b, out);
}

// Round 9
// 322.183 us; speedup vs baseline: 7.1593x; 1.0463x over previous
//
#include <hip/hip_runtime.h>
#include <hip/hip_bf16.h>
#include <math.h>

#define L_   110
#define B_   64
#define N_   7040
#define U_   768
#define G_   512
#define H_   256
#define FF_  2048
#define EPB_ 2200
#define NC_  2816   // combined att_w(512) + wrel(2048) + root(256)

typedef __attribute__((ext_vector_type(4))) float f32x4;
typedef __attribute__((ext_vector_type(8))) short bf16x8;

__device__ __forceinline__ ushort f2b(float f) {
  union { __hip_bfloat16 h; ushort u; } cv;
  cv.h = __float2bfloat16(f);
  return cv.u;
}
__device__ __forceinline__ float b2f(ushort u) {
  union { float f; unsigned int i; } cv; cv.i = ((unsigned int)u) << 16; return cv.f;
}

// prefix(j) = number of edges with src-row j' < j within one dialogue
__device__ __forceinline__ int edge_prefix(int j) {
  if (j <= 10)  return j * 11 + (j * (j - 1)) / 2;
  if (j <= 100) return 155 + (j - 10) * 21;
  return 2045 + ((141 - j) * (j - 100)) / 2;
}

// ------------- multi-segment f32->bf16 convert (one launch for 7 arrays) ---
struct Segs7 { const float* in[7]; ushort* out[7]; int n4[7]; };

__global__ __launch_bounds__(256)
void cvtmulti_kernel(Segs7 s)
{
  const int seg = blockIdx.y;
  const int n4 = s.n4[seg];
  const float* __restrict__ in = s.in[seg];
  ushort* __restrict__ out = s.out[seg];
  for (int i = blockIdx.x * 256 + threadIdx.x; i < n4; i += gridDim.x * 256) {
    float4 v = ((const float4*)in)[i];
    ushort4 o;
    o.x = f2b(v.x); o.y = f2b(v.y); o.z = f2b(v.z); o.w = f2b(v.w);
    ((ushort4*)out)[i] = o;
  }
}

// ---------- batched tiled transpose+convert: in (R,C) f32 -> out (C,R) bf16
__global__ __launch_bounds__(256)
void tcvt_kernel(const float* __restrict__ in, ushort* __restrict__ out,
                 int R, int C, size_t inStride, size_t outStride)
{
  __shared__ float t[32][33];
  const int bt = blockIdx.z;
  const int r0 = blockIdx.y * 32, c0 = blockIdx.x * 32;
  const int tx = threadIdx.x & 31, ty = threadIdx.x >> 5;
  for (int i = ty; i < 32; i += 8)
    t[i][tx] = in[bt * inStride + (size_t)(r0 + i) * C + c0 + tx];
  __syncthreads();
  for (int i = ty; i < 32; i += 8)
    out[bt * outStride + (size_t)(c0 + i) * R + r0 + tx] = f2b(t[tx][i]);
}

// -------- w_rel[r](g,h) = sum_b comp[r,b]*basis[b](g,h) -> f32 temp --------
__global__ __launch_bounds__(256)
void wrel_kernel(const float* __restrict__ basis, const float* __restrict__ comp,
                 float* __restrict__ wrel)
{
  __shared__ float cs[240];
  const int tid = threadIdx.x;
  if (tid < 240) cs[tid] = comp[tid];
  __syncthreads();
  const int gh = blockIdx.x * 256 + tid;
  float acc[8] = {};
  for (int bb = 0; bb < 30; ++bb) {
    float v = basis[(size_t)bb * (G_ * H_) + gh];
#pragma unroll
    for (int r = 0; r < 8; ++r) acc[r] = fmaf(cs[r * 30 + bb], v, acc[r]);
  }
#pragma unroll
  for (int r = 0; r < 8; ++r) wrel[(size_t)r * (G_ * H_) + gh] = acc[r];
}

// ---- prep misc: bias_comb + gccat (one launch) ----------------------------
__global__ __launch_bounds__(256)
void prepmisc_kernel(const float* __restrict__ rb, const float* __restrict__ rel,
                     const float* __restrict__ root, float* __restrict__ bias,
                     ushort* __restrict__ gccat)
{
  const int i = blockIdx.x * 256 + threadIdx.x;
  if (i < NC_) {
    bias[i] = (i < 2560) ? 0.f : rb[i - 2560];
  } else if (i < NC_ + 65536) {
    const int j = i - NC_;
    const int r = j >> 8, c = j & 255;
    gccat[(size_t)r * 512 + c]       = f2b(rel[j]);
    gccat[(size_t)r * 512 + 256 + c] = f2b(root[j]);
  }
}

// ===================== bf16 MFMA GEMM: Cb = bf16(A @ B^T (+bias)(relu)) ====
// XCD-aware bijective block remap (m204): each XCD owns a contiguous chunk of
// the x-fastest linear block order (A-panel reuse within one XCD's L2).
template<bool BIAS, bool RELU>
__global__ __launch_bounds__(256)
void mgemm_kernel(const ushort* __restrict__ A, const ushort* __restrict__ B,
                  const float* __restrict__ bias, ushort* __restrict__ Cb,
                  int K, int lda, int ldb, int ldc)
{
  __shared__ ushort sA[128 * 64];
  __shared__ ushort sB[128 * 64];
  const int tid = threadIdx.x;
  const int w = tid >> 6, l = tid & 63;

  // ---- XCD swizzle ----
  const int gx = gridDim.x;
  const int nwg = gx * gridDim.y;
  const int lid = blockIdx.y * gx + blockIdx.x;
  const int q = nwg >> 3, r = nwg & 7;
  const int xcd = lid & 7, pos = lid >> 3;
  const int nlid = (xcd < r ? xcd * (q + 1) : r * (q + 1) + (xcd - r) * q) + pos;
  const int m0 = (nlid / gx) * 128, n0 = (nlid % gx) * 128;

  const int srow = l >> 3, sg = l & 7, rbase = w * 32;
  const int wr = w >> 1, wc = w & 1;
  const int lrow = l & 15, lk = l >> 4;
  const int xm = (l & 7) << 4;
  const int kb0 = (lk * 16) ^ xm;
  int aoff[4], boff[4];
#pragma unroll
  for (int i = 0; i < 4; ++i) {
    aoff[i] = (wr * 64 + i * 16 + lrow) * 128 + kb0;
    boff[i] = (wc * 64 + i * 16 + lrow) * 128 + kb0;
  }

  f32x4 acc[4][4];
#pragma unroll
  for (int i = 0; i < 4; ++i)
#pragma unroll
    for (int j = 0; j < 4; ++j) acc[i][j] = (f32x4){0.f, 0.f, 0.f, 0.f};

#define STAGE(k0)                                                              \
  {                                                                            \
    _Pragma("unroll")                                                          \
    for (int i = 0; i < 4; ++i) {                                              \
      const int trow = rbase + i * 8 + srow;                                   \
      const int koff = (sg * 8) ^ ((trow & 7) << 3);                           \
      const ushort* ga = A + (size_t)(m0 + trow) * lda + (k0) + koff;          \
      const ushort* gb = B + (size_t)(n0 + trow) * ldb + (k0) + koff;          \
      __builtin_amdgcn_global_load_lds(                                        \
          (const __attribute__((address_space(1))) void*)ga,                   \
          (__attribute__((address_space(3))) void*)&sA[(rbase + i * 8) * 64],  \
          16, 0, 0);                                                           \
      __builtin_amdgcn_global_load_lds(                                        \
          (const __attribute__((address_space(1))) void*)gb,                   \
          (__attribute__((address_space(3))) void*)&sB[(rbase + i * 8) * 64],  \
          16, 0, 0);                                                           \
    }                                                                          \
  }

  STAGE(0)
  for (int kt = 0;;) {
    __syncthreads();
#pragma unroll
    for (int h = 0; h < 2; ++h) {
      const int hx = h * 64;
      bf16x8 af[4], bfr[4];
#pragma unroll
      for (int i = 0; i < 4; ++i) {
        af[i]  = *(const bf16x8*)&sA[(aoff[i] ^ hx) >> 1];
        bfr[i] = *(const bf16x8*)&sB[(boff[i] ^ hx) >> 1];
      }
#pragma unroll
      for (int mi = 0; mi < 4; ++mi)
#pragma unroll
        for (int ni = 0; ni < 4; ++ni)
          acc[mi][ni] = __builtin_amdgcn_mfma_f32_16x16x32_bf16(
              af[mi], bfr[ni], acc[mi][ni], 0, 0, 0);
    }
    kt += 64;
    if (kt >= K) break;
    __syncthreads();
    STAGE(kt)
  }
#undef STAGE

  const int orow = m0 + wr * 64 + lk * 4;
  const int ocol = n0 + wc * 64 + lrow;
#pragma unroll
  for (int mi = 0; mi < 4; ++mi) {
#pragma unroll
    for (int r2 = 0; r2 < 4; ++r2) {
      const int row = orow + mi * 16 + r2;
#pragma unroll
      for (int ni = 0; ni < 4; ++ni) {
        const int col = ocol + ni * 16;
        float v = acc[mi][ni][r2];
        if constexpr (BIAS) v += bias[col];
        if constexpr (RELU) v = fmaxf(v, 0.f);
        Cb[(size_t)row * ldc + col] = f2b(v);
      }
    }
  }
}

// -------- V transpose: qkvb V block (110x768) -> vt (768x128), pad 0 -------
__global__ __launch_bounds__(256)
void vtrans_kernel(const ushort* __restrict__ qkvb, ushort* __restrict__ vt)
{
  __shared__ ushort t[32][33];
  const int b = blockIdx.z;
  const int r0 = blockIdx.y * 32;   // V row (k), 0..127
  const int c0 = blockIdx.x * 32;   // V col (d), 0..767
  const int tx = threadIdx.x & 31, ty = threadIdx.x >> 5;
  for (int i = ty; i < 32; i += 8) {
    const int r = r0 + i;
    t[i][tx] = (r < L_) ? qkvb[((size_t)(b * L_) + r) * 2304 + 1536 + c0 + tx]
                        : (ushort)0;
  }
  __syncthreads();
  for (int i = ty; i < 32; i += 8)
    vt[((size_t)b * 768 + c0 + i) * 128 + r0 + tx] = t[tx][i];
}

// -------- MFMA attention: 448 blocks, XCD-grouped so one dialogue's 7 ------
// q-blocks share an XCD's L2 (K/V fetched once per dialogue per XCD).
__global__ __launch_bounds__(256)
void attnM_kernel(const ushort* __restrict__ qkvb, const ushort* __restrict__ vt,
                  ushort* __restrict__ ctxb)
{
  const int wg = blockIdx.x;
  const int xcd = wg & 7, slot = wg >> 3;
  const int b = xcd * 8 + slot / 7;
  const int qr0 = (slot % 7) * 16;
  const int tid = threadIdx.x, w = tid >> 6, l = tid & 63;
  __shared__ float  sS[16 * 128];
  __shared__ ushort sP[16 * 128];   // bf16, 16B-group XOR swizzle
  const int lrow = l & 15, lq = l >> 4;

  // ---- QK^T ----
  const ushort* Qbase = qkvb + ((size_t)(b * L_) + qr0 + lrow) * 2304 + lq * 8;
  f32x4 accS[2] = {{0.f,0.f,0.f,0.f},{0.f,0.f,0.f,0.f}};
  const int nf0 = w * 2;
  for (int k0 = 0; k0 < 768; k0 += 32) {
    bf16x8 aq = *(const bf16x8*)(Qbase + k0);
#pragma unroll
    for (int f = 0; f < 2; ++f) {
      const int nf = nf0 + f;
      if (nf < 7) {
        const ushort* Kp = qkvb + ((size_t)(b * L_) + nf * 16 + lrow) * 2304
                         + 768 + k0 + lq * 8;
        bf16x8 bk = *(const bf16x8*)Kp;
        accS[f] = __builtin_amdgcn_mfma_f32_16x16x32_bf16(aq, bk, accS[f], 0, 0, 0);
      }
    }
  }
  const float scale = 0.03608439182435161f;  // 1/sqrt(768)
#pragma unroll
  for (int f = 0; f < 2; ++f) {
    const int nf = nf0 + f;
    if (nf < 7) {
#pragma unroll
      for (int r = 0; r < 4; ++r)
        sS[(lq * 4 + r) * 128 + nf * 16 + lrow] = accS[f][r] * scale;
    }
  }
  __syncthreads();

  // ---- softmax: wave w -> rows 4w..4w+3, 16 lanes per row ----
  {
    const int row = w * 4 + lq;
    const int c0 = lrow;
    float m = -1e30f;
    for (int c = c0; c < L_; c += 16) m = fmaxf(m, sS[row * 128 + c]);
#pragma unroll
    for (int off = 8; off; off >>= 1) m = fmaxf(m, __shfl_xor(m, off));
    float pv[7];
    float sum = 0.f;
#pragma unroll
    for (int i = 0; i < 7; ++i) {
      const int c = c0 + i * 16;
      float e = (c < L_) ? __expf(sS[row * 128 + c] - m) : 0.f;
      pv[i] = e; sum += e;
    }
#pragma unroll
    for (int off = 8; off; off >>= 1) sum += __shfl_xor(sum, off);
    const float inv = 1.f / sum;
#pragma unroll
    for (int i = 0; i < 8; ++i) {
      const int c = c0 + i * 16;
      ushort pb = (i < 7 && c < L_) ? f2b(pv[i < 7 ? i : 0] * inv) : (ushort)0;
      const int g = (c >> 3) ^ (row & 7);
      sP[row * 128 + g * 8 + (c & 7)] = pb;
    }
  }
  __syncthreads();

  // ---- PV: wave w covers ctx cols [192w, 192w+192) = 12 frags, K=128 ----
  f32x4 accO[12];
#pragma unroll
  for (int i = 0; i < 12; ++i) accO[i] = (f32x4){0.f, 0.f, 0.f, 0.f};
#pragma unroll
  for (int ks = 0; ks < 4; ++ks) {
    const int k = ks * 32 + lq * 8;
    const int g = (k >> 3) ^ (lrow & 7);
    bf16x8 ap = *(const bf16x8*)&sP[lrow * 128 + g * 8];
#pragma unroll
    for (int i = 0; i < 12; ++i) {
      const int col = w * 192 + i * 16 + lrow;
      bf16x8 bv = *(const bf16x8*)(vt + ((size_t)b * 768 + col) * 128 + k);
      accO[i] = __builtin_amdgcn_mfma_f32_16x16x32_bf16(ap, bv, accO[i], 0, 0, 0);
    }
  }
#pragma unroll
  for (int i = 0; i < 12; ++i) {
    const int col = w * 192 + i * 16 + lrow;
#pragma unroll
    for (int r = 0; r < 4; ++r) {
      const int row = qr0 + lq * 4 + r;
      if (row < L_)
        ctxb[((size_t)b * L_ + row) * 768 + col] = f2b(accO[i][r]);
    }
  }
}

// ------- LayerNorm(A + Bres[bf16]) -> bf16.  A is f32 (AF32) or bf16. ------
template<bool AF32>
__global__ __launch_bounds__(256)
void ln_kernel(const float* __restrict__ Af, const ushort* __restrict__ Ab,
               const ushort* __restrict__ Bres,
               const float* __restrict__ g, const float* __restrict__ beta,
               ushort* __restrict__ outb)
{
  const int row = blockIdx.x, tid = threadIdx.x;
  const ushort* bp = Bres + (size_t)row * U_;
  float a0, a1, a2;
  if constexpr (AF32) {
    const float* ap = Af + (size_t)row * U_;
    a0 = ap[tid]; a1 = ap[tid + 256]; a2 = ap[tid + 512];
  } else {
    const ushort* ap = Ab + (size_t)row * U_;
    a0 = b2f(ap[tid]); a1 = b2f(ap[tid + 256]); a2 = b2f(ap[tid + 512]);
  }
  float v0 = a0 + b2f(bp[tid]);
  float v1 = a1 + b2f(bp[tid + 256]);
  float v2 = a2 + b2f(bp[tid + 512]);
  float s = v0 + v1 + v2, sq = v0 * v0 + v1 * v1 + v2 * v2;
  __shared__ float red[8];
#pragma unroll
  for (int off = 32; off; off >>= 1) { s += __shfl_xor(s, off); sq += __shfl_xor(sq, off); }
  const int wave = tid >> 6, lane = tid & 63;
  if (lane == 0) { red[wave] = s; red[4 + wave] = sq; }
  __syncthreads();
  if (tid == 0) {
    float ts = red[0] + red[1] + red[2] + red[3];
    float tq = red[4] + red[5] + red[6] + red[7];
    float m = ts * (1.f / 768.f);
    float var = tq * (1.f / 768.f) - m * m;
    red[0] = m; red[1] = 1.f / sqrtf(var + 1e-5f);
  }
  __syncthreads();
  const float m = red[0], inv = red[1];
  ushort* ob = outb + (size_t)row * U_;
  ob[tid]       = f2b((v0 - m) * inv * g[tid]       + beta[tid]);
  ob[tid + 256] = f2b((v1 - m) * inv * g[tid + 256] + beta[tid + 256]);
  ob[tid + 512] = f2b((v2 - m) * inv * g[tid + 512] + beta[tid + 512]);
}

// ---- graph front: role-split {RGCN gather | edge softmax}, both read combo
__global__ __launch_bounds__(256)
void graphfront_kernel(const ushort* __restrict__ combo, const ushort* __restrict__ fcat,
                       const int* __restrict__ speaker,
                       ushort* __restrict__ catb, float* __restrict__ edge_norm)
{
  const int tid = threadIdx.x;
  if (blockIdx.x < N_ / 8) {
    // ---- RGCN gather: 8 nodes/block, 32 lanes/node ----
    const int n = blockIdx.x * 8 + (tid >> 5);
    const int lane = tid & 31;
    const int b = n / L_, k = n - b * L_;
    const int j0 = max(0, k - 10), j1 = min(L_ - 1, k + 10);
    const int spk = speaker[n];
    float inv[4];
    {
      int cn[4] = {0, 0, 0, 0};
      for (int j = j0; j <= j1; ++j)
        cn[speaker[b * L_ + j] * 2 + (j >= k ? 1 : 0)]++;
#pragma unroll
      for (int q = 0; q < 4; ++q) inv[q] = cn[q] ? 1.f / (float)cn[q] : 0.f;
    }
    float acc[8] = {};
    for (int j = j0; j <= j1; ++j) {
      const int spj = speaker[b * L_ + j];
      const int c = (j >= k) ? 1 : 0;
      const int et = (spj * 2 + spk) * 2 + c;
      const float w = inv[spj * 2 + c];
      bf16x8 v = *(const bf16x8*)&combo[(size_t)(b * L_ + j) * NC_ + 512 + et * 256 + lane * 8];
#pragma unroll
      for (int i = 0; i < 8; ++i) acc[i] = fmaf(b2f((ushort)v[i]), w, acc[i]);
    }
    bf16x8 rt = *(const bf16x8*)&combo[(size_t)n * NC_ + 2560 + lane * 8];
    bf16x8 o;
#pragma unroll
    for (int i = 0; i < 8; ++i) o[i] = (short)f2b(acc[i] + b2f((ushort)rt[i]));
    *(bf16x8*)&catb[(size_t)n * 512 + 256 + lane * 8] = o;
  } else {
    // ---- windowed edge softmax ----
    const int bj = blockIdx.x - N_ / 8;
    const int b = bj / L_, j = bj - b * L_;
    const int k0 = max(0, j - 10), k1 = min(L_ - 1, j + 10);
    __shared__ float s[32];
    const int wave = tid >> 6, lane = tid & 63;
    float tr[8];
    {
      bf16x8 tv = *(const bf16x8*)&combo[(size_t)bj * NC_ + lane * 8];
#pragma unroll
      for (int i = 0; i < 8; ++i) tr[i] = b2f((ushort)tv[i]);
    }
    for (int k = k0 + wave; k <= k1; k += 4) {
      bf16x8 v = *(const bf16x8*)&fcat[(size_t)(b * L_ + k) * 768 + lane * 8];
      float sc = 0.f;
#pragma unroll
      for (int i = 0; i < 8; ++i) sc = fmaf(b2f((ushort)v[i]), tr[i], sc);
#pragma unroll
      for (int off = 32; off; off >>= 1) sc += __shfl_xor(sc, off);
      if (lane == 0) s[k - k0] = sc;
    }
    __syncthreads();
    if (tid == 0) {
      const int W = k1 - k0 + 1;
      float m = -1e30f;
      for (int t = 0; t < W; ++t) m = fmaxf(m, s[t]);
      float sum = 0.f;
      for (int t = 0; t < W; ++t) { float e = __expf(s[t] - m); s[t] = e; sum += e; }
      const float inv = 1.f / sum;
      const int base = b * EPB_ + edge_prefix(j);
      for (int t = 0; t < W; ++t) edge_norm[base + t] = s[t] * inv;
    }
  }
}

// -------- GraphConv gather: reads h1 bf16 (catb[:,256:512]) -> agg ---------
__global__ __launch_bounds__(256)
void gcn_gather2_kernel(const float* __restrict__ edge_norm,
                        ushort* __restrict__ catb)
{
  const int tid = threadIdx.x;
  const int n = blockIdx.x * 8 + (tid >> 5);
  const int lane = tid & 31;
  const int b = n / L_, k = n - b * L_;
  const int j0 = max(0, k - 10), j1 = min(L_ - 1, k + 10);
  float acc[8] = {};
  for (int j = j0; j <= j1; ++j) {
    const float w = edge_norm[b * EPB_ + edge_prefix(j) + (k - max(0, j - 10))];
    bf16x8 v = *(const bf16x8*)&catb[(size_t)(b * L_ + j) * 512 + 256 + lane * 8];
#pragma unroll
    for (int i = 0; i < 8; ++i) acc[i] = fmaf(b2f((ushort)v[i]), w, acc[i]);
  }
  bf16x8 o;
#pragma unroll
  for (int i = 0; i < 8; ++i) o[i] = (short)f2b(acc[i]);
  *(bf16x8*)&catb[(size_t)n * 512 + lane * 8] = o;
}

// ------------- final tiny GEMM: out = hid(bf16) @ clf2_w^T + clf2_b --------
__global__ __launch_bounds__(256)
void clf2_kernel(const ushort* __restrict__ hid, const float* __restrict__ w,
                 const float* __restrict__ bias, float* __restrict__ out)
{
  __shared__ float wsm[7 * H_];
  const int tid = threadIdx.x;
  for (int i = tid; i < 7 * H_; i += 256) wsm[i] = w[i];
  __syncthreads();
  const int idx = blockIdx.x * 256 + threadIdx.x;
  if (idx < N_ * 7) {
    const int n = idx / 7, t = idx - n * 7;
    const ushort* hp = hid + (size_t)n * H_;
    const float* wp = wsm + t * H_;
    float acc = bias[t];
    for (int d0 = 0; d0 < H_; d0 += 8) {
      bf16x8 v = *(const bf16x8*)(hp + d0);
#pragma unroll
      for (int i = 0; i < 8; ++i) acc = fmaf(b2f((ushort)v[i]), wp[d0 + i], acc);
    }
    out[idx] = acc;
  }
}

extern "C" void kernel_launch(void* const* d_in, const int* in_sizes, int n_in,
                              void* d_out, int out_size, void* d_ws, size_t ws_size,
                              hipStream_t stream)
{
  const float* x          = (const float*)d_in[0];
  const float* in_proj_w  = (const float*)d_in[1];
  const float* in_proj_b  = (const float*)d_in[2];
  const float* out_proj_w = (const float*)d_in[3];
  const float* out_proj_b = (const float*)d_in[4];
  const float* ln1_g      = (const float*)d_in[5];
  const float* ln1_b      = (const float*)d_in[6];
  const float* ff1_w      = (const float*)d_in[7];
  const float* ff1_b      = (const float*)d_in[8];
  const float* ff2_w      = (const float*)d_in[9];
  const float* ff2_b      = (const float*)d_in[10];
  const float* ln2_g      = (const float*)d_in[11];
  const float* ln2_b      = (const float*)d_in[12];
  const float* to_w       = (const float*)d_in[13];
  const float* to_b       = (const float*)d_in[14];
  const float* att_w      = (const float*)d_in[15];
  const float* rgcn_basis = (const float*)d_in[16];
  const float* rgcn_comp  = (const float*)d_in[17];
  const float* rgcn_root  = (const float*)d_in[18];
  const float* rgcn_bias  = (const float*)d_in[19];
  const float* gc_rel_w   = (const float*)d_in[20];
  const float* gc_rel_b   = (const float*)d_in[21];
  const float* gc_root_w  = (const float*)d_in[22];
  const float* clf1_w     = (const float*)d_in[23];
  const float* clf1_b     = (const float*)d_in[24];
  const float* clf2_w     = (const float*)d_in[25];
  const float* clf2_b     = (const float*)d_in[26];
  const int*   speaker    = (const int*)d_in[27];
  float* out = (float*)d_out;
  char* p = (char*)d_ws;

  // ---- workspace regions ----
  // R1 (65MB): wrelTmp f32 -> qkvb bf16 -> ff bf16 -> combo bf16 (N x 2816)
  float*  R1f    = (float*)p;
  ushort* R1b    = (ushort*)p;
  p += (size_t)N_ * 2304 * 4;
  // R2 (21.6MB): aprojB/ffoB bf16 (N x 768) ; tail: edge_norm f32
  ushort* aprojB = (ushort*)p;
  ushort* ffoB   = aprojB;
  float*  en     = (float*)(p + (size_t)N_ * 512 * 4);
  p += (size_t)N_ * 768 * 4;
  // R3 (21.6MB): vt bf16 (attn) -> hidB bf16
  ushort* vt    = (ushort*)p;
  ushort* hidB  = (ushort*)p;
  p += (size_t)N_ * 768 * 4;
  // R4 (10.8MB): xb -> ctxb
  ushort* xb    = (ushort*)p;
  ushort* ctxb  = xb;
  p += (size_t)N_ * 768 * 2;
  // R5 (10.8MB): hb bf16 (N x 768) -> catb bf16 (N x 512: [agg | h1])
  ushort* hb    = (ushort*)p;
  ushort* catb  = hb;
  p += (size_t)N_ * 768 * 2;
  // R6 (10.8MB): fcat bf16 (N x 768: [feats | h2])
  ushort* fcat  = (ushort*)p; p += (size_t)N_ * 768 * 2;
  // R7: bf16 weights
  ushort* in_projb = (ushort*)p; p += (size_t)2304 * 768 * 2;
  ushort* out_projb= (ushort*)p; p += (size_t)768 * 768 * 2;
  ushort* ff1b     = (ushort*)p; p += (size_t)2048 * 768 * 2;
  ushort* ff2b     = (ushort*)p; p += (size_t)768 * 2048 * 2;
  ushort* tob      = (ushort*)p; p += (size_t)512 * 768 * 2;
  ushort* combw    = (ushort*)p; p += (size_t)NC_ * 512 * 2;  // [attw_t|wrel_t|root_t]
  ushort* gccat    = (ushort*)p; p += (size_t)256 * 512 * 2;
  ushort* clf1b16  = (ushort*)p; p += (size_t)256 * 768 * 2;
  float*  bias_comb= (float*)p;  p += NC_ * 4;
  float*  wrelTmp  = R1f;   // consumed before qkv GEMM

  // ---- weight/input prep ----
  Segs7 segs;
  segs.in[0] = x;          segs.out[0] = xb;        segs.n4[0] = N_ * 768 / 4;
  segs.in[1] = in_proj_w;  segs.out[1] = in_projb;  segs.n4[1] = 2304 * 768 / 4;
  segs.in[2] = out_proj_w; segs.out[2] = out_projb; segs.n4[2] = 768 * 768 / 4;
  segs.in[3] = ff1_w;      segs.out[3] = ff1b;      segs.n4[3] = 2048 * 768 / 4;
  segs.in[4] = ff2_w;      segs.out[4] = ff2b;      segs.n4[4] = 768 * 2048 / 4;
  segs.in[5] = to_w;       segs.out[5] = tob;       segs.n4[5] = 512 * 768 / 4;
  segs.in[6] = clf1_w;     segs.out[6] = clf1b16;   segs.n4[6] = 256 * 768 / 4;
  cvtmulti_kernel<<<dim3(768, 7), 256, 0, stream>>>(segs);
  prepmisc_kernel<<<(NC_ + 65536 + 255) / 256, 256, 0, stream>>>(
      rgcn_bias, gc_rel_w, gc_root_w, bias_comb, gccat);
  // combw rows 0..511 = att_w^T
  tcvt_kernel<<<dim3(16, 16, 1), 256, 0, stream>>>(att_w, combw, 512, 512, 0, 0);
  wrel_kernel<<<512, 256, 0, stream>>>(rgcn_basis, rgcn_comp, wrelTmp);
  // combw rows 512..2559 = wrel^T (8 relations)
  tcvt_kernel<<<dim3(8, 16, 8), 256, 0, stream>>>(wrelTmp, combw + (size_t)512 * 512,
                                                  512, 256,
                                                  (size_t)512 * 256, (size_t)256 * 512);
  // combw rows 2560..2815 = root^T
  tcvt_kernel<<<dim3(8, 16, 1), 256, 0, stream>>>(rgcn_root, combw + (size_t)2560 * 512,
                                                  512, 256, 0, 0);

  // ---- main pipeline ----
  // qkvb = bf16(x @ in_proj^T + b)
  mgemm_kernel<true, false><<<dim3(18, 55), 256, 0, stream>>>(
      xb, in_projb, in_proj_b, R1b, 768, 768, 768, 2304);
  vtrans_kernel<<<dim3(24, 4, 64), 256, 0, stream>>>(R1b, vt);
  attnM_kernel<<<448, 256, 0, stream>>>(R1b, vt, ctxb);
  // aprojB = bf16(ctx @ out_proj^T + b)
  mgemm_kernel<true, false><<<dim3(6, 55), 256, 0, stream>>>(
      ctxb, out_projb, out_proj_b, aprojB, 768, 768, 768, 768);
  ln_kernel<true><<<N_, 256, 0, stream>>>(x, nullptr, aprojB, ln1_g, ln1_b, hb);
  // ff = relu(h @ ff1^T + b)  (bf16)
  mgemm_kernel<true, true><<<dim3(16, 55), 256, 0, stream>>>(
      hb, ff1b, ff1_b, R1b, 768, 768, 768, 2048);
  // ffoB = bf16(ff @ ff2^T + b)
  mgemm_kernel<true, false><<<dim3(6, 55), 256, 0, stream>>>(
      R1b, ff2b, ff2_b, ffoB, 2048, 2048, 2048, 768);
  ln_kernel<false><<<N_, 256, 0, stream>>>(nullptr, hb, ffoB, ln2_g, ln2_b, hb);
  // feats(bf16) -> fcat[:, 0:512]   (ldc = 768)
  mgemm_kernel<true, false><<<dim3(4, 55), 256, 0, stream>>>(
      hb, tob, to_b, fcat, 768, 768, 768, 768);
  // combo = bf16(feats @ [attw_t | wrel_t | root_t]^T + bias_comb) (N x 2816)
  mgemm_kernel<true, false><<<dim3(22, 55), 256, 0, stream>>>(
      fcat, combw, bias_comb, R1b, 512, 768, 512, NC_);
  graphfront_kernel<<<N_ / 8 + N_, 256, 0, stream>>>(R1b, fcat, speaker, catb, en);
  gcn_gather2_kernel<<<N_ / 8, 256, 0, stream>>>(en, catb);
  // h2(bf16) -> fcat[:, 512:768] : [agg|h1] @ [gc_rel|gc_root]^T + gc_rel_b
  mgemm_kernel<true, false><<<dim3(2, 55), 256, 0, stream>>>(
      catb, gccat, gc_rel_b, fcat + 512, 512, 512, 512, 768);
  // hidB = bf16(relu(fcat @ clf1^T + b))   (K = 768)
  mgemm_kernel<true, true><<<dim3(2, 55), 256, 0, stream>>>(
      fcat, clf1b16, clf1_b, hidB, 768, 768, 768, 256);
  clf2_kernel<<<(N_ * 7 + 255) / 256, 256, 0, stream>>>(hidB, clf2_w, clf2_b, out);
}

// Round 10
// 303.671 us; speedup vs baseline: 7.5957x; 1.0610x over previous
//
#include <hip/hip_runtime.h>
#include <hip/hip_bf16.h>
#include <math.h>

#define L_   110
#define B_   64
#define N_   7040
#define U_   768
#define G_   512
#define H_   256
#define FF_  2048
#define EPB_ 2200
#define NC_  2816   // combined att_w(512) + wrel(2048) + root(256)

typedef __attribute__((ext_vector_type(4))) float f32x4;
typedef __attribute__((ext_vector_type(8))) short bf16x8;

__device__ __forceinline__ ushort f2b(float f) {
  union { __hip_bfloat16 h; ushort u; } cv;
  cv.h = __float2bfloat16(f);
  return cv.u;
}
__device__ __forceinline__ float b2f(ushort u) {
  union { float f; unsigned int i; } cv; cv.i = ((unsigned int)u) << 16; return cv.f;
}

// prefix(j) = number of edges with src-row j' < j within one dialogue
__device__ __forceinline__ int edge_prefix(int j) {
  if (j <= 10)  return j * 11 + (j * (j - 1)) / 2;
  if (j <= 100) return 155 + (j - 10) * 21;
  return 2045 + ((141 - j) * (j - 100)) / 2;
}

// ------ multi-segment prep: 7 f32->bf16 converts + bias_comb + gccat -------
struct Segs7 { const float* in[7]; ushort* out[7]; int n4[7]; };

__global__ __launch_bounds__(256)
void cvtprep_kernel(Segs7 s, const float* __restrict__ rb,
                    const float* __restrict__ rel, const float* __restrict__ root,
                    float* __restrict__ bias, ushort* __restrict__ gccat)
{
  const int seg = blockIdx.y;
  if (seg < 7) {
    const int n4 = s.n4[seg];
    const float* __restrict__ in = s.in[seg];
    ushort* __restrict__ out = s.out[seg];
    for (int i = blockIdx.x * 256 + threadIdx.x; i < n4; i += gridDim.x * 256) {
      float4 v = ((const float4*)in)[i];
      ushort4 o;
      o.x = f2b(v.x); o.y = f2b(v.y); o.z = f2b(v.z); o.w = f2b(v.w);
      ((ushort4*)out)[i] = o;
    }
  } else {
    const int i = blockIdx.x * 256 + threadIdx.x;
    if (i < NC_) {
      bias[i] = (i < 2560) ? 0.f : rb[i - 2560];
    } else if (i < NC_ + 65536) {
      const int j = i - NC_;
      const int r = j >> 8, c = j & 255;
      gccat[(size_t)r * 512 + c]       = f2b(rel[j]);
      gccat[(size_t)r * 512 + 256 + c] = f2b(root[j]);
    }
  }
}

// ---- merged transpose+convert into combw: z=0 att_w, z=1..8 wrel, z=9 root
__global__ __launch_bounds__(256)
void tcvt3_kernel(const float* __restrict__ attw, const float* __restrict__ wrelTmp,
                  const float* __restrict__ root, ushort* __restrict__ combw)
{
  const int z = blockIdx.z;
  const float* in;
  ushort* out;
  int C;
  if (z == 0)      { in = attw; out = combw; C = 512; }
  else if (z <= 8) { if (blockIdx.x >= 8) return;
                     in = wrelTmp + (size_t)(z - 1) * 512 * 256;
                     out = combw + (size_t)(512 + (z - 1) * 256) * 512; C = 256; }
  else             { if (blockIdx.x >= 8) return;
                     in = root; out = combw + (size_t)2560 * 512; C = 256; }
  __shared__ float t[32][33];
  const int r0 = blockIdx.y * 32, c0 = blockIdx.x * 32;
  const int tx = threadIdx.x & 31, ty = threadIdx.x >> 5;
  for (int i = ty; i < 32; i += 8)
    t[i][tx] = in[(size_t)(r0 + i) * C + c0 + tx];
  __syncthreads();
  for (int i = ty; i < 32; i += 8)
    out[(size_t)(c0 + i) * 512 + r0 + tx] = f2b(t[tx][i]);
}

// -------- w_rel[r](g,h) = sum_b comp[r,b]*basis[b](g,h) -> f32 temp --------
__global__ __launch_bounds__(256)
void wrel_kernel(const float* __restrict__ basis, const float* __restrict__ comp,
                 float* __restrict__ wrel)
{
  __shared__ float cs[240];
  const int tid = threadIdx.x;
  if (tid < 240) cs[tid] = comp[tid];
  __syncthreads();
  const int gh = blockIdx.x * 256 + tid;
  float acc[8] = {};
  for (int bb = 0; bb < 30; ++bb) {
    float v = basis[(size_t)bb * (G_ * H_) + gh];
#pragma unroll
    for (int r = 0; r < 8; ++r) acc[r] = fmaf(cs[r * 30 + bb], v, acc[r]);
  }
#pragma unroll
  for (int r = 0; r < 8; ++r) wrel[(size_t)r * (G_ * H_) + gh] = acc[r];
}

// ===================== bf16 MFMA GEMM, 128x128 tile ========================
// XCD-aware bijective block remap (m204).
template<bool BIAS, bool RELU>
__global__ __launch_bounds__(256)
void mgemm_kernel(const ushort* __restrict__ A, const ushort* __restrict__ B,
                  const float* __restrict__ bias, ushort* __restrict__ Cb,
                  int K, int lda, int ldb, int ldc)
{
  __shared__ ushort sA[128 * 64];
  __shared__ ushort sB[128 * 64];
  const int tid = threadIdx.x;
  const int w = tid >> 6, l = tid & 63;

  const int gx = gridDim.x;
  const int nwg = gx * gridDim.y;
  const int lid = blockIdx.y * gx + blockIdx.x;
  const int q = nwg >> 3, r = nwg & 7;
  const int xcd = lid & 7, pos = lid >> 3;
  const int nlid = (xcd < r ? xcd * (q + 1) : r * (q + 1) + (xcd - r) * q) + pos;
  const int m0 = (nlid / gx) * 128, n0 = (nlid % gx) * 128;

  const int srow = l >> 3, sg = l & 7, rbase = w * 32;
  const int wr = w >> 1, wc = w & 1;
  const int lrow = l & 15, lk = l >> 4;
  const int xm = (l & 7) << 4;
  const int kb0 = (lk * 16) ^ xm;
  int aoff[4], boff[4];
#pragma unroll
  for (int i = 0; i < 4; ++i) {
    aoff[i] = (wr * 64 + i * 16 + lrow) * 128 + kb0;
    boff[i] = (wc * 64 + i * 16 + lrow) * 128 + kb0;
  }

  f32x4 acc[4][4];
#pragma unroll
  for (int i = 0; i < 4; ++i)
#pragma unroll
    for (int j = 0; j < 4; ++j) acc[i][j] = (f32x4){0.f, 0.f, 0.f, 0.f};

#define STAGE(k0)                                                              \
  {                                                                            \
    _Pragma("unroll")                                                          \
    for (int i = 0; i < 4; ++i) {                                              \
      const int trow = rbase + i * 8 + srow;                                   \
      const int koff = (sg * 8) ^ ((trow & 7) << 3);                           \
      const ushort* ga = A + (size_t)(m0 + trow) * lda + (k0) + koff;          \
      const ushort* gb = B + (size_t)(n0 + trow) * ldb + (k0) + koff;          \
      __builtin_amdgcn_global_load_lds(                                        \
          (const __attribute__((address_space(1))) void*)ga,                   \
          (__attribute__((address_space(3))) void*)&sA[(rbase + i * 8) * 64],  \
          16, 0, 0);                                                           \
      __builtin_amdgcn_global_load_lds(                                        \
          (const __attribute__((address_space(1))) void*)gb,                   \
          (__attribute__((address_space(3))) void*)&sB[(rbase + i * 8) * 64],  \
          16, 0, 0);                                                           \
    }                                                                          \
  }

  STAGE(0)
  for (int kt = 0;;) {
    __syncthreads();
#pragma unroll
    for (int h = 0; h < 2; ++h) {
      const int hx = h * 64;
      bf16x8 af[4], bfr[4];
#pragma unroll
      for (int i = 0; i < 4; ++i) {
        af[i]  = *(const bf16x8*)&sA[(aoff[i] ^ hx) >> 1];
        bfr[i] = *(const bf16x8*)&sB[(boff[i] ^ hx) >> 1];
      }
#pragma unroll
      for (int mi = 0; mi < 4; ++mi)
#pragma unroll
        for (int ni = 0; ni < 4; ++ni)
          acc[mi][ni] = __builtin_amdgcn_mfma_f32_16x16x32_bf16(
              af[mi], bfr[ni], acc[mi][ni], 0, 0, 0);
    }
    kt += 64;
    if (kt >= K) break;
    __syncthreads();
    STAGE(kt)
  }
#undef STAGE

  const int orow = m0 + wr * 64 + lk * 4;
  const int ocol = n0 + wc * 64 + lrow;
#pragma unroll
  for (int mi = 0; mi < 4; ++mi) {
#pragma unroll
    for (int r2 = 0; r2 < 4; ++r2) {
      const int row = orow + mi * 16 + r2;
#pragma unroll
      for (int ni = 0; ni < 4; ++ni) {
        const int col = ocol + ni * 16;
        float v = acc[mi][ni][r2];
        if constexpr (BIAS) v += bias[col];
        if constexpr (RELU) v = fmaxf(v, 0.f);
        Cb[(size_t)row * ldc + col] = f2b(v);
      }
    }
  }
}

// ===================== bf16 MFMA GEMM, 128x64 tile (narrow N) ==============
// 24KB LDS -> 6 blocks/CU; 2x block count of the 128x128 variant.
// Wave w owns rows [w*32, w*32+32), all 64 cols. Same k-order as mgemm.
template<bool BIAS, bool RELU>
__global__ __launch_bounds__(256)
void mgemm64_kernel(const ushort* __restrict__ A, const ushort* __restrict__ B,
                    const float* __restrict__ bias, ushort* __restrict__ Cb,
                    int K, int lda, int ldb, int ldc)
{
  __shared__ ushort sA[128 * 64];
  __shared__ ushort sB[64 * 64];
  const int tid = threadIdx.x;
  const int w = tid >> 6, l = tid & 63;

  const int gx = gridDim.x;
  const int nwg = gx * gridDim.y;
  const int lid = blockIdx.y * gx + blockIdx.x;
  const int q = nwg >> 3, r = nwg & 7;
  const int xcd = lid & 7, pos = lid >> 3;
  const int nlid = (xcd < r ? xcd * (q + 1) : r * (q + 1) + (xcd - r) * q) + pos;
  const int m0 = (nlid / gx) * 128, n0 = (nlid % gx) * 64;

  const int srow = l >> 3, sg = l & 7;
  const int lrow = l & 15, lk = l >> 4;
  const int xm = (l & 7) << 4;
  const int kb0 = (lk * 16) ^ xm;
  int aoff[2], boff[4];
#pragma unroll
  for (int i = 0; i < 2; ++i) aoff[i] = (w * 32 + i * 16 + lrow) * 128 + kb0;
#pragma unroll
  for (int i = 0; i < 4; ++i) boff[i] = (i * 16 + lrow) * 128 + kb0;

  f32x4 acc[2][4];
#pragma unroll
  for (int i = 0; i < 2; ++i)
#pragma unroll
    for (int j = 0; j < 4; ++j) acc[i][j] = (f32x4){0.f, 0.f, 0.f, 0.f};

#define STAGE64(k0)                                                            \
  {                                                                            \
    _Pragma("unroll")                                                          \
    for (int i = 0; i < 4; ++i) {                                              \
      const int trow = w * 32 + i * 8 + srow;                                  \
      const int koff = (sg * 8) ^ ((trow & 7) << 3);                           \
      const ushort* ga = A + (size_t)(m0 + trow) * lda + (k0) + koff;          \
      __builtin_amdgcn_global_load_lds(                                        \
          (const __attribute__((address_space(1))) void*)ga,                   \
          (__attribute__((address_space(3))) void*)&sA[(w * 32 + i * 8) * 64], \
          16, 0, 0);                                                           \
    }                                                                          \
    _Pragma("unroll")                                                          \
    for (int i = 0; i < 2; ++i) {                                              \
      const int trow = w * 16 + i * 8 + srow;                                  \
      const int koff = (sg * 8) ^ ((trow & 7) << 3);                           \
      const ushort* gb = B + (size_t)(n0 + trow) * ldb + (k0) + koff;          \
      __builtin_amdgcn_global_load_lds(                                        \
          (const __attribute__((address_space(1))) void*)gb,                   \
          (__attribute__((address_space(3))) void*)&sB[(w * 16 + i * 8) * 64], \
          16, 0, 0);                                                           \
    }                                                                          \
  }

  STAGE64(0)
  for (int kt = 0;;) {
    __syncthreads();
#pragma unroll
    for (int h = 0; h < 2; ++h) {
      const int hx = h * 64;
      bf16x8 af[2], bfr[4];
#pragma unroll
      for (int i = 0; i < 2; ++i) af[i] = *(const bf16x8*)&sA[(aoff[i] ^ hx) >> 1];
#pragma unroll
      for (int i = 0; i < 4; ++i) bfr[i] = *(const bf16x8*)&sB[(boff[i] ^ hx) >> 1];
#pragma unroll
      for (int mi = 0; mi < 2; ++mi)
#pragma unroll
        for (int ni = 0; ni < 4; ++ni)
          acc[mi][ni] = __builtin_amdgcn_mfma_f32_16x16x32_bf16(
              af[mi], bfr[ni], acc[mi][ni], 0, 0, 0);
    }
    kt += 64;
    if (kt >= K) break;
    __syncthreads();
    STAGE64(kt)
  }
#undef STAGE64

  const int orow = m0 + w * 32 + lk * 4;
  const int ocol = n0 + lrow;
#pragma unroll
  for (int mi = 0; mi < 2; ++mi) {
#pragma unroll
    for (int r2 = 0; r2 < 4; ++r2) {
      const int row = orow + mi * 16 + r2;
#pragma unroll
      for (int ni = 0; ni < 4; ++ni) {
        const int col = ocol + ni * 16;
        float v = acc[mi][ni][r2];
        if constexpr (BIAS) v += bias[col];
        if constexpr (RELU) v = fmaxf(v, 0.f);
        Cb[(size_t)row * ldc + col] = f2b(v);
      }
    }
  }
}

// -------- V transpose: qkvb V block (110x768) -> vt (768x128), pad 0 -------
__global__ __launch_bounds__(256)
void vtrans_kernel(const ushort* __restrict__ qkvb, ushort* __restrict__ vt)
{
  __shared__ ushort t[32][33];
  const int b = blockIdx.z;
  const int r0 = blockIdx.y * 32;   // V row (k), 0..127
  const int c0 = blockIdx.x * 32;   // V col (d), 0..767
  const int tx = threadIdx.x & 31, ty = threadIdx.x >> 5;
  for (int i = ty; i < 32; i += 8) {
    const int r = r0 + i;
    t[i][tx] = (r < L_) ? qkvb[((size_t)(b * L_) + r) * 2304 + 1536 + c0 + tx]
                        : (ushort)0;
  }
  __syncthreads();
  for (int i = ty; i < 32; i += 8)
    vt[((size_t)b * 768 + c0 + i) * 128 + r0 + tx] = t[tx][i];
}

// -------- MFMA attention: 448 blocks, XCD-grouped ------------------------
__global__ __launch_bounds__(256)
void attnM_kernel(const ushort* __restrict__ qkvb, const ushort* __restrict__ vt,
                  ushort* __restrict__ ctxb)
{
  const int wg = blockIdx.x;
  const int xcd = wg & 7, slot = wg >> 3;
  const int b = xcd * 8 + slot / 7;
  const int qr0 = (slot % 7) * 16;
  const int tid = threadIdx.x, w = tid >> 6, l = tid & 63;
  __shared__ float  sS[16 * 128];
  __shared__ ushort sP[16 * 128];   // bf16, 16B-group XOR swizzle
  const int lrow = l & 15, lq = l >> 4;

  const ushort* Qbase = qkvb + ((size_t)(b * L_) + qr0 + lrow) * 2304 + lq * 8;
  f32x4 accS[2] = {{0.f,0.f,0.f,0.f},{0.f,0.f,0.f,0.f}};
  const int nf0 = w * 2;
  for (int k0 = 0; k0 < 768; k0 += 32) {
    bf16x8 aq = *(const bf16x8*)(Qbase + k0);
#pragma unroll
    for (int f = 0; f < 2; ++f) {
      const int nf = nf0 + f;
      if (nf < 7) {
        const ushort* Kp = qkvb + ((size_t)(b * L_) + nf * 16 + lrow) * 2304
                         + 768 + k0 + lq * 8;
        bf16x8 bk = *(const bf16x8*)Kp;
        accS[f] = __builtin_amdgcn_mfma_f32_16x16x32_bf16(aq, bk, accS[f], 0, 0, 0);
      }
    }
  }
  const float scale = 0.03608439182435161f;  // 1/sqrt(768)
#pragma unroll
  for (int f = 0; f < 2; ++f) {
    const int nf = nf0 + f;
    if (nf < 7) {
#pragma unroll
      for (int r = 0; r < 4; ++r)
        sS[(lq * 4 + r) * 128 + nf * 16 + lrow] = accS[f][r] * scale;
    }
  }
  __syncthreads();

  {
    const int row = w * 4 + lq;
    const int c0 = lrow;
    float m = -1e30f;
    for (int c = c0; c < L_; c += 16) m = fmaxf(m, sS[row * 128 + c]);
#pragma unroll
    for (int off = 8; off; off >>= 1) m = fmaxf(m, __shfl_xor(m, off));
    float pv[7];
    float sum = 0.f;
#pragma unroll
    for (int i = 0; i < 7; ++i) {
      const int c = c0 + i * 16;
      float e = (c < L_) ? __expf(sS[row * 128 + c] - m) : 0.f;
      pv[i] = e; sum += e;
    }
#pragma unroll
    for (int off = 8; off; off >>= 1) sum += __shfl_xor(sum, off);
    const float inv = 1.f / sum;
#pragma unroll
    for (int i = 0; i < 8; ++i) {
      const int c = c0 + i * 16;
      ushort pb = (i < 7 && c < L_) ? f2b(pv[i < 7 ? i : 0] * inv) : (ushort)0;
      const int g = (c >> 3) ^ (row & 7);
      sP[row * 128 + g * 8 + (c & 7)] = pb;
    }
  }
  __syncthreads();

  f32x4 accO[12];
#pragma unroll
  for (int i = 0; i < 12; ++i) accO[i] = (f32x4){0.f, 0.f, 0.f, 0.f};
#pragma unroll
  for (int ks = 0; ks < 4; ++ks) {
    const int k = ks * 32 + lq * 8;
    const int g = (k >> 3) ^ (lrow & 7);
    bf16x8 ap = *(const bf16x8*)&sP[lrow * 128 + g * 8];
#pragma unroll
    for (int i = 0; i < 12; ++i) {
      const int col = w * 192 + i * 16 + lrow;
      bf16x8 bv = *(const bf16x8*)(vt + ((size_t)b * 768 + col) * 128 + k);
      accO[i] = __builtin_amdgcn_mfma_f32_16x16x32_bf16(ap, bv, accO[i], 0, 0, 0);
    }
  }
#pragma unroll
  for (int i = 0; i < 12; ++i) {
    const int col = w * 192 + i * 16 + lrow;
#pragma unroll
    for (int r = 0; r < 4; ++r) {
      const int row = qr0 + lq * 4 + r;
      if (row < L_)
        ctxb[((size_t)b * L_ + row) * 768 + col] = f2b(accO[i][r]);
    }
  }
}

// ------- LayerNorm(A + Bres[bf16]) -> bf16.  A is f32 (AF32) or bf16. ------
template<bool AF32>
__global__ __launch_bounds__(256)
void ln_kernel(const float* __restrict__ Af, const ushort* __restrict__ Ab,
               const ushort* __restrict__ Bres,
               const float* __restrict__ g, const float* __restrict__ beta,
               ushort* __restrict__ outb)
{
  const int row = blockIdx.x, tid = threadIdx.x;
  const ushort* bp = Bres + (size_t)row * U_;
  float a0, a1, a2;
  if constexpr (AF32) {
    const float* ap = Af + (size_t)row * U_;
    a0 = ap[tid]; a1 = ap[tid + 256]; a2 = ap[tid + 512];
  } else {
    const ushort* ap = Ab + (size_t)row * U_;
    a0 = b2f(ap[tid]); a1 = b2f(ap[tid + 256]); a2 = b2f(ap[tid + 512]);
  }
  float v0 = a0 + b2f(bp[tid]);
  float v1 = a1 + b2f(bp[tid + 256]);
  float v2 = a2 + b2f(bp[tid + 512]);
  float s = v0 + v1 + v2, sq = v0 * v0 + v1 * v1 + v2 * v2;
  __shared__ float red[8];
#pragma unroll
  for (int off = 32; off; off >>= 1) { s += __shfl_xor(s, off); sq += __shfl_xor(sq, off); }
  const int wave = tid >> 6, lane = tid & 63;
  if (lane == 0) { red[wave] = s; red[4 + wave] = sq; }
  __syncthreads();
  if (tid == 0) {
    float ts = red[0] + red[1] + red[2] + red[3];
    float tq = red[4] + red[5] + red[6] + red[7];
    float m = ts * (1.f / 768.f);
    float var = tq * (1.f / 768.f) - m * m;
    red[0] = m; red[1] = 1.f / sqrtf(var + 1e-5f);
  }
  __syncthreads();
  const float m = red[0], inv = red[1];
  ushort* ob = outb + (size_t)row * U_;
  ob[tid]       = f2b((v0 - m) * inv * g[tid]       + beta[tid]);
  ob[tid + 256] = f2b((v1 - m) * inv * g[tid + 256] + beta[tid + 256]);
  ob[tid + 512] = f2b((v2 - m) * inv * g[tid + 512] + beta[tid + 512]);
}

// ---- graph front: role-split {RGCN gather | edge softmax}, both read combo
__global__ __launch_bounds__(256)
void graphfront_kernel(const ushort* __restrict__ combo, const ushort* __restrict__ fcat,
                       const int* __restrict__ speaker,
                       ushort* __restrict__ catb, float* __restrict__ edge_norm)
{
  const int tid = threadIdx.x;
  if (blockIdx.x < N_ / 8) {
    const int n = blockIdx.x * 8 + (tid >> 5);
    const int lane = tid & 31;
    const int b = n / L_, k = n - b * L_;
    const int j0 = max(0, k - 10), j1 = min(L_ - 1, k + 10);
    const int spk = speaker[n];
    float inv[4];
    {
      int cn[4] = {0, 0, 0, 0};
      for (int j = j0; j <= j1; ++j)
        cn[speaker[b * L_ + j] * 2 + (j >= k ? 1 : 0)]++;
#pragma unroll
      for (int q = 0; q < 4; ++q) inv[q] = cn[q] ? 1.f / (float)cn[q] : 0.f;
    }
    float acc[8] = {};
    for (int j = j0; j <= j1; ++j) {
      const int spj = speaker[b * L_ + j];
      const int c = (j >= k) ? 1 : 0;
      const int et = (spj * 2 + spk) * 2 + c;
      const float w = inv[spj * 2 + c];
      bf16x8 v = *(const bf16x8*)&combo[(size_t)(b * L_ + j) * NC_ + 512 + et * 256 + lane * 8];
#pragma unroll
      for (int i = 0; i < 8; ++i) acc[i] = fmaf(b2f((ushort)v[i]), w, acc[i]);
    }
    bf16x8 rt = *(const bf16x8*)&combo[(size_t)n * NC_ + 2560 + lane * 8];
    bf16x8 o;
#pragma unroll
    for (int i = 0; i < 8; ++i) o[i] = (short)f2b(acc[i] + b2f((ushort)rt[i]));
    *(bf16x8*)&catb[(size_t)n * 512 + 256 + lane * 8] = o;
  } else {
    const int bj = blockIdx.x - N_ / 8;
    const int b = bj / L_, j = bj - b * L_;
    const int k0 = max(0, j - 10), k1 = min(L_ - 1, j + 10);
    __shared__ float s[32];
    const int wave = tid >> 6, lane = tid & 63;
    float tr[8];
    {
      bf16x8 tv = *(const bf16x8*)&combo[(size_t)bj * NC_ + lane * 8];
#pragma unroll
      for (int i = 0; i < 8; ++i) tr[i] = b2f((ushort)tv[i]);
    }
    for (int k = k0 + wave; k <= k1; k += 4) {
      bf16x8 v = *(const bf16x8*)&fcat[(size_t)(b * L_ + k) * 768 + lane * 8];
      float sc = 0.f;
#pragma unroll
      for (int i = 0; i < 8; ++i) sc = fmaf(b2f((ushort)v[i]), tr[i], sc);
#pragma unroll
      for (int off = 32; off; off >>= 1) sc += __shfl_xor(sc, off);
      if (lane == 0) s[k - k0] = sc;
    }
    __syncthreads();
    if (tid == 0) {
      const int W = k1 - k0 + 1;
      float m = -1e30f;
      for (int t = 0; t < W; ++t) m = fmaxf(m, s[t]);
      float sum = 0.f;
      for (int t = 0; t < W; ++t) { float e = __expf(s[t] - m); s[t] = e; sum += e; }
      const float inv = 1.f / sum;
      const int base = b * EPB_ + edge_prefix(j);
      for (int t = 0; t < W; ++t) edge_norm[base + t] = s[t] * inv;
    }
  }
}

// -------- GraphConv gather: reads h1 bf16 (catb[:,256:512]) -> agg ---------
__global__ __launch_bounds__(256)
void gcn_gather2_kernel(const float* __restrict__ edge_norm,
                        ushort* __restrict__ catb)
{
  const int tid = threadIdx.x;
  const int n = blockIdx.x * 8 + (tid >> 5);
  const int lane = tid & 31;
  const int b = n / L_, k = n - b * L_;
  const int j0 = max(0, k - 10), j1 = min(L_ - 1, k + 10);
  float acc[8] = {};
  for (int j = j0; j <= j1; ++j) {
    const float w = edge_norm[b * EPB_ + edge_prefix(j) + (k - max(0, j - 10))];
    bf16x8 v = *(const bf16x8*)&catb[(size_t)(b * L_ + j) * 512 + 256 + lane * 8];
#pragma unroll
    for (int i = 0; i < 8; ++i) acc[i] = fmaf(b2f((ushort)v[i]), w, acc[i]);
  }
  bf16x8 o;
#pragma unroll
  for (int i = 0; i < 8; ++i) o[i] = (short)f2b(acc[i]);
  *(bf16x8*)&catb[(size_t)n * 512 + lane * 8] = o;
}

// ------------- final tiny GEMM: out = hid(bf16) @ clf2_w^T + clf2_b --------
__global__ __launch_bounds__(256)
void clf2_kernel(const ushort* __restrict__ hid, const float* __restrict__ w,
                 const float* __restrict__ bias, float* __restrict__ out)
{
  __shared__ float wsm[7 * H_];
  const int tid = threadIdx.x;
  for (int i = tid; i < 7 * H_; i += 256) wsm[i] = w[i];
  __syncthreads();
  const int idx = blockIdx.x * 256 + threadIdx.x;
  if (idx < N_ * 7) {
    const int n = idx / 7, t = idx - n * 7;
    const ushort* hp = hid + (size_t)n * H_;
    const float* wp = wsm + t * H_;
    float acc = bias[t];
    for (int d0 = 0; d0 < H_; d0 += 8) {
      bf16x8 v = *(const bf16x8*)(hp + d0);
#pragma unroll
      for (int i = 0; i < 8; ++i) acc = fmaf(b2f((ushort)v[i]), wp[d0 + i], acc);
    }
    out[idx] = acc;
  }
}

extern "C" void kernel_launch(void* const* d_in, const int* in_sizes, int n_in,
                              void* d_out, int out_size, void* d_ws, size_t ws_size,
                              hipStream_t stream)
{
  const float* x          = (const float*)d_in[0];
  const float* in_proj_w  = (const float*)d_in[1];
  const float* in_proj_b  = (const float*)d_in[2];
  const float* out_proj_w = (const float*)d_in[3];
  const float* out_proj_b = (const float*)d_in[4];
  const float* ln1_g      = (const float*)d_in[5];
  const float* ln1_b      = (const float*)d_in[6];
  const float* ff1_w      = (const float*)d_in[7];
  const float* ff1_b      = (const float*)d_in[8];
  const float* ff2_w      = (const float*)d_in[9];
  const float* ff2_b      = (const float*)d_in[10];
  const float* ln2_g      = (const float*)d_in[11];
  const float* ln2_b      = (const float*)d_in[12];
  const float* to_w       = (const float*)d_in[13];
  const float* to_b       = (const float*)d_in[14];
  const float* att_w      = (const float*)d_in[15];
  const float* rgcn_basis = (const float*)d_in[16];
  const float* rgcn_comp  = (const float*)d_in[17];
  const float* rgcn_root  = (const float*)d_in[18];
  const float* rgcn_bias  = (const float*)d_in[19];
  const float* gc_rel_w   = (const float*)d_in[20];
  const float* gc_rel_b   = (const float*)d_in[21];
  const float* gc_root_w  = (const float*)d_in[22];
  const float* clf1_w     = (const float*)d_in[23];
  const float* clf1_b     = (const float*)d_in[24];
  const float* clf2_w     = (const float*)d_in[25];
  const float* clf2_b     = (const float*)d_in[26];
  const int*   speaker    = (const int*)d_in[27];
  float* out = (float*)d_out;
  char* p = (char*)d_ws;

  // ---- workspace regions ----
  float*  R1f    = (float*)p;
  ushort* R1b    = (ushort*)p;
  p += (size_t)N_ * 2304 * 4;
  ushort* aprojB = (ushort*)p;
  ushort* ffoB   = aprojB;
  float*  en     = (float*)(p + (size_t)N_ * 512 * 4);
  p += (size_t)N_ * 768 * 4;
  ushort* vt    = (ushort*)p;
  ushort* hidB  = (ushort*)p;
  p += (size_t)N_ * 768 * 4;
  ushort* xb    = (ushort*)p;
  ushort* ctxb  = xb;
  p += (size_t)N_ * 768 * 2;
  ushort* hb    = (ushort*)p;
  ushort* catb  = hb;
  p += (size_t)N_ * 768 * 2;
  ushort* fcat  = (ushort*)p; p += (size_t)N_ * 768 * 2;
  ushort* in_projb = (ushort*)p; p += (size_t)2304 * 768 * 2;
  ushort* out_projb= (ushort*)p; p += (size_t)768 * 768 * 2;
  ushort* ff1b     = (ushort*)p; p += (size_t)2048 * 768 * 2;
  ushort* ff2b     = (ushort*)p; p += (size_t)768 * 2048 * 2;
  ushort* tob      = (ushort*)p; p += (size_t)512 * 768 * 2;
  ushort* combw    = (ushort*)p; p += (size_t)NC_ * 512 * 2;  // [attw_t|wrel_t|root_t]
  ushort* gccat    = (ushort*)p; p += (size_t)256 * 512 * 2;
  ushort* clf1b16  = (ushort*)p; p += (size_t)256 * 768 * 2;
  float*  bias_comb= (float*)p;  p += NC_ * 4;
  float*  wrelTmp  = R1f;   // consumed before qkv GEMM

  // ---- weight/input prep (3 dispatches) ----
  Segs7 segs;
  segs.in[0] = x;          segs.out[0] = xb;        segs.n4[0] = N_ * 768 / 4;
  segs.in[1] = in_proj_w;  segs.out[1] = in_projb;  segs.n4[1] = 2304 * 768 / 4;
  segs.in[2] = out_proj_w; segs.out[2] = out_projb; segs.n4[2] = 768 * 768 / 4;
  segs.in[3] = ff1_w;      segs.out[3] = ff1b;      segs.n4[3] = 2048 * 768 / 4;
  segs.in[4] = ff2_w;      segs.out[4] = ff2b;      segs.n4[4] = 768 * 2048 / 4;
  segs.in[5] = to_w;       segs.out[5] = tob;       segs.n4[5] = 512 * 768 / 4;
  segs.in[6] = clf1_w;     segs.out[6] = clf1b16;   segs.n4[6] = 256 * 768 / 4;
  cvtprep_kernel<<<dim3(768, 8), 256, 0, stream>>>(
      segs, rgcn_bias, gc_rel_w, gc_root_w, bias_comb, gccat);
  wrel_kernel<<<512, 256, 0, stream>>>(rgcn_basis, rgcn_comp, wrelTmp);
  tcvt3_kernel<<<dim3(16, 16, 10), 256, 0, stream>>>(att_w, wrelTmp, rgcn_root, combw);

  // ---- main pipeline ----
  // qkvb = bf16(x @ in_proj^T + b)
  mgemm_kernel<true, false><<<dim3(18, 55), 256, 0, stream>>>(
      xb, in_projb, in_proj_b, R1b, 768, 768, 768, 2304);
  vtrans_kernel<<<dim3(24, 4, 64), 256, 0, stream>>>(R1b, vt);
  attnM_kernel<<<448, 256, 0, stream>>>(R1b, vt, ctxb);
  // aprojB = bf16(ctx @ out_proj^T + b)    (BN=64: 660 blocks)
  mgemm64_kernel<true, false><<<dim3(12, 55), 256, 0, stream>>>(
      ctxb, out_projb, out_proj_b, aprojB, 768, 768, 768, 768);
  ln_kernel<true><<<N_, 256, 0, stream>>>(x, nullptr, aprojB, ln1_g, ln1_b, hb);
  // ff = relu(h @ ff1^T + b)  (bf16)
  mgemm_kernel<true, true><<<dim3(16, 55), 256, 0, stream>>>(
      hb, ff1b, ff1_b, R1b, 768, 768, 768, 2048);
  // ffoB = bf16(ff @ ff2^T + b)            (BN=64: 660 blocks)
  mgemm64_kernel<true, false><<<dim3(12, 55), 256, 0, stream>>>(
      R1b, ff2b, ff2_b, ffoB, 2048, 2048, 2048, 768);
  ln_kernel<false><<<N_, 256, 0, stream>>>(nullptr, hb, ffoB, ln2_g, ln2_b, hb);
  // feats(bf16) -> fcat[:, 0:512]          (BN=64: 440 blocks)
  mgemm64_kernel<true, false><<<dim3(8, 55), 256, 0, stream>>>(
      hb, tob, to_b, fcat, 768, 768, 768, 768);
  // combo = bf16(feats @ [attw_t | wrel_t | root_t]^T + bias_comb) (N x 2816)
  mgemm_kernel<true, false><<<dim3(22, 55), 256, 0, stream>>>(
      fcat, combw, bias_comb, R1b, 512, 768, 512, NC_);
  graphfront_kernel<<<N_ / 8 + N_, 256, 0, stream>>>(R1b, fcat, speaker, catb, en);
  gcn_gather2_kernel<<<N_ / 8, 256, 0, stream>>>(en, catb);
  // h2(bf16) -> fcat[:, 512:768]           (BN=64: 220 blocks)
  mgemm64_kernel<true, false><<<dim3(4, 55), 256, 0, stream>>>(
      catb, gccat, gc_rel_b, fcat + 512, 512, 512, 512, 768);
  // hidB = bf16(relu(fcat @ clf1^T + b))   (BN=64: 220 blocks)
  mgemm64_kernel<true, true><<<dim3(4, 55), 256, 0, stream>>>(
      fcat, clf1b16, clf1_b, hidB, 768, 768, 768, 256);
  clf2_kernel<<<(N_ * 7 + 255) / 256, 256, 0, stream>>>(hidB, clf2_w, clf2_b, out);
}

// Round 11
// 300.691 us; speedup vs baseline: 7.6710x; 1.0099x over previous
//
#include <hip/hip_runtime.h>
#include <hip/hip_bf16.h>
#include <math.h>

#define L_   110
#define B_   64
#define N_   7040
#define U_   768
#define G_   512
#define H_   256
#define FF_  2048
#define EPB_ 2200
#define NC_  2816   // combined att_w(512) + wrel(2048) + root(256)

typedef __attribute__((ext_vector_type(4))) float f32x4;
typedef __attribute__((ext_vector_type(8))) short bf16x8;

__device__ __forceinline__ ushort f2b(float f) {
  union { __hip_bfloat16 h; ushort u; } cv;
  cv.h = __float2bfloat16(f);
  return cv.u;
}
__device__ __forceinline__ float b2f(ushort u) {
  union { float f; unsigned int i; } cv; cv.i = ((unsigned int)u) << 16; return cv.f;
}

// prefix(j) = number of edges with src-row j' < j within one dialogue
__device__ __forceinline__ int edge_prefix(int j) {
  if (j <= 10)  return j * 11 + (j * (j - 1)) / 2;
  if (j <= 100) return 155 + (j - 10) * 21;
  return 2045 + ((141 - j) * (j - 100)) / 2;
}

// ------ multi-segment prep: 7 f32->bf16 converts + bias_comb + gccat -------
struct Segs7 { const float* in[7]; ushort* out[7]; int n4[7]; };

__global__ __launch_bounds__(256)
void cvtprep_kernel(Segs7 s, const float* __restrict__ rb,
                    const float* __restrict__ rel, const float* __restrict__ root,
                    float* __restrict__ bias, ushort* __restrict__ gccat)
{
  const int seg = blockIdx.y;
  if (seg < 7) {
    const int n4 = s.n4[seg];
    const float* __restrict__ in = s.in[seg];
    ushort* __restrict__ out = s.out[seg];
    for (int i = blockIdx.x * 256 + threadIdx.x; i < n4; i += gridDim.x * 256) {
      float4 v = ((const float4*)in)[i];
      ushort4 o;
      o.x = f2b(v.x); o.y = f2b(v.y); o.z = f2b(v.z); o.w = f2b(v.w);
      ((ushort4*)out)[i] = o;
    }
  } else {
    const int i = blockIdx.x * 256 + threadIdx.x;
    if (i < NC_) {
      bias[i] = (i < 2560) ? 0.f : rb[i - 2560];
    } else if (i < NC_ + 65536) {
      const int j = i - NC_;
      const int r = j >> 8, c = j & 255;
      gccat[(size_t)r * 512 + c]       = f2b(rel[j]);
      gccat[(size_t)r * 512 + 256 + c] = f2b(root[j]);
    }
  }
}

// ---- fused wrel-compute + all transposes into combw ----------------------
// z=0: att_w (512x512) -> combw rows 0..511 (16x16 tiles)
// z=1 (by<8): root^T -> rows 2560..2815 ; wrel[r]^T -> rows 512..2559
__global__ __launch_bounds__(256)
void wrelt_kernel(const float* __restrict__ attw, const float* __restrict__ basis,
                  const float* __restrict__ comp, const float* __restrict__ root,
                  ushort* __restrict__ combw)
{
  const int tx = threadIdx.x & 31, ty = threadIdx.x >> 5;
  __shared__ float t[32][33];
  if (blockIdx.z == 0) {
    const int r0 = blockIdx.y * 32, c0 = blockIdx.x * 32;
    for (int i = ty; i < 32; i += 8)
      t[i][tx] = attw[(size_t)(r0 + i) * 512 + c0 + tx];
    __syncthreads();
    for (int i = ty; i < 32; i += 8)
      combw[(size_t)(c0 + i) * 512 + r0 + tx] = f2b(t[tx][i]);
  } else {
    if (blockIdx.y >= 8) return;
    const int g0 = blockIdx.x * 32, h0 = blockIdx.y * 32;
    __shared__ float cs[240];
    if (threadIdx.x < 240) cs[threadIdx.x] = comp[threadIdx.x];
    // root transpose: combw[(2560+h)*512+g] = root[g*256+h]
    for (int i = ty; i < 32; i += 8)
      t[i][tx] = root[(size_t)(g0 + i) * 256 + h0 + tx];
    __syncthreads();   // also makes cs visible
    for (int i = ty; i < 32; i += 8)
      combw[(size_t)(2560 + h0 + i) * 512 + g0 + tx] = f2b(t[tx][i]);
    // wrel accumulate: acc[r][k] over 30 bases at (g0+ty+8k, h0+tx)
    float acc[8][4] = {};
    for (int bb = 0; bb < 30; ++bb) {
      const float* bp = basis + (size_t)bb * (G_ * H_);
#pragma unroll
      for (int k = 0; k < 4; ++k) {
        float v = bp[(size_t)(g0 + ty + 8 * k) * 256 + h0 + tx];
#pragma unroll
        for (int r = 0; r < 8; ++r) acc[r][k] = fmaf(cs[r * 30 + bb], v, acc[r][k]);
      }
    }
    for (int r = 0; r < 8; ++r) {
      __syncthreads();
#pragma unroll
      for (int k = 0; k < 4; ++k) t[ty + 8 * k][tx] = acc[r][k];
      __syncthreads();
      for (int i = ty; i < 32; i += 8)
        combw[(size_t)(512 + r * 256 + h0 + i) * 512 + g0 + tx] = f2b(t[tx][i]);
    }
  }
}

// ===================== bf16 MFMA GEMM, 128x128 tile ========================
// XCD-aware bijective block remap (m204).
template<bool BIAS, bool RELU>
__global__ __launch_bounds__(256)
void mgemm_kernel(const ushort* __restrict__ A, const ushort* __restrict__ B,
                  const float* __restrict__ bias, ushort* __restrict__ Cb,
                  int K, int lda, int ldb, int ldc)
{
  __shared__ ushort sA[128 * 64];
  __shared__ ushort sB[128 * 64];
  const int tid = threadIdx.x;
  const int w = tid >> 6, l = tid & 63;

  const int gx = gridDim.x;
  const int nwg = gx * gridDim.y;
  const int lid = blockIdx.y * gx + blockIdx.x;
  const int q = nwg >> 3, r = nwg & 7;
  const int xcd = lid & 7, pos = lid >> 3;
  const int nlid = (xcd < r ? xcd * (q + 1) : r * (q + 1) + (xcd - r) * q) + pos;
  const int m0 = (nlid / gx) * 128, n0 = (nlid % gx) * 128;

  const int srow = l >> 3, sg = l & 7, rbase = w * 32;
  const int wr = w >> 1, wc = w & 1;
  const int lrow = l & 15, lk = l >> 4;
  const int xm = (l & 7) << 4;
  const int kb0 = (lk * 16) ^ xm;
  int aoff[4], boff[4];
#pragma unroll
  for (int i = 0; i < 4; ++i) {
    aoff[i] = (wr * 64 + i * 16 + lrow) * 128 + kb0;
    boff[i] = (wc * 64 + i * 16 + lrow) * 128 + kb0;
  }

  f32x4 acc[4][4];
#pragma unroll
  for (int i = 0; i < 4; ++i)
#pragma unroll
    for (int j = 0; j < 4; ++j) acc[i][j] = (f32x4){0.f, 0.f, 0.f, 0.f};

#define STAGE(k0)                                                              \
  {                                                                            \
    _Pragma("unroll")                                                          \
    for (int i = 0; i < 4; ++i) {                                              \
      const int trow = rbase + i * 8 + srow;                                   \
      const int koff = (sg * 8) ^ ((trow & 7) << 3);                           \
      const ushort* ga = A + (size_t)(m0 + trow) * lda + (k0) + koff;          \
      const ushort* gb = B + (size_t)(n0 + trow) * ldb + (k0) + koff;          \
      __builtin_amdgcn_global_load_lds(                                        \
          (const __attribute__((address_space(1))) void*)ga,                   \
          (__attribute__((address_space(3))) void*)&sA[(rbase + i * 8) * 64],  \
          16, 0, 0);                                                           \
      __builtin_amdgcn_global_load_lds(                                        \
          (const __attribute__((address_space(1))) void*)gb,                   \
          (__attribute__((address_space(3))) void*)&sB[(rbase + i * 8) * 64],  \
          16, 0, 0);                                                           \
    }                                                                          \
  }

  STAGE(0)
  for (int kt = 0;;) {
    __syncthreads();
#pragma unroll
    for (int h = 0; h < 2; ++h) {
      const int hx = h * 64;
      bf16x8 af[4], bfr[4];
#pragma unroll
      for (int i = 0; i < 4; ++i) {
        af[i]  = *(const bf16x8*)&sA[(aoff[i] ^ hx) >> 1];
        bfr[i] = *(const bf16x8*)&sB[(boff[i] ^ hx) >> 1];
      }
#pragma unroll
      for (int mi = 0; mi < 4; ++mi)
#pragma unroll
        for (int ni = 0; ni < 4; ++ni)
          acc[mi][ni] = __builtin_amdgcn_mfma_f32_16x16x32_bf16(
              af[mi], bfr[ni], acc[mi][ni], 0, 0, 0);
    }
    kt += 64;
    if (kt >= K) break;
    __syncthreads();
    STAGE(kt)
  }
#undef STAGE

  const int orow = m0 + wr * 64 + lk * 4;
  const int ocol = n0 + wc * 64 + lrow;
#pragma unroll
  for (int mi = 0; mi < 4; ++mi) {
#pragma unroll
    for (int r2 = 0; r2 < 4; ++r2) {
      const int row = orow + mi * 16 + r2;
#pragma unroll
      for (int ni = 0; ni < 4; ++ni) {
        const int col = ocol + ni * 16;
        float v = acc[mi][ni][r2];
        if constexpr (BIAS) v += bias[col];
        if constexpr (RELU) v = fmaxf(v, 0.f);
        Cb[(size_t)row * ldc + col] = f2b(v);
      }
    }
  }
}

// ===================== bf16 MFMA GEMM, 128x64 tile (narrow N) ==============
template<bool BIAS, bool RELU>
__global__ __launch_bounds__(256)
void mgemm64_kernel(const ushort* __restrict__ A, const ushort* __restrict__ B,
                    const float* __restrict__ bias, ushort* __restrict__ Cb,
                    int K, int lda, int ldb, int ldc)
{
  __shared__ ushort sA[128 * 64];
  __shared__ ushort sB[64 * 64];
  const int tid = threadIdx.x;
  const int w = tid >> 6, l = tid & 63;

  const int gx = gridDim.x;
  const int nwg = gx * gridDim.y;
  const int lid = blockIdx.y * gx + blockIdx.x;
  const int q = nwg >> 3, r = nwg & 7;
  const int xcd = lid & 7, pos = lid >> 3;
  const int nlid = (xcd < r ? xcd * (q + 1) : r * (q + 1) + (xcd - r) * q) + pos;
  const int m0 = (nlid / gx) * 128, n0 = (nlid % gx) * 64;

  const int srow = l >> 3, sg = l & 7;
  const int lrow = l & 15, lk = l >> 4;
  const int xm = (l & 7) << 4;
  const int kb0 = (lk * 16) ^ xm;
  int aoff[2], boff[4];
#pragma unroll
  for (int i = 0; i < 2; ++i) aoff[i] = (w * 32 + i * 16 + lrow) * 128 + kb0;
#pragma unroll
  for (int i = 0; i < 4; ++i) boff[i] = (i * 16 + lrow) * 128 + kb0;

  f32x4 acc[2][4];
#pragma unroll
  for (int i = 0; i < 2; ++i)
#pragma unroll
    for (int j = 0; j < 4; ++j) acc[i][j] = (f32x4){0.f, 0.f, 0.f, 0.f};

#define STAGE64(k0)                                                            \
  {                                                                            \
    _Pragma("unroll")                                                          \
    for (int i = 0; i < 4; ++i) {                                              \
      const int trow = w * 32 + i * 8 + srow;                                  \
      const int koff = (sg * 8) ^ ((trow & 7) << 3);                           \
      const ushort* ga = A + (size_t)(m0 + trow) * lda + (k0) + koff;          \
      __builtin_amdgcn_global_load_lds(                                        \
          (const __attribute__((address_space(1))) void*)ga,                   \
          (__attribute__((address_space(3))) void*)&sA[(w * 32 + i * 8) * 64], \
          16, 0, 0);                                                           \
    }                                                                          \
    _Pragma("unroll")                                                          \
    for (int i = 0; i < 2; ++i) {                                              \
      const int trow = w * 16 + i * 8 + srow;                                  \
      const int koff = (sg * 8) ^ ((trow & 7) << 3);                           \
      const ushort* gb = B + (size_t)(n0 + trow) * ldb + (k0) + koff;          \
      __builtin_amdgcn_global_load_lds(                                        \
          (const __attribute__((address_space(1))) void*)gb,                   \
          (__attribute__((address_space(3))) void*)&sB[(w * 16 + i * 8) * 64], \
          16, 0, 0);                                                           \
    }                                                                          \
  }

  STAGE64(0)
  for (int kt = 0;;) {
    __syncthreads();
#pragma unroll
    for (int h = 0; h < 2; ++h) {
      const int hx = h * 64;
      bf16x8 af[2], bfr[4];
#pragma unroll
      for (int i = 0; i < 2; ++i) af[i] = *(const bf16x8*)&sA[(aoff[i] ^ hx) >> 1];
#pragma unroll
      for (int i = 0; i < 4; ++i) bfr[i] = *(const bf16x8*)&sB[(boff[i] ^ hx) >> 1];
#pragma unroll
      for (int mi = 0; mi < 2; ++mi)
#pragma unroll
        for (int ni = 0; ni < 4; ++ni)
          acc[mi][ni] = __builtin_amdgcn_mfma_f32_16x16x32_bf16(
              af[mi], bfr[ni], acc[mi][ni], 0, 0, 0);
    }
    kt += 64;
    if (kt >= K) break;
    __syncthreads();
    STAGE64(kt)
  }
#undef STAGE64

  const int orow = m0 + w * 32 + lk * 4;
  const int ocol = n0 + lrow;
#pragma unroll
  for (int mi = 0; mi < 2; ++mi) {
#pragma unroll
    for (int r2 = 0; r2 < 4; ++r2) {
      const int row = orow + mi * 16 + r2;
#pragma unroll
      for (int ni = 0; ni < 4; ++ni) {
        const int col = ocol + ni * 16;
        float v = acc[mi][ni][r2];
        if constexpr (BIAS) v += bias[col];
        if constexpr (RELU) v = fmaxf(v, 0.f);
        Cb[(size_t)row * ldc + col] = f2b(v);
      }
    }
  }
}

// -------- V transpose (ushort2-vectorized): V(110x768) -> vt(768x128) ------
__global__ __launch_bounds__(256)
void vtrans_kernel(const ushort* __restrict__ qkvb, ushort* __restrict__ vt)
{
  __shared__ ushort t[32][34];
  const int b = blockIdx.z;
  const int r0 = blockIdx.y * 32;   // V row (k), 0..127
  const int c0 = blockIdx.x * 32;   // V col (d), 0..767
  const int tid = threadIdx.x;
  for (int e = tid; e < 512; e += 256) {
    const int ri = e >> 4, ci2 = (e & 15) * 2;
    ushort2 v = make_ushort2(0, 0);
    if (r0 + ri < L_)
      v = *(const ushort2*)&qkvb[((size_t)(b * L_) + r0 + ri) * 2304 + 1536 + c0 + ci2];
    t[ri][ci2] = v.x; t[ri][ci2 + 1] = v.y;
  }
  __syncthreads();
  for (int e = tid; e < 512; e += 256) {
    const int ci = e >> 4, ri2 = (e & 15) * 2;
    ushort2 o = make_ushort2(t[ri2][ci], t[ri2 + 1][ci]);
    *(ushort2*)&vt[((size_t)b * 768 + c0 + ci) * 128 + r0 + ri2] = o;
  }
}

// -------- MFMA attention: 448 blocks, XCD-grouped ------------------------
__global__ __launch_bounds__(256)
void attnM_kernel(const ushort* __restrict__ qkvb, const ushort* __restrict__ vt,
                  ushort* __restrict__ ctxb)
{
  const int wg = blockIdx.x;
  const int xcd = wg & 7, slot = wg >> 3;
  const int b = xcd * 8 + slot / 7;
  const int qr0 = (slot % 7) * 16;
  const int tid = threadIdx.x, w = tid >> 6, l = tid & 63;
  __shared__ float  sS[16 * 128];
  __shared__ ushort sP[16 * 128];   // bf16, 16B-group XOR swizzle
  const int lrow = l & 15, lq = l >> 4;

  const ushort* Qbase = qkvb + ((size_t)(b * L_) + qr0 + lrow) * 2304 + lq * 8;
  f32x4 accS[2] = {{0.f,0.f,0.f,0.f},{0.f,0.f,0.f,0.f}};
  const int nf0 = w * 2;
  for (int k0 = 0; k0 < 768; k0 += 32) {
    bf16x8 aq = *(const bf16x8*)(Qbase + k0);
#pragma unroll
    for (int f = 0; f < 2; ++f) {
      const int nf = nf0 + f;
      if (nf < 7) {
        const ushort* Kp = qkvb + ((size_t)(b * L_) + nf * 16 + lrow) * 2304
                         + 768 + k0 + lq * 8;
        bf16x8 bk = *(const bf16x8*)Kp;
        accS[f] = __builtin_amdgcn_mfma_f32_16x16x32_bf16(aq, bk, accS[f], 0, 0, 0);
      }
    }
  }
  const float scale = 0.03608439182435161f;  // 1/sqrt(768)
#pragma unroll
  for (int f = 0; f < 2; ++f) {
    const int nf = nf0 + f;
    if (nf < 7) {
#pragma unroll
      for (int r = 0; r < 4; ++r)
        sS[(lq * 4 + r) * 128 + nf * 16 + lrow] = accS[f][r] * scale;
    }
  }
  __syncthreads();

  {
    const int row = w * 4 + lq;
    const int c0 = lrow;
    float m = -1e30f;
    for (int c = c0; c < L_; c += 16) m = fmaxf(m, sS[row * 128 + c]);
#pragma unroll
    for (int off = 8; off; off >>= 1) m = fmaxf(m, __shfl_xor(m, off));
    float pv[7];
    float sum = 0.f;
#pragma unroll
    for (int i = 0; i < 7; ++i) {
      const int c = c0 + i * 16;
      float e = (c < L_) ? __expf(sS[row * 128 + c] - m) : 0.f;
      pv[i] = e; sum += e;
    }
#pragma unroll
    for (int off = 8; off; off >>= 1) sum += __shfl_xor(sum, off);
    const float inv = 1.f / sum;
#pragma unroll
    for (int i = 0; i < 8; ++i) {
      const int c = c0 + i * 16;
      ushort pb = (i < 7 && c < L_) ? f2b(pv[i < 7 ? i : 0] * inv) : (ushort)0;
      const int g = (c >> 3) ^ (row & 7);
      sP[row * 128 + g * 8 + (c & 7)] = pb;
    }
  }
  __syncthreads();

  f32x4 accO[12];
#pragma unroll
  for (int i = 0; i < 12; ++i) accO[i] = (f32x4){0.f, 0.f, 0.f, 0.f};
#pragma unroll
  for (int ks = 0; ks < 4; ++ks) {
    const int k = ks * 32 + lq * 8;
    const int g = (k >> 3) ^ (lrow & 7);
    bf16x8 ap = *(const bf16x8*)&sP[lrow * 128 + g * 8];
#pragma unroll
    for (int i = 0; i < 12; ++i) {
      const int col = w * 192 + i * 16 + lrow;
      bf16x8 bv = *(const bf16x8*)(vt + ((size_t)b * 768 + col) * 128 + k);
      accO[i] = __builtin_amdgcn_mfma_f32_16x16x32_bf16(ap, bv, accO[i], 0, 0, 0);
    }
  }
#pragma unroll
  for (int i = 0; i < 12; ++i) {
    const int col = w * 192 + i * 16 + lrow;
#pragma unroll
    for (int r = 0; r < 4; ++r) {
      const int row = qr0 + lq * 4 + r;
      if (row < L_)
        ctxb[((size_t)b * L_ + row) * 768 + col] = f2b(accO[i][r]);
    }
  }
}

// ------- LayerNorm(A[bf16] + Bres[bf16]) -> bf16 ---------------------------
__global__ __launch_bounds__(256)
void ln_kernel(const ushort* __restrict__ Ab, const ushort* __restrict__ Bres,
               const float* __restrict__ g, const float* __restrict__ beta,
               ushort* __restrict__ outb)
{
  const int row = blockIdx.x, tid = threadIdx.x;
  const ushort* ap = Ab + (size_t)row * U_;
  const ushort* bp = Bres + (size_t)row * U_;
  float v0 = b2f(ap[tid])       + b2f(bp[tid]);
  float v1 = b2f(ap[tid + 256]) + b2f(bp[tid + 256]);
  float v2 = b2f(ap[tid + 512]) + b2f(bp[tid + 512]);
  float s = v0 + v1 + v2, sq = v0 * v0 + v1 * v1 + v2 * v2;
  __shared__ float red[8];
#pragma unroll
  for (int off = 32; off; off >>= 1) { s += __shfl_xor(s, off); sq += __shfl_xor(sq, off); }
  const int wave = tid >> 6, lane = tid & 63;
  if (lane == 0) { red[wave] = s; red[4 + wave] = sq; }
  __syncthreads();
  if (tid == 0) {
    float ts = red[0] + red[1] + red[2] + red[3];
    float tq = red[4] + red[5] + red[6] + red[7];
    float m = ts * (1.f / 768.f);
    float var = tq * (1.f / 768.f) - m * m;
    red[0] = m; red[1] = 1.f / sqrtf(var + 1e-5f);
  }
  __syncthreads();
  const float m = red[0], inv = red[1];
  ushort* ob = outb + (size_t)row * U_;
  ob[tid]       = f2b((v0 - m) * inv * g[tid]       + beta[tid]);
  ob[tid + 256] = f2b((v1 - m) * inv * g[tid + 256] + beta[tid + 256]);
  ob[tid + 512] = f2b((v2 - m) * inv * g[tid + 512] + beta[tid + 512]);
}

// ---- graph front: role-split {RGCN gather | edge softmax}, both read combo
__global__ __launch_bounds__(256)
void graphfront_kernel(const ushort* __restrict__ combo, const ushort* __restrict__ fcat,
                       const int* __restrict__ speaker,
                       ushort* __restrict__ catb, float* __restrict__ edge_norm)
{
  const int tid = threadIdx.x;
  if (blockIdx.x < N_ / 8) {
    const int n = blockIdx.x * 8 + (tid >> 5);
    const int lane = tid & 31;
    const int b = n / L_, k = n - b * L_;
    const int j0 = max(0, k - 10), j1 = min(L_ - 1, k + 10);
    const int spk = speaker[n];
    float inv[4];
    {
      int cn[4] = {0, 0, 0, 0};
      for (int j = j0; j <= j1; ++j)
        cn[speaker[b * L_ + j] * 2 + (j >= k ? 1 : 0)]++;
#pragma unroll
      for (int q = 0; q < 4; ++q) inv[q] = cn[q] ? 1.f / (float)cn[q] : 0.f;
    }
    float acc[8] = {};
    for (int j = j0; j <= j1; ++j) {
      const int spj = speaker[b * L_ + j];
      const int c = (j >= k) ? 1 : 0;
      const int et = (spj * 2 + spk) * 2 + c;
      const float w = inv[spj * 2 + c];
      bf16x8 v = *(const bf16x8*)&combo[(size_t)(b * L_ + j) * NC_ + 512 + et * 256 + lane * 8];
#pragma unroll
      for (int i = 0; i < 8; ++i) acc[i] = fmaf(b2f((ushort)v[i]), w, acc[i]);
    }
    bf16x8 rt = *(const bf16x8*)&combo[(size_t)n * NC_ + 2560 + lane * 8];
    bf16x8 o;
#pragma unroll
    for (int i = 0; i < 8; ++i) o[i] = (short)f2b(acc[i] + b2f((ushort)rt[i]));
    *(bf16x8*)&catb[(size_t)n * 512 + 256 + lane * 8] = o;
  } else {
    const int bj = blockIdx.x - N_ / 8;
    const int b = bj / L_, j = bj - b * L_;
    const int k0 = max(0, j - 10), k1 = min(L_ - 1, j + 10);
    __shared__ float s[32];
    const int wave = tid >> 6, lane = tid & 63;
    float tr[8];
    {
      bf16x8 tv = *(const bf16x8*)&combo[(size_t)bj * NC_ + lane * 8];
#pragma unroll
      for (int i = 0; i < 8; ++i) tr[i] = b2f((ushort)tv[i]);
    }
    for (int k = k0 + wave; k <= k1; k += 4) {
      bf16x8 v = *(const bf16x8*)&fcat[(size_t)(b * L_ + k) * 768 + lane * 8];
      float sc = 0.f;
#pragma unroll
      for (int i = 0; i < 8; ++i) sc = fmaf(b2f((ushort)v[i]), tr[i], sc);
#pragma unroll
      for (int off = 32; off; off >>= 1) sc += __shfl_xor(sc, off);
      if (lane == 0) s[k - k0] = sc;
    }
    __syncthreads();
    if (tid == 0) {
      const int W = k1 - k0 + 1;
      float m = -1e30f;
      for (int t = 0; t < W; ++t) m = fmaxf(m, s[t]);
      float sum = 0.f;
      for (int t = 0; t < W; ++t) { float e = __expf(s[t] - m); s[t] = e; sum += e; }
      const float inv = 1.f / sum;
      const int base = b * EPB_ + edge_prefix(j);
      for (int t = 0; t < W; ++t) edge_norm[base + t] = s[t] * inv;
    }
  }
}

// -------- GraphConv gather: reads h1 bf16 (catb[:,256:512]) -> agg ---------
__global__ __launch_bounds__(256)
void gcn_gather2_kernel(const float* __restrict__ edge_norm,
                        ushort* __restrict__ catb)
{
  const int tid = threadIdx.x;
  const int n = blockIdx.x * 8 + (tid >> 5);
  const int lane = tid & 31;
  const int b = n / L_, k = n - b * L_;
  const int j0 = max(0, k - 10), j1 = min(L_ - 1, k + 10);
  float acc[8] = {};
  for (int j = j0; j <= j1; ++j) {
    const float w = edge_norm[b * EPB_ + edge_prefix(j) + (k - max(0, j - 10))];
    bf16x8 v = *(const bf16x8*)&catb[(size_t)(b * L_ + j) * 512 + 256 + lane * 8];
#pragma unroll
    for (int i = 0; i < 8; ++i) acc[i] = fmaf(b2f((ushort)v[i]), w, acc[i]);
  }
  bf16x8 o;
#pragma unroll
  for (int i = 0; i < 8; ++i) o[i] = (short)f2b(acc[i]);
  *(bf16x8*)&catb[(size_t)n * 512 + lane * 8] = o;
}

// ------------- final tiny GEMM: out = hid(bf16) @ clf2_w^T + clf2_b --------
__global__ __launch_bounds__(256)
void clf2_kernel(const ushort* __restrict__ hid, const float* __restrict__ w,
                 const float* __restrict__ bias, float* __restrict__ out)
{
  __shared__ float wsm[7 * H_];
  const int tid = threadIdx.x;
  for (int i = tid; i < 7 * H_; i += 256) wsm[i] = w[i];
  __syncthreads();
  const int idx = blockIdx.x * 256 + threadIdx.x;
  if (idx < N_ * 7) {
    const int n = idx / 7, t = idx - n * 7;
    const ushort* hp = hid + (size_t)n * H_;
    const float* wp = wsm + t * H_;
    float acc = bias[t];
    for (int d0 = 0; d0 < H_; d0 += 8) {
      bf16x8 v = *(const bf16x8*)(hp + d0);
#pragma unroll
      for (int i = 0; i < 8; ++i) acc = fmaf(b2f((ushort)v[i]), wp[d0 + i], acc);
    }
    out[idx] = acc;
  }
}

extern "C" void kernel_launch(void* const* d_in, const int* in_sizes, int n_in,
                              void* d_out, int out_size, void* d_ws, size_t ws_size,
                              hipStream_t stream)
{
  const float* x          = (const float*)d_in[0];
  const float* in_proj_w  = (const float*)d_in[1];
  const float* in_proj_b  = (const float*)d_in[2];
  const float* out_proj_w = (const float*)d_in[3];
  const float* out_proj_b = (const float*)d_in[4];
  const float* ln1_g      = (const float*)d_in[5];
  const float* ln1_b      = (const float*)d_in[6];
  const float* ff1_w      = (const float*)d_in[7];
  const float* ff1_b      = (const float*)d_in[8];
  const float* ff2_w      = (const float*)d_in[9];
  const float* ff2_b      = (const float*)d_in[10];
  const float* ln2_g      = (const float*)d_in[11];
  const float* ln2_b      = (const float*)d_in[12];
  const float* to_w       = (const float*)d_in[13];
  const float* to_b       = (const float*)d_in[14];
  const float* att_w      = (const float*)d_in[15];
  const float* rgcn_basis = (const float*)d_in[16];
  const float* rgcn_comp  = (const float*)d_in[17];
  const float* rgcn_root  = (const float*)d_in[18];
  const float* rgcn_bias  = (const float*)d_in[19];
  const float* gc_rel_w   = (const float*)d_in[20];
  const float* gc_rel_b   = (const float*)d_in[21];
  const float* gc_root_w  = (const float*)d_in[22];
  const float* clf1_w     = (const float*)d_in[23];
  const float* clf1_b     = (const float*)d_in[24];
  const float* clf2_w     = (const float*)d_in[25];
  const float* clf2_b     = (const float*)d_in[26];
  const int*   speaker    = (const int*)d_in[27];
  float* out = (float*)d_out;
  char* p = (char*)d_ws;

  // ---- workspace regions ----
  // R1 (65MB): qkvb bf16 -> ff bf16 -> combo bf16 (N x 2816)
  ushort* R1b    = (ushort*)p;
  p += (size_t)N_ * 2304 * 4;
  // R2 (21.6MB): aprojB/ffoB bf16 ; tail: edge_norm f32
  ushort* aprojB = (ushort*)p;
  ushort* ffoB   = aprojB;
  float*  en     = (float*)(p + (size_t)N_ * 512 * 4);
  p += (size_t)N_ * 768 * 4;
  // R3 (21.6MB): vt bf16 (attn) -> hidB bf16
  ushort* vt    = (ushort*)p;
  ushort* hidB  = (ushort*)p;
  p += (size_t)N_ * 768 * 4;
  // R4 (10.8MB): xb (persists through ln1)
  ushort* xb    = (ushort*)p;
  p += (size_t)N_ * 768 * 2;
  // R5 (10.8MB): hb bf16 (N x 768) -> catb bf16 (N x 512: [agg | h1])
  ushort* hb    = (ushort*)p;
  ushort* catb  = hb;
  p += (size_t)N_ * 768 * 2;
  // R6 (10.8MB): ctxb (attn out) -> fcat bf16 (N x 768: [feats | h2])
  ushort* fcat  = (ushort*)p;
  ushort* ctxb  = fcat;
  p += (size_t)N_ * 768 * 2;
  // R7: bf16 weights
  ushort* in_projb = (ushort*)p; p += (size_t)2304 * 768 * 2;
  ushort* out_projb= (ushort*)p; p += (size_t)768 * 768 * 2;
  ushort* ff1b     = (ushort*)p; p += (size_t)2048 * 768 * 2;
  ushort* ff2b     = (ushort*)p; p += (size_t)768 * 2048 * 2;
  ushort* tob      = (ushort*)p; p += (size_t)512 * 768 * 2;
  ushort* combw    = (ushort*)p; p += (size_t)NC_ * 512 * 2;  // [attw_t|wrel_t|root_t]
  ushort* gccat    = (ushort*)p; p += (size_t)256 * 512 * 2;
  ushort* clf1b16  = (ushort*)p; p += (size_t)256 * 768 * 2;
  float*  bias_comb= (float*)p;  p += NC_ * 4;

  // ---- weight/input prep (2 dispatches) ----
  Segs7 segs;
  segs.in[0] = x;          segs.out[0] = xb;        segs.n4[0] = N_ * 768 / 4;
  segs.in[1] = in_proj_w;  segs.out[1] = in_projb;  segs.n4[1] = 2304 * 768 / 4;
  segs.in[2] = out_proj_w; segs.out[2] = out_projb; segs.n4[2] = 768 * 768 / 4;
  segs.in[3] = ff1_w;      segs.out[3] = ff1b;      segs.n4[3] = 2048 * 768 / 4;
  segs.in[4] = ff2_w;      segs.out[4] = ff2b;      segs.n4[4] = 768 * 2048 / 4;
  segs.in[5] = to_w;       segs.out[5] = tob;       segs.n4[5] = 512 * 768 / 4;
  segs.in[6] = clf1_w;     segs.out[6] = clf1b16;   segs.n4[6] = 256 * 768 / 4;
  cvtprep_kernel<<<dim3(768, 8), 256, 0, stream>>>(
      segs, rgcn_bias, gc_rel_w, gc_root_w, bias_comb, gccat);
  wrelt_kernel<<<dim3(16, 16, 2), 256, 0, stream>>>(
      att_w, rgcn_basis, rgcn_comp, rgcn_root, combw);

  // ---- main pipeline ----
  // qkvb = bf16(x @ in_proj^T + b)
  mgemm_kernel<true, false><<<dim3(18, 55), 256, 0, stream>>>(
      xb, in_projb, in_proj_b, R1b, 768, 768, 768, 2304);
  vtrans_kernel<<<dim3(24, 4, 64), 256, 0, stream>>>(R1b, vt);
  attnM_kernel<<<448, 256, 0, stream>>>(R1b, vt, ctxb);
  // aprojB = bf16(ctx @ out_proj^T + b)    (BN=64: 660 blocks)
  mgemm64_kernel<true, false><<<dim3(12, 55), 256, 0, stream>>>(
      ctxb, out_projb, out_proj_b, aprojB, 768, 768, 768, 768);
  ln_kernel<<<N_, 256, 0, stream>>>(xb, aprojB, ln1_g, ln1_b, hb);
  // ff = relu(h @ ff1^T + b)  (bf16)
  mgemm_kernel<true, true><<<dim3(16, 55), 256, 0, stream>>>(
      hb, ff1b, ff1_b, R1b, 768, 768, 768, 2048);
  // ffoB = bf16(ff @ ff2^T + b)            (BN=64: 660 blocks)
  mgemm64_kernel<true, false><<<dim3(12, 55), 256, 0, stream>>>(
      R1b, ff2b, ff2_b, ffoB, 2048, 2048, 2048, 768);
  ln_kernel<<<N_, 256, 0, stream>>>(hb, ffoB, ln2_g, ln2_b, hb);
  // feats(bf16) -> fcat[:, 0:512]          (BN=64: 440 blocks)
  mgemm64_kernel<true, false><<<dim3(8, 55), 256, 0, stream>>>(
      hb, tob, to_b, fcat, 768, 768, 768, 768);
  // combo = bf16(feats @ [attw_t | wrel_t | root_t]^T + bias_comb) (N x 2816)
  mgemm_kernel<true, false><<<dim3(22, 55), 256, 0, stream>>>(
      fcat, combw, bias_comb, R1b, 512, 768, 512, NC_);
  graphfront_kernel<<<N_ / 8 + N_, 256, 0, stream>>>(R1b, fcat, speaker, catb, en);
  gcn_gather2_kernel<<<N_ / 8, 256, 0, stream>>>(en, catb);
  // h2(bf16) -> fcat[:, 512:768]           (BN=64: 220 blocks)
  mgemm64_kernel<true, false><<<dim3(4, 55), 256, 0, stream>>>(
      catb, gccat, gc_rel_b, fcat + 512, 512, 512, 512, 768);
  // hidB = bf16(relu(fcat @ clf1^T + b))   (BN=64: 220 blocks)
  mgemm64_kernel<true, true><<<dim3(4, 55), 256, 0, stream>>>(
      fcat, clf1b16, clf1_b, hidB, 768, 768, 768, 256);
  clf2_kernel<<<(N_ * 7 + 255) / 256, 256, 0, stream>>>(hidB, clf2_w, clf2_b, out);
}